// Round 1
// baseline (3811.757 us; speedup 1.0000x reference)
//
#include <hip/hip_runtime.h>
#include <float.h>

// Problem constants: B=1, S=2048, D=2048, H=16, HD=128, HV=4, R=128, NV=2048, K=4
#define NEG_MIN (-3.4028234663852886e38f)   // jnp.finfo(f32).min == -FLT_MAX
#define INV_SQRT_HD 0.08838834764831845f    // 1/sqrt(128)

// ---------------------------------------------------------------------------
// Generic f32 GEMM: C[M,N] = A[M,K] @ B[K,N], row-major, strides lda/ldb/ldc.
// 128x128 tile, K-step 16, 256 threads, 8x8 per-thread microtile.
// M = gridDim.y*128, N = gridDim.x*128 (all dims here divide evenly).
// ---------------------------------------------------------------------------
__global__ __launch_bounds__(256) void gemm_f32(
    const float* __restrict__ A, int lda,
    const float* __restrict__ B, int ldb,
    float* __restrict__ C, int ldc,
    int Kd)
{
  __shared__ float As[16][128];   // As[k][m]
  __shared__ float Bs[16][128];   // Bs[k][n]
  const int t  = threadIdx.x;
  const int tx = t & 15, ty = t >> 4;
  const int bm = blockIdx.y << 7, bn = blockIdx.x << 7;
  float acc[8][8];
#pragma unroll
  for (int i = 0; i < 8; ++i)
#pragma unroll
    for (int j = 0; j < 8; ++j) acc[i][j] = 0.f;

  for (int k0 = 0; k0 < Kd; k0 += 16) {
    __syncthreads();
    // A tile: 128 rows x 16 cols = 512 float4, 2 per thread; store transposed
    for (int i = t; i < 512; i += 256) {
      int rr = i >> 2, c4 = (i & 3) << 2;
      float4 av = *(const float4*)(A + (size_t)(bm + rr) * lda + k0 + c4);
      As[c4 + 0][rr] = av.x;
      As[c4 + 1][rr] = av.y;
      As[c4 + 2][rr] = av.z;
      As[c4 + 3][rr] = av.w;
    }
    // B tile: 16 rows x 128 cols = 512 float4
    for (int i = t; i < 512; i += 256) {
      int rr = i >> 5, c4 = (i & 31) << 2;
      *(float4*)(&Bs[rr][c4]) = *(const float4*)(B + (size_t)(k0 + rr) * ldb + bn + c4);
    }
    __syncthreads();
#pragma unroll
    for (int kk = 0; kk < 16; ++kk) {
      float4 a0 = *(const float4*)(&As[kk][ty * 8]);
      float4 a1 = *(const float4*)(&As[kk][ty * 8 + 4]);
      float4 b0 = *(const float4*)(&Bs[kk][tx * 8]);
      float4 b1 = *(const float4*)(&Bs[kk][tx * 8 + 4]);
      float av[8] = {a0.x, a0.y, a0.z, a0.w, a1.x, a1.y, a1.z, a1.w};
      float bv[8] = {b0.x, b0.y, b0.z, b0.w, b1.x, b1.y, b1.z, b1.w};
#pragma unroll
      for (int i = 0; i < 8; ++i)
#pragma unroll
        for (int j = 0; j < 8; ++j)
          acc[i][j] = fmaf(av[i], bv[j], acc[i][j]);
    }
  }
#pragma unroll
  for (int i = 0; i < 8; ++i) {
    int row = bm + ty * 8 + i;
#pragma unroll
    for (int j4 = 0; j4 < 8; j4 += 4) {
      float4 o = make_float4(acc[i][j4], acc[i][j4 + 1], acc[i][j4 + 2], acc[i][j4 + 3]);
      *(float4*)(C + (size_t)row * ldc + bn + tx * 8 + j4) = o;
    }
  }
}

// ---------------------------------------------------------------------------
// Per-row top-4 of a materialized 2048-wide sim row (one block per s).
// Tie-break: lower index first (matches jax.lax.top_k).
// ---------------------------------------------------------------------------
__global__ __launch_bounds__(256) void topk_rows(const float* __restrict__ sim,
                                                 int* __restrict__ idxo, int hv)
{
  const int s = blockIdx.x;
  const int t = threadIdx.x;
  const float* row = sim + (size_t)s * 2048;
  float bv[4] = {-FLT_MAX, -FLT_MAX, -FLT_MAX, -FLT_MAX};
  int   bi[4] = {0x7fffffff, 0x7fffffff, 0x7fffffff, 0x7fffffff};
  for (int j = 0; j < 8; ++j) {
    int n = t + (j << 8);
    float val = row[n];
    if (val > bv[3]) {              // strict > keeps earlier (lower) index on tie
      bv[3] = val; bi[3] = n;
      for (int p = 3; p > 0 && bv[p] > bv[p - 1]; --p) {
        float tv = bv[p]; bv[p] = bv[p - 1]; bv[p - 1] = tv;
        int   ti = bi[p]; bi[p] = bi[p - 1]; bi[p - 1] = ti;
      }
    }
  }
  __shared__ float rv[1024];
  __shared__ int   ri[1024];
  for (int p = 0; p < 4; ++p) { rv[t * 4 + p] = bv[p]; ri[t * 4 + p] = bi[p]; }
  __syncthreads();
  if (t == 0) {
    for (int pick = 0; pick < 4; ++pick) {
      float best = -FLT_MAX; int bidx = 0x7fffffff; int bpos = 0;
      for (int e = 0; e < 1024; ++e) {
        float v = rv[e];
        if (v > best || (v == best && ri[e] < bidx)) { best = v; bidx = ri[e]; bpos = e; }
      }
      idxo[((size_t)hv * 2048 + s) * 4 + pick] = bidx;
      rv[bpos] = -FLT_MAX; ri[bpos] = 0x7fffffff;
    }
  }
}

// ---------------------------------------------------------------------------
// v[s][d] = hs[s][d] * sum over 16 gathered v_embed rows (4 hv * top-4)
// ---------------------------------------------------------------------------
__global__ __launch_bounds__(256) void gather_mul_v(const float* __restrict__ hs,
    const float* __restrict__ vemb, const int* __restrict__ idx,
    float* __restrict__ v)
{
  const int s = blockIdx.x;
  const int t = threadIdx.x;
  __shared__ int id[16];
  if (t < 16) id[t] = idx[((size_t)(t >> 2) * 2048 + s) * 4 + (t & 3)];
  __syncthreads();
  for (int j = 0; j < 2; ++j) {
    int d = (t + (j << 8)) << 2;   // float4 per thread, coalesced
    float4 g = make_float4(0.f, 0.f, 0.f, 0.f);
#pragma unroll
    for (int e = 0; e < 16; ++e) {
      float4 ve = *(const float4*)(vemb + (size_t)id[e] * 2048 + d);
      g.x += ve.x; g.y += ve.y; g.z += ve.z; g.w += ve.w;
    }
    float4 hv4 = *(const float4*)(hs + (size_t)s * 2048 + d);
    float4 o = make_float4(hv4.x * g.x, hv4.y * g.y, hv4.z * g.z, hv4.w * g.w);
    *(float4*)(v + (size_t)s * 2048 + d) = o;
  }
}

// ---------------------------------------------------------------------------
// In-place RoPE on q (reference ropes q only, not k).
// q'[d]    = q[d]*cos[d]    - q[d+64]*sin[d]      (d < 64)
// q'[d+64] = q[d+64]*cos[d+64] + q[d]*sin[d+64]
// ---------------------------------------------------------------------------
__global__ __launch_bounds__(256) void rope_q(float* __restrict__ q,
    const float* __restrict__ cosb, const float* __restrict__ sinb)
{
  int tid = blockIdx.x * 256 + threadIdx.x;  // S*H*64 = 2,097,152 threads
  int d = tid & 63;
  int h = (tid >> 6) & 15;
  int s = tid >> 10;
  size_t base = (size_t)s * 2048 + h * 128;
  float c0 = cosb[s * 128 + d],      s0 = sinb[s * 128 + d];
  float c1 = cosb[s * 128 + d + 64], s1 = sinb[s * 128 + d + 64];
  float a = q[base + d], b = q[base + d + 64];
  q[base + d]      = a * c0 - b * s0;
  q[base + d + 64] = b * c1 + a * s1;
}

// ---------------------------------------------------------------------------
// Fused causal+dynamic-mask attention, online softmax, f32.
// Block = (64 q-rows, one head). 256 threads: tr=t/16 owns rows tr*4..+3,
// tc=t%16 owns score cols {tc+16j} and output dims tc*8..+7.
// Iterates ALL column tiles (fully-masked rows must softmax uniformly over
// all 2048 cols, exp(min_v - min_v) == 1 — exact reference semantics).
// ---------------------------------------------------------------------------
__global__ __launch_bounds__(256) void attn_fused(
    const float* __restrict__ q, const float* __restrict__ k,
    const float* __restrict__ v, const float* __restrict__ amask,
    const float* __restrict__ dmask, float* __restrict__ out)
{
  const int h  = blockIdx.y;
  const int q0 = blockIdx.x << 6;
  const int t  = threadIdx.x;
  const int tr = t >> 4;
  const int tc = t & 15;
  __shared__ float qs[64][132];   // +4 pad: keeps float4 alignment, spreads banks
  __shared__ float ks[64][132];
  __shared__ float vs[64][132];
  __shared__ float ps[64][65];
  __shared__ float mcol[64];

  for (int i = t; i < 2048; i += 256) {
    int rr = i >> 5, cc = (i & 31) << 2;
    *(float4*)(&qs[rr][cc]) = *(const float4*)(q + (size_t)(q0 + rr) * 2048 + h * 128 + cc);
  }
  float m[4], l[4], acc[4][8];
#pragma unroll
  for (int i = 0; i < 4; ++i) {
    m[i] = -FLT_MAX; l[i] = 0.f;
#pragma unroll
    for (int d = 0; d < 8; ++d) acc[i][d] = 0.f;
  }

  for (int c0 = 0; c0 < 2048; c0 += 64) {
    __syncthreads();
    for (int i = t; i < 2048; i += 256) {
      int rr = i >> 5, cc = (i & 31) << 2;
      *(float4*)(&ks[rr][cc]) = *(const float4*)(k + (size_t)(c0 + rr) * 2048 + h * 128 + cc);
      *(float4*)(&vs[rr][cc]) = *(const float4*)(v + (size_t)(c0 + rr) * 2048 + h * 128 + cc);
    }
    if (t < 64) mcol[t] = amask[c0 + t] * dmask[h * 2048 + c0 + t];
    __syncthreads();

    // ---- scores: 4 rows x 4 cols per thread, register-blocked over k
    float sc[4][4];
#pragma unroll
    for (int i = 0; i < 4; ++i)
#pragma unroll
      for (int j = 0; j < 4; ++j) sc[i][j] = 0.f;
    for (int kk = 0; kk < 128; kk += 4) {
      float4 qv[4], kv[4];
#pragma unroll
      for (int i = 0; i < 4; ++i) qv[i] = *(const float4*)(&qs[tr * 4 + i][kk]);
#pragma unroll
      for (int j = 0; j < 4; ++j) kv[j] = *(const float4*)(&ks[tc + 16 * j][kk]);
#pragma unroll
      for (int i = 0; i < 4; ++i)
#pragma unroll
        for (int j = 0; j < 4; ++j)
          sc[i][j] += qv[i].x * kv[j].x + qv[i].y * kv[j].y
                    + qv[i].z * kv[j].z + qv[i].w * kv[j].w;
    }

    // ---- mask + online softmax (per row, reduced across the 16 col-threads)
#pragma unroll
    for (int i = 0; i < 4; ++i) {
      int gr = q0 + tr * 4 + i;
      float tmax = -FLT_MAX;
      float sv[4];
#pragma unroll
      for (int j = 0; j < 4; ++j) {
        int c = tc + 16 * j;
        float x = sc[i][j] * INV_SQRT_HD;
        if (c0 + c > gr || mcol[c] == 0.f) x = NEG_MIN;
        sv[j] = x;
        tmax = fmaxf(tmax, x);
      }
      tmax = fmaxf(tmax, __shfl_xor(tmax, 1));
      tmax = fmaxf(tmax, __shfl_xor(tmax, 2));
      tmax = fmaxf(tmax, __shfl_xor(tmax, 4));
      tmax = fmaxf(tmax, __shfl_xor(tmax, 8));
      float mn = fmaxf(m[i], tmax);
      float scale = __expf(m[i] - mn);
      float psum = 0.f;
#pragma unroll
      for (int j = 0; j < 4; ++j) {
        float p = __expf(sv[j] - mn);
        ps[tr * 4 + i][tc + 16 * j] = p;
        psum += p;
      }
      psum += __shfl_xor(psum, 1);
      psum += __shfl_xor(psum, 2);
      psum += __shfl_xor(psum, 4);
      psum += __shfl_xor(psum, 8);
      l[i] = l[i] * scale + psum;
      m[i] = mn;
#pragma unroll
      for (int d = 0; d < 8; ++d) acc[i][d] *= scale;
    }
    __syncthreads();

    // ---- PV: acc[i][*] += p * v
    for (int c = 0; c < 64; ++c) {
      float4 v0 = *(const float4*)(&vs[c][tc * 8]);
      float4 v1 = *(const float4*)(&vs[c][tc * 8 + 4]);
#pragma unroll
      for (int i = 0; i < 4; ++i) {
        float p = ps[tr * 4 + i][c];
        acc[i][0] += p * v0.x; acc[i][1] += p * v0.y;
        acc[i][2] += p * v0.z; acc[i][3] += p * v0.w;
        acc[i][4] += p * v1.x; acc[i][5] += p * v1.y;
        acc[i][6] += p * v1.z; acc[i][7] += p * v1.w;
      }
    }
  }

#pragma unroll
  for (int i = 0; i < 4; ++i) {
    float inv = 1.f / l[i];
    int row = q0 + tr * 4 + i;
    float4 o0 = make_float4(acc[i][0] * inv, acc[i][1] * inv, acc[i][2] * inv, acc[i][3] * inv);
    float4 o1 = make_float4(acc[i][4] * inv, acc[i][5] * inv, acc[i][6] * inv, acc[i][7] * inv);
    *(float4*)(out + (size_t)row * 2048 + h * 128 + tc * 8)     = o0;
    *(float4*)(out + (size_t)row * 2048 + h * 128 + tc * 8 + 4) = o1;
  }
}

// ---------------------------------------------------------------------------
extern "C" void kernel_launch(void* const* d_in, const int* in_sizes, int n_in,
                              void* d_out, int out_size, void* d_ws, size_t ws_size,
                              hipStream_t stream)
{
  const float* hs    = (const float*)d_in[0];
  const float* amask = (const float*)d_in[1];
  const float* cosb  = (const float*)d_in[2];
  const float* sinb  = (const float*)d_in[3];
  const float* dmask = (const float*)d_in[4];
  const float* Wq    = (const float*)d_in[5];
  const float* Wk    = (const float*)d_in[6];
  const float* Wvq   = (const float*)d_in[7];
  const float* vkeys = (const float*)d_in[8];
  const float* vemb  = (const float*)d_in[9];
  const float* Wo    = (const float*)d_in[10];
  float* outp = (float*)d_out;

  // Workspace layout (floats). Peak 68.1 MB:
  //   q[4M] | k[4M] | v[4M] | vq[1M] sim[4M] idx  ... ao aliases vq+sim (dead)
  float* q   = (float*)d_ws;
  float* kb  = q  + (size_t)4194304;
  float* vb  = kb + (size_t)4194304;
  float* vq  = vb + (size_t)4194304;
  float* sim = vq + (size_t)1048576;
  int*   idx = (int*)(sim + (size_t)4194304);
  float* ao  = vq;  // reuse: vq/sim are dead by the time attention runs

  dim3 blk(256);
  // Projections
  gemm_f32<<<dim3(16, 16), blk, 0, stream>>>(hs, 2048, Wq, 2048, q, 2048, 2048);
  gemm_f32<<<dim3(16, 16), blk, 0, stream>>>(hs, 2048, Wk, 2048, kb, 2048, 2048);
  gemm_f32<<<dim3(4, 16),  blk, 0, stream>>>(hs, 2048, Wvq, 512, vq, 512, 2048);
  // Value routing: sim per hv head -> top-4 indices
  for (int hv = 0; hv < 4; ++hv) {
    gemm_f32<<<dim3(16, 16), blk, 0, stream>>>(vq + hv * 128, 512,
        vkeys + (size_t)hv * 128 * 2048, 2048, sim, 2048, 128);
    topk_rows<<<dim3(2048), blk, 0, stream>>>(sim, idx, hv);
  }
  // v = hs * gathered-sum(v_embed)
  gather_mul_v<<<dim3(2048), blk, 0, stream>>>(hs, vemb, idx, vb);
  // RoPE (q only)
  rope_q<<<dim3(8192), blk, 0, stream>>>(q, cosb, sinb);
  // Fused attention
  attn_fused<<<dim3(32, 16), blk, 0, stream>>>(q, kb, vb, amask, dmask, ao);
  // Output projection
  gemm_f32<<<dim3(16, 16), blk, 0, stream>>>(ao, 2048, Wo, 2048, outp, 2048, 2048);
}

// Round 2
// 2183.638 us; speedup vs baseline: 1.7456x; 1.7456x over previous
//
#include <hip/hip_runtime.h>
#include <float.h>

// B=1, S=2048, D=2048, H=16, HD=128, HV=4, R=128, NV=2048, K=4
#define NEG_MIN (-3.4028234663852886e38f)
#define INV_SQRT_HD 0.08838834764831845f

typedef __attribute__((ext_vector_type(8))) short bf16x8;
typedef __attribute__((ext_vector_type(4))) float f32x4;

__device__ __forceinline__ void gload_lds16(const void* g, void* l) {
  __builtin_amdgcn_global_load_lds((const __attribute__((address_space(1))) void*)g,
                                   (__attribute__((address_space(3))) void*)l, 16, 0, 0);
}
__device__ __forceinline__ ushort f2bf(float x) {
  union { float f; unsigned u; } v; v.f = x;
  unsigned r = v.u + 0x7fffu + ((v.u >> 16) & 1u);   // RNE
  return (ushort)(r >> 16);
}
__device__ __forceinline__ float bf2f(ushort u) {
  union { unsigned i; float f; } v; v.i = ((unsigned)u) << 16; return v.f;
}

// ---------------------------------------------------------------------------
// f32 GEMM (kept for the top-k routing path: vq and sim; index-exactness)
// ---------------------------------------------------------------------------
__global__ __launch_bounds__(256) void gemm_f32(
    const float* __restrict__ A, int lda,
    const float* __restrict__ B, int ldb,
    float* __restrict__ C, int ldc, int Kd)
{
  __shared__ float As[16][128];
  __shared__ float Bs[16][128];
  const int t = threadIdx.x;
  const int tx = t & 15, ty = t >> 4;
  const int bm = blockIdx.y << 7, bn = blockIdx.x << 7;
  float acc[8][8];
#pragma unroll
  for (int i = 0; i < 8; ++i)
#pragma unroll
    for (int j = 0; j < 8; ++j) acc[i][j] = 0.f;
  for (int k0 = 0; k0 < Kd; k0 += 16) {
    __syncthreads();
    for (int i = t; i < 512; i += 256) {
      int rr = i >> 2, c4 = (i & 3) << 2;
      float4 av = *(const float4*)(A + (size_t)(bm + rr) * lda + k0 + c4);
      As[c4 + 0][rr] = av.x; As[c4 + 1][rr] = av.y;
      As[c4 + 2][rr] = av.z; As[c4 + 3][rr] = av.w;
    }
    for (int i = t; i < 512; i += 256) {
      int rr = i >> 5, c4 = (i & 31) << 2;
      *(float4*)(&Bs[rr][c4]) = *(const float4*)(B + (size_t)(k0 + rr) * ldb + bn + c4);
    }
    __syncthreads();
#pragma unroll
    for (int kk = 0; kk < 16; ++kk) {
      float4 a0 = *(const float4*)(&As[kk][ty * 8]);
      float4 a1 = *(const float4*)(&As[kk][ty * 8 + 4]);
      float4 b0 = *(const float4*)(&Bs[kk][tx * 8]);
      float4 b1 = *(const float4*)(&Bs[kk][tx * 8 + 4]);
      float av[8] = {a0.x, a0.y, a0.z, a0.w, a1.x, a1.y, a1.z, a1.w};
      float bv[8] = {b0.x, b0.y, b0.z, b0.w, b1.x, b1.y, b1.z, b1.w};
#pragma unroll
      for (int i = 0; i < 8; ++i)
#pragma unroll
        for (int j = 0; j < 8; ++j)
          acc[i][j] = fmaf(av[i], bv[j], acc[i][j]);
    }
  }
#pragma unroll
  for (int i = 0; i < 8; ++i) {
    int row = bm + ty * 8 + i;
#pragma unroll
    for (int j4 = 0; j4 < 8; j4 += 4) {
      float4 o = make_float4(acc[i][j4], acc[i][j4+1], acc[i][j4+2], acc[i][j4+3]);
      *(float4*)(C + (size_t)row * ldc + bn + tx * 8 + j4) = o;
    }
  }
}

// ---------------------------------------------------------------------------
// bf16 MFMA GEMM: C[M,N] = A[M,K] * Bt[N,K]^T.  128x128 tile, BK=64,
// 4 waves in 2x2 quadrants, 4x4 16x16x32 frags per wave.
// LDS XOR-swizzled (byte ^= (row&7)<<4) via pre-swizzled global source.
// ---------------------------------------------------------------------------
template<int OUT_BF16>
__global__ __launch_bounds__(256) void gemm_bf16(
    const ushort* __restrict__ A, int lda,
    const ushort* __restrict__ Bt, int ldb,
    void* __restrict__ C, int ldc, int Kd)
{
  __shared__ ushort As[128 * 64];
  __shared__ ushort Bs[128 * 64];
  const int t = threadIdx.x, w = t >> 6, lane = t & 63;
  const int lr = lane & 15, lk = lane >> 4;
  const int bm = blockIdx.y << 7, bn = blockIdx.x << 7;
  const int wm = (w >> 1) << 6, wn = (w & 1) << 6;
  f32x4 acc[4][4];
#pragma unroll
  for (int i = 0; i < 4; ++i)
#pragma unroll
    for (int j = 0; j < 4; ++j) acc[i][j] = (f32x4){0.f, 0.f, 0.f, 0.f};

  for (int k0 = 0; k0 < Kd; k0 += 64) {
    __syncthreads();
#pragma unroll
    for (int qI = 0; qI < 4; ++qI) {            // A tile [128][64] bf16, 128B rows
      int b = w * 4096 + qI * 1024 + lane * 16;
      int row = b >> 7, colb = b & 127;
      int src = colb ^ ((row & 7) << 4);
      gload_lds16((const char*)A + ((size_t)(bm + row) * lda + k0) * 2 + src,
                  (char*)As + w * 4096 + qI * 1024);
    }
#pragma unroll
    for (int qI = 0; qI < 4; ++qI) {            // Bt tile [128][64]
      int b = w * 4096 + qI * 1024 + lane * 16;
      int row = b >> 7, colb = b & 127;
      int src = colb ^ ((row & 7) << 4);
      gload_lds16((const char*)Bt + ((size_t)(bn + row) * ldb + k0) * 2 + src,
                  (char*)Bs + w * 4096 + qI * 1024);
    }
    __syncthreads();
#pragma unroll
    for (int kk = 0; kk < 2; ++kk) {
      bf16x8 af[4], bf[4];
#pragma unroll
      for (int mi = 0; mi < 4; ++mi) {
        int row = wm + mi * 16 + lr;
        af[mi] = *(const bf16x8*)((const char*)As + row * 128 + ((kk * 64 + lk * 16) ^ ((row & 7) << 4)));
      }
#pragma unroll
      for (int ni = 0; ni < 4; ++ni) {
        int row = wn + ni * 16 + lr;
        bf[ni] = *(const bf16x8*)((const char*)Bs + row * 128 + ((kk * 64 + lk * 16) ^ ((row & 7) << 4)));
      }
#pragma unroll
      for (int mi = 0; mi < 4; ++mi)
#pragma unroll
        for (int ni = 0; ni < 4; ++ni)
          acc[mi][ni] = __builtin_amdgcn_mfma_f32_16x16x32_bf16(af[mi], bf[ni], acc[mi][ni], 0, 0, 0);
    }
  }
#pragma unroll
  for (int mi = 0; mi < 4; ++mi)
#pragma unroll
    for (int j = 0; j < 4; ++j) {
      int row = bm + wm + mi * 16 + lk * 4 + j;
#pragma unroll
      for (int ni = 0; ni < 4; ++ni) {
        int col = bn + wn + ni * 16 + lr;
        if (OUT_BF16) ((ushort*)C)[(size_t)row * ldc + col] = f2bf(acc[mi][ni][j]);
        else          ((float*)C)[(size_t)row * ldc + col]  = acc[mi][ni][j];
      }
    }
}

// ---------------------------------------------------------------------------
// transpose + f32->bf16:  dst[c][r] = src[r][c]
// ---------------------------------------------------------------------------
__global__ __launch_bounds__(256) void transpose_cvt(
    const float* __restrict__ src, ushort* __restrict__ dst, int R, int Cc)
{
  __shared__ float tile[64][65];
  const int r0 = blockIdx.y << 6, c0 = blockIdx.x << 6;
  const int t = threadIdx.x;
  for (int i = t; i < 1024; i += 256) {
    int r = i >> 4, c = (i & 15) << 2;
    float4 v = *(const float4*)(src + (size_t)(r0 + r) * Cc + c0 + c);
    tile[r][c] = v.x; tile[r][c+1] = v.y; tile[r][c+2] = v.z; tile[r][c+3] = v.w;
  }
  __syncthreads();
  int c = t >> 2, rb = (t & 3) << 4;
#pragma unroll
  for (int u = 0; u < 16; u += 4) {
    ushort4 o;
    o.x = f2bf(tile[rb+u+0][c]); o.y = f2bf(tile[rb+u+1][c]);
    o.z = f2bf(tile[rb+u+2][c]); o.w = f2bf(tile[rb+u+3][c]);
    *(ushort4*)(dst + (size_t)(c0 + c) * R + r0 + rb + u) = o;
  }
}

// elementwise f32 -> bf16
__global__ __launch_bounds__(256) void cvt_bf16(const float* __restrict__ src,
                                                ushort* __restrict__ dst)
{
  int i = blockIdx.x * 256 + threadIdx.x;
  float4 v = ((const float4*)src)[i];
  ushort4 o; o.x = f2bf(v.x); o.y = f2bf(v.y); o.z = f2bf(v.z); o.w = f2bf(v.w);
  ((ushort4*)dst)[i] = o;
}

// ---------------------------------------------------------------------------
// top-4 per sim row (tie-break lower index, matches jax.lax.top_k)
// ---------------------------------------------------------------------------
__global__ __launch_bounds__(256) void topk_rows(const float* __restrict__ sim,
                                                 int* __restrict__ idxo, int hv)
{
  const int s = blockIdx.x;
  const int t = threadIdx.x;
  const float* row = sim + (size_t)s * 2048;
  float bv[4] = {-FLT_MAX, -FLT_MAX, -FLT_MAX, -FLT_MAX};
  int   bi[4] = {0x7fffffff, 0x7fffffff, 0x7fffffff, 0x7fffffff};
  for (int j = 0; j < 8; ++j) {
    int n = t + (j << 8);
    float val = row[n];
    if (val > bv[3]) {
      bv[3] = val; bi[3] = n;
      for (int p = 3; p > 0 && bv[p] > bv[p-1]; --p) {
        float tv = bv[p]; bv[p] = bv[p-1]; bv[p-1] = tv;
        int   ti = bi[p]; bi[p] = bi[p-1]; bi[p-1] = ti;
      }
    }
  }
  __shared__ float rv[1024];
  __shared__ int   ri[1024];
  for (int p = 0; p < 4; ++p) { rv[t*4+p] = bv[p]; ri[t*4+p] = bi[p]; }
  __syncthreads();
  if (t == 0) {
    for (int pick = 0; pick < 4; ++pick) {
      float best = -FLT_MAX; int bidx = 0x7fffffff; int bpos = 0;
      for (int e = 0; e < 1024; ++e) {
        float v = rv[e];
        if (v > best || (v == best && ri[e] < bidx)) { best = v; bidx = ri[e]; bpos = e; }
      }
      idxo[((size_t)hv * 2048 + s) * 4 + pick] = bidx;
      rv[bpos] = -FLT_MAX; ri[bpos] = 0x7fffffff;
    }
  }
}

__global__ __launch_bounds__(256) void gather_mul_v(const float* __restrict__ hs,
    const float* __restrict__ vemb, const int* __restrict__ idx,
    float* __restrict__ v)
{
  const int s = blockIdx.x;
  const int t = threadIdx.x;
  __shared__ int id[16];
  if (t < 16) id[t] = idx[((size_t)(t >> 2) * 2048 + s) * 4 + (t & 3)];
  __syncthreads();
  for (int j = 0; j < 2; ++j) {
    int d = (t + (j << 8)) << 2;
    float4 g = make_float4(0.f, 0.f, 0.f, 0.f);
#pragma unroll
    for (int e = 0; e < 16; ++e) {
      float4 ve = *(const float4*)(vemb + (size_t)id[e] * 2048 + d);
      g.x += ve.x; g.y += ve.y; g.z += ve.z; g.w += ve.w;
    }
    float4 hv4 = *(const float4*)(hs + (size_t)s * 2048 + d);
    *(float4*)(v + (size_t)s * 2048 + d) =
        make_float4(hv4.x*g.x, hv4.y*g.y, hv4.z*g.z, hv4.w*g.w);
  }
}

// RoPE on bf16 q, in place
__global__ __launch_bounds__(256) void rope_q_bf(ushort* __restrict__ q,
    const float* __restrict__ cosb, const float* __restrict__ sinb)
{
  int tid = blockIdx.x * 256 + threadIdx.x;   // 2M threads
  int d = tid & 63, h = (tid >> 6) & 15, s = tid >> 10;
  size_t base = (size_t)s * 2048 + h * 128;
  float c0 = cosb[s*128 + d],      s0 = sinb[s*128 + d];
  float c1 = cosb[s*128 + d + 64], s1 = sinb[s*128 + d + 64];
  float a = bf2f(q[base + d]), b = bf2f(q[base + d + 64]);
  q[base + d]      = f2bf(a * c0 - b * s0);
  q[base + d + 64] = f2bf(b * c1 + a * s1);
}

// ---------------------------------------------------------------------------
// MFMA flash attention. Block = 64 q-rows x 1 head, 4 waves (wave w: rows
// w*16..+16). K/V tiles of 64 cols. q,k bf16 [s][2048]; vt bf16 [2048 d][2048 s].
// All LDS tiles XOR-swizzled; C-layout shared by S-acc and O-acc so softmax
// state (m,l) is lane-local. Iterates ALL tiles (fully-masked-row semantics).
// ---------------------------------------------------------------------------
__global__ __launch_bounds__(256) void attn_mfma(
    const ushort* __restrict__ qb, const ushort* __restrict__ kb,
    const ushort* __restrict__ vt, const float* __restrict__ amask,
    const float* __restrict__ dmask, ushort* __restrict__ ao)
{
  const int h  = blockIdx.y;
  const int q0 = blockIdx.x << 6;
  const int t  = threadIdx.x, w = t >> 6, lane = t & 63;
  const int lr = lane & 15, lk = lane >> 4;

  __shared__ ushort Qs[64 * 128];   // [64 rows][256B], swizzled
  __shared__ ushort Ks[64 * 128];
  __shared__ ushort Vs[128 * 64];   // [128 d][128B]
  __shared__ ushort Ps[64 * 64];    // [64 rows][128B]
  __shared__ float mcol[64];

#pragma unroll
  for (int qI = 0; qI < 4; ++qI) {            // stage Q once
    int b = w * 4096 + qI * 1024 + lane * 16;
    int row = b >> 8, colb = b & 255;
    int src = colb ^ ((row & 7) << 4);
    gload_lds16((const char*)qb + ((size_t)(q0 + row) * 2048 + h * 128) * 2 + src,
                (char*)Qs + w * 4096 + qI * 1024);
  }

  float m[4], l[4];
  f32x4 acc_o[8];
#pragma unroll
  for (int j = 0; j < 4; ++j) { m[j] = -FLT_MAX; l[j] = 0.f; }
#pragma unroll
  for (int ni = 0; ni < 8; ++ni) acc_o[ni] = (f32x4){0.f, 0.f, 0.f, 0.f};

  for (int c0 = 0; c0 < 2048; c0 += 64) {
    __syncthreads();
#pragma unroll
    for (int qI = 0; qI < 4; ++qI) {          // K tile [64][128] bf16
      int b = w * 4096 + qI * 1024 + lane * 16;
      int row = b >> 8, colb = b & 255;
      int src = colb ^ ((row & 7) << 4);
      gload_lds16((const char*)kb + ((size_t)(c0 + row) * 2048 + h * 128) * 2 + src,
                  (char*)Ks + w * 4096 + qI * 1024);
    }
#pragma unroll
    for (int qI = 0; qI < 4; ++qI) {          // Vt tile [128][64] bf16
      int b = w * 4096 + qI * 1024 + lane * 16;
      int row = b >> 7, colb = b & 127;
      int src = colb ^ ((row & 7) << 4);
      gload_lds16((const char*)vt + ((size_t)(h * 128 + row) * 2048 + c0) * 2 + src,
                  (char*)Vs + w * 4096 + qI * 1024);
    }
    if (t < 64) mcol[t] = amask[c0 + t] * dmask[h * 2048 + c0 + t];
    __syncthreads();

    // ---- S = Q K^T (wave rows w*16..+16, cols 0..64 of tile)
    f32x4 sacc[4];
#pragma unroll
    for (int ni = 0; ni < 4; ++ni) sacc[ni] = (f32x4){0.f, 0.f, 0.f, 0.f};
#pragma unroll
    for (int kk = 0; kk < 4; ++kk) {
      int qrow = w * 16 + lr;
      bf16x8 a = *(const bf16x8*)((const char*)Qs + qrow * 256 + ((kk * 64 + lk * 16) ^ ((qrow & 7) << 4)));
#pragma unroll
      for (int ni = 0; ni < 4; ++ni) {
        int krow = ni * 16 + lr;
        bf16x8 bfr = *(const bf16x8*)((const char*)Ks + krow * 256 + ((kk * 64 + lk * 16) ^ ((krow & 7) << 4)));
        sacc[ni] = __builtin_amdgcn_mfma_f32_16x16x32_bf16(a, bfr, sacc[ni], 0, 0, 0);
      }
    }

    // ---- mask + online softmax; write P (bf16) to swizzled LDS
#pragma unroll
    for (int j = 0; j < 4; ++j) {
      int grow = q0 + w * 16 + lk * 4 + j;
      float x[4]; float tmax = -FLT_MAX;
#pragma unroll
      for (int ni = 0; ni < 4; ++ni) {
        int c = ni * 16 + lr;
        float v = sacc[ni][j] * INV_SQRT_HD;
        if (c0 + c > grow || mcol[c] == 0.f) v = NEG_MIN;
        x[ni] = v; tmax = fmaxf(tmax, v);
      }
      tmax = fmaxf(tmax, __shfl_xor(tmax, 1));
      tmax = fmaxf(tmax, __shfl_xor(tmax, 2));
      tmax = fmaxf(tmax, __shfl_xor(tmax, 4));
      tmax = fmaxf(tmax, __shfl_xor(tmax, 8));
      float mn = fmaxf(m[j], tmax);
      float sc = __expf(m[j] - mn);
      float psum = 0.f;
      int prow = w * 16 + lk * 4 + j;
#pragma unroll
      for (int ni = 0; ni < 4; ++ni) {
        float p = __expf(x[ni] - mn);
        psum += p;
        *(ushort*)((char*)Ps + prow * 128 + ((2 * (ni * 16 + lr)) ^ ((prow & 7) << 4))) = f2bf(p);
      }
      psum += __shfl_xor(psum, 1);
      psum += __shfl_xor(psum, 2);
      psum += __shfl_xor(psum, 4);
      psum += __shfl_xor(psum, 8);
      l[j] = l[j] * sc + psum;
      m[j] = mn;
#pragma unroll
      for (int ni = 0; ni < 8; ++ni) acc_o[ni][j] *= sc;
    }
    __syncthreads();

    // ---- O += P V  (wave reads its own 16 P-rows; Vt gives contiguous k)
#pragma unroll
    for (int kk = 0; kk < 2; ++kk) {
      int prow = w * 16 + lr;
      bf16x8 a = *(const bf16x8*)((const char*)Ps + prow * 128 + ((kk * 64 + lk * 16) ^ ((prow & 7) << 4)));
#pragma unroll
      for (int ni = 0; ni < 8; ++ni) {
        int vrow = ni * 16 + lr;
        bf16x8 bfr = *(const bf16x8*)((const char*)Vs + vrow * 128 + ((kk * 64 + lk * 16) ^ ((vrow & 7) << 4)));
        acc_o[ni] = __builtin_amdgcn_mfma_f32_16x16x32_bf16(a, bfr, acc_o[ni], 0, 0, 0);
      }
    }
  }

#pragma unroll
  for (int j = 0; j < 4; ++j) {
    float inv = 1.f / l[j];
    int row = q0 + w * 16 + lk * 4 + j;
#pragma unroll
    for (int ni = 0; ni < 8; ++ni)
      ao[(size_t)row * 2048 + h * 128 + ni * 16 + lr] = f2bf(acc_o[ni][j] * inv);
  }
}

// ---------------------------------------------------------------------------
extern "C" void kernel_launch(void* const* d_in, const int* in_sizes, int n_in,
                              void* d_out, int out_size, void* d_ws, size_t ws_size,
                              hipStream_t stream)
{
  const float* hs    = (const float*)d_in[0];
  const float* amask = (const float*)d_in[1];
  const float* cosb  = (const float*)d_in[2];
  const float* sinb  = (const float*)d_in[3];
  const float* dmask = (const float*)d_in[4];
  const float* Wq    = (const float*)d_in[5];
  const float* Wk    = (const float*)d_in[6];
  const float* Wvq   = (const float*)d_in[7];
  const float* vkeys = (const float*)d_in[8];
  const float* vemb  = (const float*)d_in[9];
  const float* Wo    = (const float*)d_in[10];
  float* outp = (float*)d_out;

  char* ws = (char*)d_ws;
  // byte offsets (total 68.13 MB, fits the previously-validated footprint)
  ushort* hs_bf = (ushort*)(ws + 0);          //  8 MB [0,8M)
  ushort* WqT   = (ushort*)(ws + 8388608);    //  8 MB
  ushort* WkT   = (ushort*)(ws + 16777216);   //  8 MB
  ushort* WoT   = (ushort*)(ws + 25165824);   //  8 MB (live to the end)
  ushort* q_bf  = (ushort*)(ws + 33554432);   //  8 MB
  ushort* k_bf  = (ushort*)(ws + 41943040);   //  8 MB
  float*  vq    = (float*)(ws + 50331648);    //  4 MB
  float*  sim   = (float*)(ws + 54525952);    // 16 MB
  int*    idx   = (int*)(ws + 71303168);      // 128 KB  (end 71.43 MB... see aliases)
  float*  vb    = (float*)(ws + 0);           // 16 MB, aliases hs_bf+WqT (dead)
  ushort* vt    = (ushort*)(ws + 16777216);   //  8 MB, aliases WkT (dead)
  ushort* ao    = (ushort*)(ws + 50331648);   //  8 MB, aliases vq+sim head (dead)

  dim3 blk(256);
  // bf16 conversions / weight transposes
  cvt_bf16<<<dim3(4096), blk, 0, stream>>>(hs, hs_bf);
  transpose_cvt<<<dim3(32, 32), blk, 0, stream>>>(Wq, WqT, 2048, 2048);
  transpose_cvt<<<dim3(32, 32), blk, 0, stream>>>(Wk, WkT, 2048, 2048);
  transpose_cvt<<<dim3(32, 32), blk, 0, stream>>>(Wo, WoT, 2048, 2048);
  // projections (bf16 MFMA)
  gemm_bf16<1><<<dim3(16, 16), blk, 0, stream>>>(hs_bf, 2048, WqT, 2048, q_bf, 2048, 2048);
  gemm_bf16<1><<<dim3(16, 16), blk, 0, stream>>>(hs_bf, 2048, WkT, 2048, k_bf, 2048, 2048);
  // routing path in f32 (exact top-k indices)
  gemm_f32<<<dim3(4, 16), blk, 0, stream>>>(hs, 2048, Wvq, 512, vq, 512, 2048);
  for (int hv = 0; hv < 4; ++hv) {
    gemm_f32<<<dim3(16, 16), blk, 0, stream>>>(vq + hv * 128, 512,
        vkeys + (size_t)hv * 128 * 2048, 2048, sim, 2048, 128);
    topk_rows<<<dim3(2048), blk, 0, stream>>>(sim, idx, hv);
  }
  gather_mul_v<<<dim3(2048), blk, 0, stream>>>(hs, vemb, idx, vb);
  transpose_cvt<<<dim3(32, 32), blk, 0, stream>>>(vb, vt, 2048, 2048);
  // RoPE on q (bf16, in place)
  rope_q_bf<<<dim3(8192), blk, 0, stream>>>(q_bf, cosb, sinb);
  // fused MFMA attention
  attn_mfma<<<dim3(32, 16), blk, 0, stream>>>(q_bf, k_bf, vt, amask, dmask, ao);
  // output projection -> f32
  gemm_bf16<0><<<dim3(16, 16), blk, 0, stream>>>(ao, 2048, WoT, 2048, outp, 2048, 2048);
}

// Round 3
// 477.032 us; speedup vs baseline: 7.9906x; 4.5775x over previous
//
#include <hip/hip_runtime.h>
#include <float.h>

// B=1, S=2048, D=2048, H=16, HD=128, HV=4, R=128, NV=2048, K=4
#define NEG_MIN (-3.4028234663852886e38f)
#define INV_SQRT_HD 0.08838834764831845f

typedef __attribute__((ext_vector_type(8))) short bf16x8;
typedef __attribute__((ext_vector_type(4))) float f32x4;

__device__ __forceinline__ void gload_lds16(const void* g, void* l) {
  __builtin_amdgcn_global_load_lds((const __attribute__((address_space(1))) void*)g,
                                   (__attribute__((address_space(3))) void*)l, 16, 0, 0);
}
__device__ __forceinline__ ushort f2bf(float x) {
  union { float f; unsigned u; } v; v.f = x;
  unsigned r = v.u + 0x7fffu + ((v.u >> 16) & 1u);   // RNE
  return (ushort)(r >> 16);
}
__device__ __forceinline__ float bf2f(ushort u) {
  union { unsigned i; float f; } v; v.i = ((unsigned)u) << 16; return v.f;
}

// ---------------------------------------------------------------------------
// Split-K f32 GEMM: Cp[z][M][N] = A[M, z*Kc:(z+1)*Kc] @ B[same rows, N]
// 64x64 tile, 4x4 microtile, 256 threads. grid=(N/64, M/64, KSplit).
// 1024 blocks -> 4 blocks/CU -> LDS latency hidden (fixes R2's 3% occupancy).
// ---------------------------------------------------------------------------
__global__ __launch_bounds__(256) void gemm_f32_sk(
    const float* __restrict__ A, int lda,
    const float* __restrict__ B, int ldb,
    float* __restrict__ Cp, int ldc, int M, int N, int Kchunk)
{
  const int t = threadIdx.x, tx = t & 15, ty = t >> 4;
  const int bm = blockIdx.y << 6, bn = blockIdx.x << 6;
  const int k0base = blockIdx.z * Kchunk;
  __shared__ float As[16][68];   // [k][m], 272B rows keep float4 alignment
  __shared__ float Bs[16][68];   // [k][n]
  float acc[4][4];
#pragma unroll
  for (int i = 0; i < 4; ++i)
#pragma unroll
    for (int j = 0; j < 4; ++j) acc[i][j] = 0.f;

  for (int k0 = 0; k0 < Kchunk; k0 += 16) {
    __syncthreads();
    {
      int rr = t >> 2, c4 = (t & 3) << 2;   // A: 64 rows x 16 k, store transposed
      float4 av = *(const float4*)(A + (size_t)(bm + rr) * lda + k0base + k0 + c4);
      As[c4 + 0][rr] = av.x; As[c4 + 1][rr] = av.y;
      As[c4 + 2][rr] = av.z; As[c4 + 3][rr] = av.w;
    }
    {
      int rr = t >> 4, c4 = (t & 15) << 2;  // B: 16 k x 64 n
      *(float4*)(&Bs[rr][c4]) = *(const float4*)(B + (size_t)(k0base + k0 + rr) * ldb + bn + c4);
    }
    __syncthreads();
#pragma unroll
    for (int kk = 0; kk < 16; ++kk) {
      float4 a = *(const float4*)(&As[kk][ty * 4]);
      float4 b = *(const float4*)(&Bs[kk][tx * 4]);
      float av[4] = {a.x, a.y, a.z, a.w};
      float bv[4] = {b.x, b.y, b.z, b.w};
#pragma unroll
      for (int i = 0; i < 4; ++i)
#pragma unroll
        for (int j = 0; j < 4; ++j)
          acc[i][j] = fmaf(av[i], bv[j], acc[i][j]);
    }
  }
  float* C = Cp + (size_t)blockIdx.z * M * N;
#pragma unroll
  for (int i = 0; i < 4; ++i)
    *(float4*)(C + (size_t)(bm + ty * 4 + i) * ldc + bn + tx * 4) =
        make_float4(acc[i][0], acc[i][1], acc[i][2], acc[i][3]);
}

// deterministic 4-way reduce of split-K partials + bf16 copy
__global__ __launch_bounds__(256) void reduce4_cvt(const float* __restrict__ Cp,
    float* __restrict__ vq, ushort* __restrict__ vq_bf)
{
  int i = (blockIdx.x * 256 + threadIdx.x) << 2;   // 1,048,576 floats total
  float4 a = *(const float4*)(Cp + i);
  float4 b = *(const float4*)(Cp + 1048576 + i);
  float4 c = *(const float4*)(Cp + 2097152 + i);
  float4 d = *(const float4*)(Cp + 3145728 + i);
  float4 s = make_float4(((a.x + b.x) + c.x) + d.x, ((a.y + b.y) + c.y) + d.y,
                         ((a.z + b.z) + c.z) + d.z, ((a.w + b.w) + c.w) + d.w);
  *(float4*)(vq + i) = s;
  ushort4 o; o.x = f2bf(s.x); o.y = f2bf(s.y); o.z = f2bf(s.z); o.w = f2bf(s.w);
  *(ushort4*)(vq_bf + i) = o;
}

// ---------------------------------------------------------------------------
// bf16 MFMA GEMM (z-batched): C = A @ Bt^T. 128x128 tile, BK=64, 4 waves,
// 4x4 16x16x32 frags. XOR-swizzled LDS via pre-swizzled global source.
// ---------------------------------------------------------------------------
template<int OUT_BF16>
__global__ __launch_bounds__(256) void gemm_bf16(
    const ushort* __restrict__ A0, int lda,
    const ushort* __restrict__ Bt0, int ldb,
    void* __restrict__ C0, int ldc, int Kd,
    size_t strA, size_t strB, size_t strC)
{
  const ushort* A  = A0  + blockIdx.z * strA;
  const ushort* Bt = Bt0 + blockIdx.z * strB;
  __shared__ ushort As[128 * 64];
  __shared__ ushort Bs[128 * 64];
  const int t = threadIdx.x, w = t >> 6, lane = t & 63;
  const int lr = lane & 15, lk = lane >> 4;
  const int bm = blockIdx.y << 7, bn = blockIdx.x << 7;
  const int wm = (w >> 1) << 6, wn = (w & 1) << 6;
  f32x4 acc[4][4];
#pragma unroll
  for (int i = 0; i < 4; ++i)
#pragma unroll
    for (int j = 0; j < 4; ++j) acc[i][j] = (f32x4){0.f, 0.f, 0.f, 0.f};

  for (int k0 = 0; k0 < Kd; k0 += 64) {
    __syncthreads();
#pragma unroll
    for (int qI = 0; qI < 4; ++qI) {
      int b = w * 4096 + qI * 1024 + lane * 16;
      int row = b >> 7, colb = b & 127;
      int src = colb ^ ((row & 7) << 4);
      gload_lds16((const char*)A + ((size_t)(bm + row) * lda + k0) * 2 + src,
                  (char*)As + w * 4096 + qI * 1024);
    }
#pragma unroll
    for (int qI = 0; qI < 4; ++qI) {
      int b = w * 4096 + qI * 1024 + lane * 16;
      int row = b >> 7, colb = b & 127;
      int src = colb ^ ((row & 7) << 4);
      gload_lds16((const char*)Bt + ((size_t)(bn + row) * ldb + k0) * 2 + src,
                  (char*)Bs + w * 4096 + qI * 1024);
    }
    __syncthreads();
#pragma unroll
    for (int kk = 0; kk < 2; ++kk) {
      bf16x8 af[4], bf[4];
#pragma unroll
      for (int mi = 0; mi < 4; ++mi) {
        int row = wm + mi * 16 + lr;
        af[mi] = *(const bf16x8*)((const char*)As + row * 128 + ((kk * 64 + lk * 16) ^ ((row & 7) << 4)));
      }
#pragma unroll
      for (int ni = 0; ni < 4; ++ni) {
        int row = wn + ni * 16 + lr;
        bf[ni] = *(const bf16x8*)((const char*)Bs + row * 128 + ((kk * 64 + lk * 16) ^ ((row & 7) << 4)));
      }
#pragma unroll
      for (int mi = 0; mi < 4; ++mi)
#pragma unroll
        for (int ni = 0; ni < 4; ++ni)
          acc[mi][ni] = __builtin_amdgcn_mfma_f32_16x16x32_bf16(af[mi], bf[ni], acc[mi][ni], 0, 0, 0);
    }
  }
#pragma unroll
  for (int mi = 0; mi < 4; ++mi)
#pragma unroll
    for (int j = 0; j < 4; ++j) {
      int row = bm + wm + mi * 16 + lk * 4 + j;
#pragma unroll
      for (int ni = 0; ni < 4; ++ni) {
        int col = bn + wn + ni * 16 + lr;
        if (OUT_BF16) ((ushort*)C0)[blockIdx.z * strC + (size_t)row * ldc + col] = f2bf(acc[mi][ni][j]);
        else          ((float*)C0)[blockIdx.z * strC + (size_t)row * ldc + col]  = acc[mi][ni][j];
      }
    }
}

// ---------------------------------------------------------------------------
// transpose + f32->bf16:  dst[c][r] = src[r][c]   (R, Cc multiples of 64)
// ---------------------------------------------------------------------------
__global__ __launch_bounds__(256) void transpose_cvt(
    const float* __restrict__ src, ushort* __restrict__ dst, int R, int Cc)
{
  __shared__ float tile[64][65];
  const int r0 = blockIdx.y << 6, c0 = blockIdx.x << 6;
  const int t = threadIdx.x;
  for (int i = t; i < 1024; i += 256) {
    int r = i >> 4, c = (i & 15) << 2;
    float4 v = *(const float4*)(src + (size_t)(r0 + r) * Cc + c0 + c);
    tile[r][c] = v.x; tile[r][c+1] = v.y; tile[r][c+2] = v.z; tile[r][c+3] = v.w;
  }
  __syncthreads();
  int c = t >> 2, rb = (t & 3) << 4;
#pragma unroll
  for (int u = 0; u < 16; u += 4) {
    ushort4 o;
    o.x = f2bf(tile[rb+u+0][c]); o.y = f2bf(tile[rb+u+1][c]);
    o.z = f2bf(tile[rb+u+2][c]); o.w = f2bf(tile[rb+u+3][c]);
    *(ushort4*)(dst + (size_t)(c0 + c) * R + r0 + rb + u) = o;
  }
}

__global__ __launch_bounds__(256) void cvt_bf16(const float* __restrict__ src,
                                                ushort* __restrict__ dst)
{
  int i = blockIdx.x * 256 + threadIdx.x;
  float4 v = ((const float4*)src)[i];
  ushort4 o; o.x = f2bf(v.x); o.y = f2bf(v.y); o.z = f2bf(v.z); o.w = f2bf(v.w);
  ((ushort4*)dst)[i] = o;
}

// ---------------------------------------------------------------------------
// Candidate top-8 per sim row from bf16 sim. One wave per row (4 rows/block).
// bf16 error ~1e-3 << 4th-to-9th order-stat gap (~0.28) -> true top-4 is
// inside the candidate set. Tie-break: lower index first.
// ---------------------------------------------------------------------------
__global__ __launch_bounds__(256) void topk8(const ushort* __restrict__ sim,
                                             int* __restrict__ cand)
{
  const int row = blockIdx.x * 4 + (threadIdx.x >> 6);   // 0..8191
  const int lane = threadIdx.x & 63;
  const ushort* r = sim + (size_t)row * 2048;
  float v[8]; int ix[8];
#pragma unroll
  for (int p = 0; p < 8; ++p) { v[p] = -FLT_MAX; ix[p] = 0x7fffffff; }
  for (int j = 0; j < 32; ++j) {
    int n = lane + (j << 6);
    float val = bf2f(r[n]);
    if (val > v[7]) {
      v[7] = val; ix[7] = n;
#pragma unroll
      for (int p = 7; p > 0; --p) {
        if (v[p] > v[p-1]) {
          float tv = v[p]; v[p] = v[p-1]; v[p-1] = tv;
          int   ti = ix[p]; ix[p] = ix[p-1]; ix[p-1] = ti;
        }
      }
    }
  }
  int head = 0;
  int out[8];
#pragma unroll
  for (int r8 = 0; r8 < 8; ++r8) {
    float cv = -FLT_MAX; int ci = 0x7fffffff;
#pragma unroll
    for (int p = 0; p < 8; ++p)  // my current best = v[head] (static-index select)
      if (p == head) { cv = v[p]; ci = ix[p]; }
#pragma unroll
    for (int d = 1; d < 64; d <<= 1) {
      float ov = __shfl_xor(cv, d); int oi = __shfl_xor(ci, d);
      if (ov > cv || (ov == cv && oi < ci)) { cv = ov; ci = oi; }
    }
    out[r8] = ci;
    bool mine = false;
#pragma unroll
    for (int p = 0; p < 8; ++p) if (p == head && ix[p] == ci) mine = true;
    if (mine) head++;
  }
  if (lane == 0) {
#pragma unroll
    for (int p = 0; p < 8; ++p) cand[(size_t)row * 8 + p] = out[p];
  }
}

// ---------------------------------------------------------------------------
// Exact f32 recompute of the 8 candidates + exact top-4 select (index tie-break).
// One wave per row: lane = cand(3b) x rchunk(3b); 16 k-elems per lane.
// ---------------------------------------------------------------------------
__global__ __launch_bounds__(256) void recomp_sel(
    const float* __restrict__ vq, const float* __restrict__ vkeys,
    const int* __restrict__ cand, int* __restrict__ idxo)
{
  const int row = blockIdx.x * 4 + (threadIdx.x >> 6);
  const int hv = row >> 11, s = row & 2047;
  const int lane = threadIdx.x & 63;
  const int c = lane & 7, rc = lane >> 3;
  const int n = cand[(size_t)row * 8 + c];
  const float* vqr = vq + (size_t)s * 512 + hv * 128 + rc * 16;
  const float* vk  = vkeys + (size_t)hv * 262144 + (size_t)(rc * 16) * 2048 + n;
  float acc = 0.f;
#pragma unroll
  for (int u = 0; u < 16; ++u) acc = fmaf(vqr[u], vk[(size_t)u * 2048], acc);
  acc += __shfl_xor(acc, 8);
  acc += __shfl_xor(acc, 16);
  acc += __shfl_xor(acc, 32);
  // every lane now holds the exact sim for its candidate c
  float cv = acc; int ci = n;
  int picks[4];
#pragma unroll
  for (int p = 0; p < 4; ++p) {
    float bv = cv; int bi = ci;
#pragma unroll
    for (int d = 1; d < 8; d <<= 1) {
      float ov = __shfl_xor(bv, d); int oi = __shfl_xor(bi, d);
      if (ov > bv || (ov == bv && oi < bi)) { bv = ov; bi = oi; }
    }
    picks[p] = bi;
    if (bi == ci) cv = -FLT_MAX;   // pop winner
  }
  if (lane == 0) {
#pragma unroll
    for (int p = 0; p < 4; ++p) idxo[(size_t)row * 4 + p] = picks[p];
  }
}

// ---------------------------------------------------------------------------
__global__ __launch_bounds__(256) void gather_mul_v(const float* __restrict__ hs,
    const float* __restrict__ vemb, const int* __restrict__ idx,
    float* __restrict__ v)
{
  const int s = blockIdx.x;
  const int t = threadIdx.x;
  __shared__ int id[16];
  if (t < 16) id[t] = idx[((size_t)(t >> 2) * 2048 + s) * 4 + (t & 3)];
  __syncthreads();
  for (int j = 0; j < 2; ++j) {
    int d = (t + (j << 8)) << 2;
    float4 g = make_float4(0.f, 0.f, 0.f, 0.f);
#pragma unroll
    for (int e = 0; e < 16; ++e) {
      float4 ve = *(const float4*)(vemb + (size_t)id[e] * 2048 + d);
      g.x += ve.x; g.y += ve.y; g.z += ve.z; g.w += ve.w;
    }
    float4 hv4 = *(const float4*)(hs + (size_t)s * 2048 + d);
    *(float4*)(v + (size_t)s * 2048 + d) =
        make_float4(hv4.x*g.x, hv4.y*g.y, hv4.z*g.z, hv4.w*g.w);
  }
}

__global__ __launch_bounds__(256) void rope_q_bf(ushort* __restrict__ q,
    const float* __restrict__ cosb, const float* __restrict__ sinb)
{
  int tid = blockIdx.x * 256 + threadIdx.x;
  int d = tid & 63, h = (tid >> 6) & 15, s = tid >> 10;
  size_t base = (size_t)s * 2048 + h * 128;
  float c0 = cosb[s*128 + d],      s0 = sinb[s*128 + d];
  float c1 = cosb[s*128 + d + 64], s1 = sinb[s*128 + d + 64];
  float a = bf2f(q[base + d]), b = bf2f(q[base + d + 64]);
  q[base + d]      = f2bf(a * c0 - b * s0);
  q[base + d + 64] = f2bf(b * c1 + a * s1);
}

// ---------------------------------------------------------------------------
// MFMA flash attention (unchanged from R2).
// ---------------------------------------------------------------------------
__global__ __launch_bounds__(256) void attn_mfma(
    const ushort* __restrict__ qb, const ushort* __restrict__ kb,
    const ushort* __restrict__ vt, const float* __restrict__ amask,
    const float* __restrict__ dmask, ushort* __restrict__ ao)
{
  const int h  = blockIdx.y;
  const int q0 = blockIdx.x << 6;
  const int t  = threadIdx.x, w = t >> 6, lane = t & 63;
  const int lr = lane & 15, lk = lane >> 4;

  __shared__ ushort Qs[64 * 128];
  __shared__ ushort Ks[64 * 128];
  __shared__ ushort Vs[128 * 64];
  __shared__ ushort Ps[64 * 64];
  __shared__ float mcol[64];

#pragma unroll
  for (int qI = 0; qI < 4; ++qI) {
    int b = w * 4096 + qI * 1024 + lane * 16;
    int row = b >> 8, colb = b & 255;
    int src = colb ^ ((row & 7) << 4);
    gload_lds16((const char*)qb + ((size_t)(q0 + row) * 2048 + h * 128) * 2 + src,
                (char*)Qs + w * 4096 + qI * 1024);
  }

  float m[4], l[4];
  f32x4 acc_o[8];
#pragma unroll
  for (int j = 0; j < 4; ++j) { m[j] = -FLT_MAX; l[j] = 0.f; }
#pragma unroll
  for (int ni = 0; ni < 8; ++ni) acc_o[ni] = (f32x4){0.f, 0.f, 0.f, 0.f};

  for (int c0 = 0; c0 < 2048; c0 += 64) {
    __syncthreads();
#pragma unroll
    for (int qI = 0; qI < 4; ++qI) {
      int b = w * 4096 + qI * 1024 + lane * 16;
      int row = b >> 8, colb = b & 255;
      int src = colb ^ ((row & 7) << 4);
      gload_lds16((const char*)kb + ((size_t)(c0 + row) * 2048 + h * 128) * 2 + src,
                  (char*)Ks + w * 4096 + qI * 1024);
    }
#pragma unroll
    for (int qI = 0; qI < 4; ++qI) {
      int b = w * 4096 + qI * 1024 + lane * 16;
      int row = b >> 7, colb = b & 127;
      int src = colb ^ ((row & 7) << 4);
      gload_lds16((const char*)vt + ((size_t)(h * 128 + row) * 2048 + c0) * 2 + src,
                  (char*)Vs + w * 4096 + qI * 1024);
    }
    if (t < 64) mcol[t] = amask[c0 + t] * dmask[h * 2048 + c0 + t];
    __syncthreads();

    f32x4 sacc[4];
#pragma unroll
    for (int ni = 0; ni < 4; ++ni) sacc[ni] = (f32x4){0.f, 0.f, 0.f, 0.f};
#pragma unroll
    for (int kk = 0; kk < 4; ++kk) {
      int qrow = w * 16 + lr;
      bf16x8 a = *(const bf16x8*)((const char*)Qs + qrow * 256 + ((kk * 64 + lk * 16) ^ ((qrow & 7) << 4)));
#pragma unroll
      for (int ni = 0; ni < 4; ++ni) {
        int krow = ni * 16 + lr;
        bf16x8 bfr = *(const bf16x8*)((const char*)Ks + krow * 256 + ((kk * 64 + lk * 16) ^ ((krow & 7) << 4)));
        sacc[ni] = __builtin_amdgcn_mfma_f32_16x16x32_bf16(a, bfr, sacc[ni], 0, 0, 0);
      }
    }

#pragma unroll
    for (int j = 0; j < 4; ++j) {
      int grow = q0 + w * 16 + lk * 4 + j;
      float x[4]; float tmax = -FLT_MAX;
#pragma unroll
      for (int ni = 0; ni < 4; ++ni) {
        int c = ni * 16 + lr;
        float v = sacc[ni][j] * INV_SQRT_HD;
        if (c0 + c > grow || mcol[c] == 0.f) v = NEG_MIN;
        x[ni] = v; tmax = fmaxf(tmax, v);
      }
      tmax = fmaxf(tmax, __shfl_xor(tmax, 1));
      tmax = fmaxf(tmax, __shfl_xor(tmax, 2));
      tmax = fmaxf(tmax, __shfl_xor(tmax, 4));
      tmax = fmaxf(tmax, __shfl_xor(tmax, 8));
      float mn = fmaxf(m[j], tmax);
      float sc = __expf(m[j] - mn);
      float psum = 0.f;
      int prow = w * 16 + lk * 4 + j;
#pragma unroll
      for (int ni = 0; ni < 4; ++ni) {
        float p = __expf(x[ni] - mn);
        psum += p;
        *(ushort*)((char*)Ps + prow * 128 + ((2 * (ni * 16 + lr)) ^ ((prow & 7) << 4))) = f2bf(p);
      }
      psum += __shfl_xor(psum, 1);
      psum += __shfl_xor(psum, 2);
      psum += __shfl_xor(psum, 4);
      psum += __shfl_xor(psum, 8);
      l[j] = l[j] * sc + psum;
      m[j] = mn;
#pragma unroll
      for (int ni = 0; ni < 8; ++ni) acc_o[ni][j] *= sc;
    }
    __syncthreads();

#pragma unroll
    for (int kk = 0; kk < 2; ++kk) {
      int prow = w * 16 + lr;
      bf16x8 a = *(const bf16x8*)((const char*)Ps + prow * 128 + ((kk * 64 + lk * 16) ^ ((prow & 7) << 4)));
#pragma unroll
      for (int ni = 0; ni < 8; ++ni) {
        int vrow = ni * 16 + lr;
        bf16x8 bfr = *(const bf16x8*)((const char*)Vs + vrow * 128 + ((kk * 64 + lk * 16) ^ ((vrow & 7) << 4)));
        acc_o[ni] = __builtin_amdgcn_mfma_f32_16x16x32_bf16(a, bfr, acc_o[ni], 0, 0, 0);
      }
    }
  }

#pragma unroll
  for (int j = 0; j < 4; ++j) {
    float inv = 1.f / l[j];
    int row = q0 + w * 16 + lk * 4 + j;
#pragma unroll
    for (int ni = 0; ni < 8; ++ni)
      ao[(size_t)row * 2048 + h * 128 + ni * 16 + lr] = f2bf(acc_o[ni][j] * inv);
  }
}

// ---------------------------------------------------------------------------
extern "C" void kernel_launch(void* const* d_in, const int* in_sizes, int n_in,
                              void* d_out, int out_size, void* d_ws, size_t ws_size,
                              hipStream_t stream)
{
  const float* hs    = (const float*)d_in[0];
  const float* amask = (const float*)d_in[1];
  const float* cosb  = (const float*)d_in[2];
  const float* sinb  = (const float*)d_in[3];
  const float* dmask = (const float*)d_in[4];
  const float* Wq    = (const float*)d_in[5];
  const float* Wk    = (const float*)d_in[6];
  const float* Wvq   = (const float*)d_in[7];
  const float* vkeys = (const float*)d_in[8];
  const float* vemb  = (const float*)d_in[9];
  const float* Wo    = (const float*)d_in[10];
  float* outp = (float*)d_out;

  char* ws = (char*)d_ws;
  const size_t MB = 1048576;
  // Live-range-packed layout, high-water ~66 MB (R2 validated >= 71.4 MB).
  float*  pvq    = (float*) (ws + 0);          // [0,16M)   split-K partials
  float*  vq_f32 = (float*) (ws + 16*MB);      // [16,20M)  until recomp_sel
  ushort* vq_bf  = (ushort*)(ws + 20*MB);      // [20,22M)  until sim gemm
  ushort* vkT    = (ushort*)(ws + 22*MB);      // [22,24M)  until sim gemm
  ushort* sim_bf = (ushort*)(ws + 24*MB);      // [24,56M)  until topk8
  int*    cand   = (int*)   (ws + 56*MB);      // 256 KB    until recomp_sel
  int*    idx    = (int*)   (ws + 56*MB + 262144); // 128 KB until gather
  float*  vb     = (float*) (ws + 24*MB);      // [24,40M)  over dead sim_bf
  ushort* vt     = (ushort*)(ws + 0);          // [0,8M)    over dead pvq
  ushort* hs_bf  = (ushort*)(ws + 8*MB);       // [8,16M)   over dead pvq
  ushort* q_bf   = (ushort*)(ws + 24*MB);      // [24,32M)  over dead vb
  ushort* k_bf   = (ushort*)(ws + 32*MB);      // [32,40M)
  ushort* WqT    = (ushort*)(ws + 40*MB);      // [40,48M)
  ushort* WkT    = (ushort*)(ws + 48*MB);      // [48,56M)
  ushort* WoT    = (ushort*)(ws + 58*MB);      // [58,66M)  live to end
  ushort* ao     = (ushort*)(ws + 16*MB);      // [16,24M)  over dead vq_f32/vq_bf/vkT

  dim3 blk(256);
  // ---- routing path ----
  // vq (exact f32): split-K GEMM, 1024 blocks
  gemm_f32_sk<<<dim3(8, 32, 4), blk, 0, stream>>>(hs, 2048, Wvq, 512, pvq, 512, 2048, 512, 512);
  reduce4_cvt<<<dim3(1024), blk, 0, stream>>>(pvq, vq_f32, vq_bf);
  // v_keys -> [hv][n][k] bf16
  for (int hv = 0; hv < 4; ++hv)
    transpose_cvt<<<dim3(32, 2), blk, 0, stream>>>(vkeys + (size_t)hv * 262144,
        vkT + (size_t)hv * 262144, 128, 2048);
  // sim (bf16 MFMA, z-batched over hv)
  gemm_bf16<1><<<dim3(16, 16, 4), blk, 0, stream>>>(vq_bf, 512, vkT, 128,
      sim_bf, 2048, 128, 128, 262144, 4194304);
  // candidates + exact select
  topk8<<<dim3(2048), blk, 0, stream>>>(sim_bf, cand);
  recomp_sel<<<dim3(2048), blk, 0, stream>>>(vq_f32, vkeys, cand, idx);
  // ---- v construction ----
  gather_mul_v<<<dim3(2048), blk, 0, stream>>>(hs, vemb, idx, vb);
  transpose_cvt<<<dim3(32, 32), blk, 0, stream>>>(vb, vt, 2048, 2048);
  // ---- projections ----
  cvt_bf16<<<dim3(4096), blk, 0, stream>>>(hs, hs_bf);
  transpose_cvt<<<dim3(32, 32), blk, 0, stream>>>(Wq, WqT, 2048, 2048);
  transpose_cvt<<<dim3(32, 32), blk, 0, stream>>>(Wk, WkT, 2048, 2048);
  transpose_cvt<<<dim3(32, 32), blk, 0, stream>>>(Wo, WoT, 2048, 2048);
  gemm_bf16<1><<<dim3(16, 16, 1), blk, 0, stream>>>(hs_bf, 2048, WqT, 2048, q_bf, 2048, 2048, 0, 0, 0);
  gemm_bf16<1><<<dim3(16, 16, 1), blk, 0, stream>>>(hs_bf, 2048, WkT, 2048, k_bf, 2048, 2048, 0, 0, 0);
  rope_q_bf<<<dim3(8192), blk, 0, stream>>>(q_bf, cosb, sinb);
  // ---- attention + output projection ----
  attn_mfma<<<dim3(32, 16), blk, 0, stream>>>(q_bf, k_bf, vt, amask, dmask, ao);
  gemm_bf16<0><<<dim3(16, 16, 1), blk, 0, stream>>>(ao, 2048, WoT, 2048, outp, 2048, 2048, 0, 0, 0);
}

// Round 4
// 466.465 us; speedup vs baseline: 8.1716x; 1.0227x over previous
//
#include <hip/hip_runtime.h>
#include <float.h>

// B=1, S=2048, D=2048, H=16, HD=128, HV=4, R=128, NV=2048, K=4
#define NEG_MIN (-3.4028234663852886e38f)
#define INV_SQRT_HD 0.08838834764831845f

typedef __attribute__((ext_vector_type(8))) short bf16x8;
typedef __attribute__((ext_vector_type(8))) unsigned short u16x8;
typedef __attribute__((ext_vector_type(4))) float f32x4;

__device__ __forceinline__ void gload_lds16(const void* g, void* l) {
  __builtin_amdgcn_global_load_lds((const __attribute__((address_space(1))) void*)g,
                                   (__attribute__((address_space(3))) void*)l, 16, 0, 0);
}
__device__ __forceinline__ ushort f2bf(float x) {
  union { float f; unsigned u; } v; v.f = x;
  unsigned r = v.u + 0x7fffu + ((v.u >> 16) & 1u);   // RNE
  return (ushort)(r >> 16);
}
__device__ __forceinline__ float bf2f(ushort u) {
  union { unsigned i; float f; } v; v.i = ((unsigned)u) << 16; return v.f;
}
// VALU-speed cross-lane rotate within each 16-lane DPP row (no LDS pipe).
template<int CTRL>
__device__ __forceinline__ float dpp_ror(float x) {
  return __int_as_float(__builtin_amdgcn_mov_dpp(__float_as_int(x), CTRL, 0xF, 0xF, true));
}

// ---------------------------------------------------------------------------
// Split-K f32 GEMM, 128x128 tile, 8x8 microtile. grid=(N/128, M/128, KS).
// Exact-f32 path for vq (top-k index fidelity). Kchunk = K/KS.
// ---------------------------------------------------------------------------
__global__ __launch_bounds__(256) void gemm_f32_sk(
    const float* __restrict__ A, int lda,
    const float* __restrict__ B, int ldb,
    float* __restrict__ Cp, int ldc, int M, int N, int Kchunk)
{
  __shared__ float As[16][128];
  __shared__ float Bs[16][128];
  const int t = threadIdx.x, tx = t & 15, ty = t >> 4;
  const int bm = blockIdx.y << 7, bn = blockIdx.x << 7;
  const int k0base = blockIdx.z * Kchunk;
  float acc[8][8];
#pragma unroll
  for (int i = 0; i < 8; ++i)
#pragma unroll
    for (int j = 0; j < 8; ++j) acc[i][j] = 0.f;
  for (int k0 = 0; k0 < Kchunk; k0 += 16) {
    __syncthreads();
    for (int i = t; i < 512; i += 256) {
      int rr = i >> 2, c4 = (i & 3) << 2;
      float4 av = *(const float4*)(A + (size_t)(bm + rr) * lda + k0base + k0 + c4);
      As[c4 + 0][rr] = av.x; As[c4 + 1][rr] = av.y;
      As[c4 + 2][rr] = av.z; As[c4 + 3][rr] = av.w;
    }
    for (int i = t; i < 512; i += 256) {
      int rr = i >> 5, c4 = (i & 31) << 2;
      *(float4*)(&Bs[rr][c4]) = *(const float4*)(B + (size_t)(k0base + k0 + rr) * ldb + bn + c4);
    }
    __syncthreads();
#pragma unroll
    for (int kk = 0; kk < 16; ++kk) {
      float4 a0 = *(const float4*)(&As[kk][ty * 8]);
      float4 a1 = *(const float4*)(&As[kk][ty * 8 + 4]);
      float4 b0 = *(const float4*)(&Bs[kk][tx * 8]);
      float4 b1 = *(const float4*)(&Bs[kk][tx * 8 + 4]);
      float av[8] = {a0.x, a0.y, a0.z, a0.w, a1.x, a1.y, a1.z, a1.w};
      float bv[8] = {b0.x, b0.y, b0.z, b0.w, b1.x, b1.y, b1.z, b1.w};
#pragma unroll
      for (int i = 0; i < 8; ++i)
#pragma unroll
        for (int j = 0; j < 8; ++j)
          acc[i][j] = fmaf(av[i], bv[j], acc[i][j]);
    }
  }
  float* C = Cp + (size_t)blockIdx.z * M * N;
#pragma unroll
  for (int i = 0; i < 8; ++i) {
    int row = bm + ty * 8 + i;
#pragma unroll
    for (int j4 = 0; j4 < 8; j4 += 4)
      *(float4*)(C + (size_t)row * ldc + bn + tx * 8 + j4) =
          make_float4(acc[i][j4], acc[i][j4+1], acc[i][j4+2], acc[i][j4+3]);
  }
}

// deterministic 8-way reduce of split-K partials + bf16 copy (1M floats)
__global__ __launch_bounds__(256) void reduce8_cvt(const float* __restrict__ Cp,
    float* __restrict__ vq, ushort* __restrict__ vq_bf)
{
  int i = (blockIdx.x * 256 + threadIdx.x) << 2;
  float4 s = make_float4(0.f, 0.f, 0.f, 0.f);
#pragma unroll
  for (int z = 0; z < 8; ++z) {
    float4 a = *(const float4*)(Cp + (size_t)z * 1048576 + i);
    s.x += a.x; s.y += a.y; s.z += a.z; s.w += a.w;
  }
  *(float4*)(vq + i) = s;
  ushort4 o; o.x = f2bf(s.x); o.y = f2bf(s.y); o.z = f2bf(s.z); o.w = f2bf(s.w);
  *(ushort4*)(vq_bf + i) = o;
}

// ---------------------------------------------------------------------------
// bf16 MFMA GEMM (z-batched): C = A @ Bt^T. 128x128 tile, BK=64, 4 waves,
// 4x4 16x16x32 frags. XOR-swizzled LDS via pre-swizzled global source.
// ---------------------------------------------------------------------------
template<int OUT_BF16>
__global__ __launch_bounds__(256) void gemm_bf16(
    const ushort* __restrict__ A0, int lda,
    const ushort* __restrict__ Bt0, int ldb,
    void* __restrict__ C0, int ldc, int Kd,
    size_t strA, size_t strB, size_t strC)
{
  const ushort* A  = A0  + blockIdx.z * strA;
  const ushort* Bt = Bt0 + blockIdx.z * strB;
  __shared__ ushort As[128 * 64];
  __shared__ ushort Bs[128 * 64];
  const int t = threadIdx.x, w = t >> 6, lane = t & 63;
  const int lr = lane & 15, lk = lane >> 4;
  const int bm = blockIdx.y << 7, bn = blockIdx.x << 7;
  const int wm = (w >> 1) << 6, wn = (w & 1) << 6;
  f32x4 acc[4][4];
#pragma unroll
  for (int i = 0; i < 4; ++i)
#pragma unroll
    for (int j = 0; j < 4; ++j) acc[i][j] = (f32x4){0.f, 0.f, 0.f, 0.f};

  for (int k0 = 0; k0 < Kd; k0 += 64) {
    __syncthreads();
#pragma unroll
    for (int qI = 0; qI < 4; ++qI) {
      int b = w * 4096 + qI * 1024 + lane * 16;
      int row = b >> 7, colb = b & 127;
      int src = colb ^ ((row & 7) << 4);
      gload_lds16((const char*)A + ((size_t)(bm + row) * lda + k0) * 2 + src,
                  (char*)As + w * 4096 + qI * 1024);
    }
#pragma unroll
    for (int qI = 0; qI < 4; ++qI) {
      int b = w * 4096 + qI * 1024 + lane * 16;
      int row = b >> 7, colb = b & 127;
      int src = colb ^ ((row & 7) << 4);
      gload_lds16((const char*)Bt + ((size_t)(bn + row) * ldb + k0) * 2 + src,
                  (char*)Bs + w * 4096 + qI * 1024);
    }
    __syncthreads();
#pragma unroll
    for (int kk = 0; kk < 2; ++kk) {
      bf16x8 af[4], bf[4];
#pragma unroll
      for (int mi = 0; mi < 4; ++mi) {
        int row = wm + mi * 16 + lr;
        af[mi] = *(const bf16x8*)((const char*)As + row * 128 + ((kk * 64 + lk * 16) ^ ((row & 7) << 4)));
      }
#pragma unroll
      for (int ni = 0; ni < 4; ++ni) {
        int row = wn + ni * 16 + lr;
        bf[ni] = *(const bf16x8*)((const char*)Bs + row * 128 + ((kk * 64 + lk * 16) ^ ((row & 7) << 4)));
      }
#pragma unroll
      for (int mi = 0; mi < 4; ++mi)
#pragma unroll
        for (int ni = 0; ni < 4; ++ni)
          acc[mi][ni] = __builtin_amdgcn_mfma_f32_16x16x32_bf16(af[mi], bf[ni], acc[mi][ni], 0, 0, 0);
    }
  }
#pragma unroll
  for (int mi = 0; mi < 4; ++mi)
#pragma unroll
    for (int j = 0; j < 4; ++j) {
      int row = bm + wm + mi * 16 + lk * 4 + j;
#pragma unroll
      for (int ni = 0; ni < 4; ++ni) {
        int col = bn + wn + ni * 16 + lr;
        if (OUT_BF16) ((ushort*)C0)[blockIdx.z * strC + (size_t)row * ldc + col] = f2bf(acc[mi][ni][j]);
        else          ((float*)C0)[blockIdx.z * strC + (size_t)row * ldc + col]  = acc[mi][ni][j];
      }
    }
}

// ---------------------------------------------------------------------------
// transpose + f32->bf16:  dst[c][r] = src[r][c]
// ---------------------------------------------------------------------------
__global__ __launch_bounds__(256) void transpose_cvt(
    const float* __restrict__ src, ushort* __restrict__ dst, int R, int Cc)
{
  __shared__ float tile[64][65];
  const int r0 = blockIdx.y << 6, c0 = blockIdx.x << 6;
  const int t = threadIdx.x;
  for (int i = t; i < 1024; i += 256) {
    int r = i >> 4, c = (i & 15) << 2;
    float4 v = *(const float4*)(src + (size_t)(r0 + r) * Cc + c0 + c);
    tile[r][c] = v.x; tile[r][c+1] = v.y; tile[r][c+2] = v.z; tile[r][c+3] = v.w;
  }
  __syncthreads();
  int c = t >> 2, rb = (t & 3) << 4;
#pragma unroll
  for (int u = 0; u < 16; u += 4) {
    ushort4 o;
    o.x = f2bf(tile[rb+u+0][c]); o.y = f2bf(tile[rb+u+1][c]);
    o.z = f2bf(tile[rb+u+2][c]); o.w = f2bf(tile[rb+u+3][c]);
    *(ushort4*)(dst + (size_t)(c0 + c) * R + r0 + rb + u) = o;
  }
}

// bf16 -> bf16 transpose (2048x2048): dst[c][r] = src[r][c]
__global__ __launch_bounds__(256) void transpose_bf(
    const ushort* __restrict__ src, ushort* __restrict__ dst)
{
  __shared__ ushort tile[64][66];
  const int r0 = blockIdx.y << 6, c0 = blockIdx.x << 6;
  const int t = threadIdx.x;
  for (int i = t; i < 512; i += 256) {
    int r = i >> 3, c8 = (i & 7) << 3;
    *(u16x8*)(&tile[r][c8]) = *(const u16x8*)(src + (size_t)(r0 + r) * 2048 + c0 + c8);
  }
  __syncthreads();
  for (int i = t; i < 512; i += 256) {
    int c = i >> 3, r8 = (i & 7) << 3;
    u16x8 o;
#pragma unroll
    for (int u = 0; u < 8; ++u) o[u] = tile[r8 + u][c];
    *(u16x8*)(dst + (size_t)(c0 + c) * 2048 + r0 + r8) = o;
  }
}

__global__ __launch_bounds__(256) void cvt_bf16(const float* __restrict__ src,
                                                ushort* __restrict__ dst)
{
  int i = blockIdx.x * 256 + threadIdx.x;
  float4 v = ((const float4*)src)[i];
  ushort4 o; o.x = f2bf(v.x); o.y = f2bf(v.y); o.z = f2bf(v.z); o.w = f2bf(v.w);
  ((ushort4*)dst)[i] = o;
}

// ---------------------------------------------------------------------------
// Candidate top-8 per sim row from bf16 sim (wave per row).
// ---------------------------------------------------------------------------
__global__ __launch_bounds__(256) void topk8(const ushort* __restrict__ sim,
                                             int* __restrict__ cand)
{
  const int row = blockIdx.x * 4 + (threadIdx.x >> 6);
  const int lane = threadIdx.x & 63;
  const ushort* r = sim + (size_t)row * 2048;
  float v[8]; int ix[8];
#pragma unroll
  for (int p = 0; p < 8; ++p) { v[p] = -FLT_MAX; ix[p] = 0x7fffffff; }
  for (int j = 0; j < 32; ++j) {
    int n = lane + (j << 6);
    float val = bf2f(r[n]);
    if (val > v[7]) {
      v[7] = val; ix[7] = n;
#pragma unroll
      for (int p = 7; p > 0; --p) {
        if (v[p] > v[p-1]) {
          float tv = v[p]; v[p] = v[p-1]; v[p-1] = tv;
          int   ti = ix[p]; ix[p] = ix[p-1]; ix[p-1] = ti;
        }
      }
    }
  }
  int head = 0;
  int out[8];
#pragma unroll
  for (int r8 = 0; r8 < 8; ++r8) {
    float cv = -FLT_MAX; int ci = 0x7fffffff;
#pragma unroll
    for (int p = 0; p < 8; ++p)
      if (p == head) { cv = v[p]; ci = ix[p]; }
#pragma unroll
    for (int d = 1; d < 64; d <<= 1) {
      float ov = __shfl_xor(cv, d); int oi = __shfl_xor(ci, d);
      if (ov > cv || (ov == cv && oi < ci)) { cv = ov; ci = oi; }
    }
    out[r8] = ci;
    bool mine = false;
#pragma unroll
    for (int p = 0; p < 8; ++p) if (p == head && ix[p] == ci) mine = true;
    if (mine) head++;
  }
  if (lane == 0) {
#pragma unroll
    for (int p = 0; p < 8; ++p) cand[(size_t)row * 8 + p] = out[p];
  }
}

// ---------------------------------------------------------------------------
// Exact f32 recompute of 8 candidates + exact top-4 (index tie-break).
// ---------------------------------------------------------------------------
__global__ __launch_bounds__(256) void recomp_sel(
    const float* __restrict__ vq, const float* __restrict__ vkeys,
    const int* __restrict__ cand, int* __restrict__ idxo)
{
  const int row = blockIdx.x * 4 + (threadIdx.x >> 6);
  const int hv = row >> 11, s = row & 2047;
  const int lane = threadIdx.x & 63;
  const int c = lane & 7, rc = lane >> 3;
  const int n = cand[(size_t)row * 8 + c];
  const float* vqr = vq + (size_t)s * 512 + hv * 128 + rc * 16;
  const float* vk  = vkeys + (size_t)hv * 262144 + (size_t)(rc * 16) * 2048 + n;
  float acc = 0.f;
#pragma unroll
  for (int u = 0; u < 16; ++u) acc = fmaf(vqr[u], vk[(size_t)u * 2048], acc);
  acc += __shfl_xor(acc, 8);
  acc += __shfl_xor(acc, 16);
  acc += __shfl_xor(acc, 32);
  float cv = acc; int ci = n;
  int picks[4];
#pragma unroll
  for (int p = 0; p < 4; ++p) {
    float bv = cv; int bi = ci;
#pragma unroll
    for (int d = 1; d < 8; d <<= 1) {
      float ov = __shfl_xor(bv, d); int oi = __shfl_xor(bi, d);
      if (ov > bv || (ov == bv && oi < bi)) { bv = ov; bi = oi; }
    }
    picks[p] = bi;
    if (bi == ci) cv = -FLT_MAX;
  }
  if (lane == 0) {
#pragma unroll
    for (int p = 0; p < 4; ++p) idxo[(size_t)row * 4 + p] = picks[p];
  }
}

// ---------------------------------------------------------------------------
// v[s][:] = hs[s][:] * sum of 16 gathered v_embed rows (bf16 table) -> bf16
// ---------------------------------------------------------------------------
__global__ __launch_bounds__(256) void gather_mul_bf(const float* __restrict__ hs,
    const ushort* __restrict__ vemb_bf, const int* __restrict__ idx,
    ushort* __restrict__ vb)
{
  const int s = blockIdx.x;
  const int t = threadIdx.x;
  __shared__ int id[16];
  if (t < 16) id[t] = idx[((size_t)(t >> 2) * 2048 + s) * 4 + (t & 3)];
  __syncthreads();
  int d0 = t << 3;
  float g[8] = {0.f, 0.f, 0.f, 0.f, 0.f, 0.f, 0.f, 0.f};
#pragma unroll
  for (int e = 0; e < 16; ++e) {
    u16x8 ve = *(const u16x8*)(vemb_bf + (size_t)id[e] * 2048 + d0);
#pragma unroll
    for (int u = 0; u < 8; ++u) g[u] += bf2f(ve[u]);
  }
  float4 h0 = *(const float4*)(hs + (size_t)s * 2048 + d0);
  float4 h1 = *(const float4*)(hs + (size_t)s * 2048 + d0 + 4);
  float hv[8] = {h0.x, h0.y, h0.z, h0.w, h1.x, h1.y, h1.z, h1.w};
  u16x8 o;
#pragma unroll
  for (int u = 0; u < 8; ++u) o[u] = f2bf(hv[u] * g[u]);
  *(u16x8*)(vb + (size_t)s * 2048 + d0) = o;
}

// vmean partials: part[(h*8+chunk)*128+d] = sum over 256 s-rows of v[s][h*128+d]
__global__ __launch_bounds__(256) void vmean_part(const ushort* __restrict__ vb,
                                                  float* __restrict__ part)
{
  const int h = blockIdx.y, chunk = blockIdx.x;
  const int t = threadIdx.x, d = t & 127, half = t >> 7;
  float s = 0.f;
  int r0 = chunk * 256 + half * 128;
  for (int r = r0; r < r0 + 128; ++r)
    s += bf2f(vb[(size_t)r * 2048 + h * 128 + d]);
  __shared__ float red[256];
  red[t] = s;
  __syncthreads();
  if (t < 128) part[(size_t)(h * 8 + chunk) * 128 + d] = red[t] + red[t + 128];
}

// vmean[h*128+d] = (1/2048) * sum_chunk part  ;  i0[h] = first col with mask!=0
__global__ __launch_bounds__(128) void vmean_fin(const float* __restrict__ part,
                                                 float* __restrict__ vmean)
{
  const int h = blockIdx.x, d = threadIdx.x;
  float s = 0.f;
#pragma unroll
  for (int c = 0; c < 8; ++c) s += part[(size_t)(h * 8 + c) * 128 + d];
  vmean[h * 128 + d] = s * (1.f / 2048.f);
}

__global__ __launch_bounds__(256) void i0_scan(const float* __restrict__ amask,
    const float* __restrict__ dmask, int* __restrict__ i0)
{
  const int h = blockIdx.x, t = threadIdx.x;
  int best = 0x7fffffff;
  for (int j = t; j < 2048; j += 256) {
    if (amask[j] * dmask[h * 2048 + j] != 0.f) { best = j; break; }
  }
  __shared__ int red[256];
  red[t] = best;
  __syncthreads();
  for (int off = 128; off > 0; off >>= 1) {
    if (t < off) red[t] = min(red[t], red[t + off]);
    __syncthreads();
  }
  if (t == 0) i0[h] = red[0];
}

// RoPE on bf16 q (row stride ld), in place
__global__ __launch_bounds__(256) void rope_q_bf(ushort* __restrict__ q,
    const float* __restrict__ cosb, const float* __restrict__ sinb, int ld)
{
  int tid = blockIdx.x * 256 + threadIdx.x;
  int d = tid & 63, h = (tid >> 6) & 15, s = tid >> 10;
  size_t base = (size_t)s * ld + h * 128;
  float c0 = cosb[s*128 + d],      s0 = sinb[s*128 + d];
  float c1 = cosb[s*128 + d + 64], s1 = sinb[s*128 + d + 64];
  float a = bf2f(q[base + d]), b = bf2f(q[base + d + 64]);
  q[base + d]      = f2bf(a * c0 - b * s0);
  q[base + d + 64] = f2bf(b * c1 + a * s1);
}

// ---------------------------------------------------------------------------
// MFMA flash attention with causal tile skip + uniform-row closed form.
// q/k row stride 4096 (fused qk buffer). DPP row_ror reductions (VALU pipe).
// ---------------------------------------------------------------------------
#define QLD 4096
__global__ __launch_bounds__(256) void attn_mfma(
    const ushort* __restrict__ qb, const ushort* __restrict__ kb,
    const ushort* __restrict__ vt, const float* __restrict__ amask,
    const float* __restrict__ dmask, const float* __restrict__ vmean,
    const int* __restrict__ i0, ushort* __restrict__ ao)
{
  const int h  = blockIdx.y;
  const int q0 = blockIdx.x << 6;
  const int t  = threadIdx.x, w = t >> 6, lane = t & 63;
  const int lr = lane & 15, lk = lane >> 4;

  __shared__ ushort Qs[64 * 128];
  __shared__ ushort Ks[64 * 128];
  __shared__ ushort Vs[128 * 64];
  __shared__ ushort Ps[64 * 64];
  __shared__ float mcol[64];

#pragma unroll
  for (int qI = 0; qI < 4; ++qI) {
    int b = w * 4096 + qI * 1024 + lane * 16;
    int row = b >> 8, colb = b & 255;
    int src = colb ^ ((row & 7) << 4);
    gload_lds16((const char*)qb + ((size_t)(q0 + row) * QLD + h * 128) * 2 + src,
                (char*)Qs + w * 4096 + qI * 1024);
  }

  float m[4], l[4];
  f32x4 acc_o[8];
#pragma unroll
  for (int j = 0; j < 4; ++j) { m[j] = -FLT_MAX; l[j] = 0.f; }
#pragma unroll
  for (int ni = 0; ni < 8; ++ni) acc_o[ni] = (f32x4){0.f, 0.f, 0.f, 0.f};

  const int ctiles = (q0 >> 6) + 1;   // causal: tiles with c0 <= q0 only
  for (int ct = 0; ct < ctiles; ++ct) {
    const int c0 = ct << 6;
    __syncthreads();
#pragma unroll
    for (int qI = 0; qI < 4; ++qI) {
      int b = w * 4096 + qI * 1024 + lane * 16;
      int row = b >> 8, colb = b & 255;
      int src = colb ^ ((row & 7) << 4);
      gload_lds16((const char*)kb + ((size_t)(c0 + row) * QLD + h * 128) * 2 + src,
                  (char*)Ks + w * 4096 + qI * 1024);
    }
#pragma unroll
    for (int qI = 0; qI < 4; ++qI) {
      int b = w * 4096 + qI * 1024 + lane * 16;
      int row = b >> 7, colb = b & 127;
      int src = colb ^ ((row & 7) << 4);
      gload_lds16((const char*)vt + ((size_t)(h * 128 + row) * 2048 + c0) * 2 + src,
                  (char*)Vs + w * 4096 + qI * 1024);
    }
    if (t < 64) mcol[t] = amask[c0 + t] * dmask[h * 2048 + c0 + t];
    __syncthreads();

    // ---- S = Q K^T
    f32x4 sacc[4];
#pragma unroll
    for (int ni = 0; ni < 4; ++ni) sacc[ni] = (f32x4){0.f, 0.f, 0.f, 0.f};
#pragma unroll
    for (int kk = 0; kk < 4; ++kk) {
      int qrow = w * 16 + lr;
      bf16x8 a = *(const bf16x8*)((const char*)Qs + qrow * 256 + ((kk * 64 + lk * 16) ^ ((qrow & 7) << 4)));
#pragma unroll
      for (int ni = 0; ni < 4; ++ni) {
        int krow = ni * 16 + lr;
        bf16x8 bfr = *(const bf16x8*)((const char*)Ks + krow * 256 + ((kk * 64 + lk * 16) ^ ((krow & 7) << 4)));
        sacc[ni] = __builtin_amdgcn_mfma_f32_16x16x32_bf16(a, bfr, sacc[ni], 0, 0, 0);
      }
    }

    // ---- mask + online softmax (DPP row reductions, conditional rescale)
#pragma unroll
    for (int j = 0; j < 4; ++j) {
      int grow = q0 + w * 16 + lk * 4 + j;
      float x[4]; float tmax = -FLT_MAX;
#pragma unroll
      for (int ni = 0; ni < 4; ++ni) {
        int c = ni * 16 + lr;
        float v = sacc[ni][j] * INV_SQRT_HD;
        if (c0 + c > grow || mcol[c] == 0.f) v = NEG_MIN;
        x[ni] = v; tmax = fmaxf(tmax, v);
      }
      tmax = fmaxf(tmax, dpp_ror<0x121>(tmax));
      tmax = fmaxf(tmax, dpp_ror<0x122>(tmax));
      tmax = fmaxf(tmax, dpp_ror<0x124>(tmax));
      tmax = fmaxf(tmax, dpp_ror<0x128>(tmax));
      float mn = fmaxf(m[j], tmax);
      float psum = 0.f;
      int prow = w * 16 + lk * 4 + j;
#pragma unroll
      for (int ni = 0; ni < 4; ++ni) {
        float p = __expf(x[ni] - mn);
        psum += p;
        *(ushort*)((char*)Ps + prow * 128 + ((2 * (ni * 16 + lr)) ^ ((prow & 7) << 4))) = f2bf(p);
      }
      psum += dpp_ror<0x121>(psum);
      psum += dpp_ror<0x122>(psum);
      psum += dpp_ror<0x124>(psum);
      psum += dpp_ror<0x128>(psum);
      if (mn > m[j]) {               // rescale only when the max grew
        float sc = __expf(m[j] - mn);
        l[j] *= sc;
#pragma unroll
        for (int ni = 0; ni < 8; ++ni) acc_o[ni][j] *= sc;
        m[j] = mn;
      }
      l[j] += psum;
    }
    // Ps/Vs produced and consumed by the same wave / already synced; PV next.

    // ---- O += P V
#pragma unroll
    for (int kk = 0; kk < 2; ++kk) {
      int prow = w * 16 + lr;
      bf16x8 a = *(const bf16x8*)((const char*)Ps + prow * 128 + ((kk * 64 + lk * 16) ^ ((prow & 7) << 4)));
#pragma unroll
      for (int ni = 0; ni < 8; ++ni) {
        int vrow = ni * 16 + lr;
        bf16x8 bfr = *(const bf16x8*)((const char*)Vs + vrow * 128 + ((kk * 64 + lk * 16) ^ ((vrow & 7) << 4)));
        acc_o[ni] = __builtin_amdgcn_mfma_f32_16x16x32_bf16(a, bfr, acc_o[ni], 0, 0, 0);
      }
    }
  }

  const int i0h = i0[h];
#pragma unroll
  for (int j = 0; j < 4; ++j) {
    int row = q0 + w * 16 + lk * 4 + j;
    if (row < i0h) {
      // fully-masked row: softmax uniform over ALL 2048 cols -> mean(V)
#pragma unroll
      for (int ni = 0; ni < 8; ++ni)
        ao[(size_t)row * 2048 + h * 128 + ni * 16 + lr] = f2bf(vmean[h * 128 + ni * 16 + lr]);
    } else {
      float inv = 1.f / l[j];
#pragma unroll
      for (int ni = 0; ni < 8; ++ni)
        ao[(size_t)row * 2048 + h * 128 + ni * 16 + lr] = f2bf(acc_o[ni][j] * inv);
    }
  }
}

// ---------------------------------------------------------------------------
extern "C" void kernel_launch(void* const* d_in, const int* in_sizes, int n_in,
                              void* d_out, int out_size, void* d_ws, size_t ws_size,
                              hipStream_t stream)
{
  const float* hs    = (const float*)d_in[0];
  const float* amask = (const float*)d_in[1];
  const float* cosb  = (const float*)d_in[2];
  const float* sinb  = (const float*)d_in[3];
  const float* dmask = (const float*)d_in[4];
  const float* Wq    = (const float*)d_in[5];
  const float* Wk    = (const float*)d_in[6];
  const float* Wvq   = (const float*)d_in[7];
  const float* vkeys = (const float*)d_in[8];
  const float* vemb  = (const float*)d_in[9];
  const float* Wo    = (const float*)d_in[10];
  float* outp = (float*)d_out;

  char* ws = (char*)d_ws;
  const size_t MB = 1048576;
  // Live-range-packed; high-water 64 MB.
  float*  pvq     = (float*) (ws + 0);            // [0,32)  split-K partials
  float*  vq_f32  = (float*) (ws + 32*MB);        // [32,36) until recomp_sel
  ushort* vq_bf   = (ushort*)(ws + 36*MB);        // [36,38) until sim gemm
  ushort* vkT     = (ushort*)(ws + 38*MB);        // [38,40) until sim gemm
  int*    cand    = (int*)   (ws + 40*MB);        // 256 KB  until recomp_sel
  int*    idx     = (int*)   (ws + 40*MB + 262144); // 128 KB until gather
  float*  part    = (float*) (ws + 41*MB);        // 64 KB
  float*  vmean   = (float*) (ws + 41*MB + 65536);// 8 KB    live to attn
  int*    i0b     = (int*)   (ws + 41*MB + 73728);// 64 B    live to attn
  ushort* sim_bf  = (ushort*)(ws + 0);            // [0,32)  over dead pvq
  ushort* vb      = (ushort*)(ws + 0);            // [0,8)   over dead sim_bf
  ushort* vt      = (ushort*)(ws + 8*MB);         // [8,16)
  ushort* hs_bf   = (ushort*)(ws + 16*MB);        // [16,24)
  ushort* qkC     = (ushort*)(ws + 24*MB);        // [24,40) fused q|k, ld 4096
  ushort* vemb_bf = (ushort*)(ws + 48*MB);        // [48,56) until gather
  ushort* WBig    = (ushort*)(ws + 48*MB);        // [48,64) over dead vemb_bf
  ushort* WoT     = (ushort*)(ws + 48*MB);        // [48,56) over dead WBig
  ushort* ao      = (ushort*)(ws + 0);            // [0,8)   over dead vb

  dim3 blk(256);
  // ---- routing path ----
  gemm_f32_sk<<<dim3(4, 16, 8), blk, 0, stream>>>(hs, 2048, Wvq, 512, pvq, 512, 2048, 512, 256);
  reduce8_cvt<<<dim3(1024), blk, 0, stream>>>(pvq, vq_f32, vq_bf);
  for (int hv = 0; hv < 4; ++hv)
    transpose_cvt<<<dim3(32, 2), blk, 0, stream>>>(vkeys + (size_t)hv * 262144,
        vkT + (size_t)hv * 262144, 128, 2048);
  gemm_bf16<1><<<dim3(16, 16, 4), blk, 0, stream>>>(vq_bf, 512, vkT, 128,
      sim_bf, 2048, 128, 128, 262144, 4194304);
  topk8<<<dim3(2048), blk, 0, stream>>>(sim_bf, cand);
  recomp_sel<<<dim3(2048), blk, 0, stream>>>(vq_f32, vkeys, cand, idx);
  // ---- v construction (bf16 gather) ----
  cvt_bf16<<<dim3(4096), blk, 0, stream>>>(vemb, vemb_bf);
  gather_mul_bf<<<dim3(2048), blk, 0, stream>>>(hs, vemb_bf, idx, vb);
  transpose_bf<<<dim3(32, 32), blk, 0, stream>>>(vb, vt);
  vmean_part<<<dim3(8, 16), blk, 0, stream>>>(vb, part);
  vmean_fin<<<dim3(16), dim3(128), 0, stream>>>(part, vmean);
  i0_scan<<<dim3(16), blk, 0, stream>>>(amask, dmask, i0b);
  // ---- projections (fused q|k) ----
  cvt_bf16<<<dim3(4096), blk, 0, stream>>>(hs, hs_bf);
  transpose_cvt<<<dim3(32, 32), blk, 0, stream>>>(Wq, WBig, 2048, 2048);
  transpose_cvt<<<dim3(32, 32), blk, 0, stream>>>(Wk, WBig + (size_t)2048 * 2048, 2048, 2048);
  gemm_bf16<1><<<dim3(32, 16, 1), blk, 0, stream>>>(hs_bf, 2048, WBig, 2048, qkC, 4096, 2048, 0, 0, 0);
  rope_q_bf<<<dim3(8192), blk, 0, stream>>>(qkC, cosb, sinb, 4096);
  // ---- attention ----
  transpose_cvt<<<dim3(32, 32), blk, 0, stream>>>(Wo, WoT, 2048, 2048);
  attn_mfma<<<dim3(32, 16), blk, 0, stream>>>(qkC, qkC + 2048, vt, amask, dmask, vmean, i0b, ao);
  // ---- output projection ----
  gemm_bf16<0><<<dim3(16, 16, 1), blk, 0, stream>>>(ao, 2048, WoT, 2048, outp, 2048, 2048, 0, 0, 0);
}

// Round 5
// 432.825 us; speedup vs baseline: 8.8067x; 1.0777x over previous
//
#include <hip/hip_runtime.h>
#include <float.h>

// B=1, S=2048, D=2048, H=16, HD=128, HV=4, R=128, NV=2048, K=4
#define NEG_MIN (-3.4028234663852886e38f)
#define INV_SQRT_HD 0.08838834764831845f

typedef __attribute__((ext_vector_type(8))) short bf16x8;
typedef __attribute__((ext_vector_type(8))) unsigned short u16x8;
typedef __attribute__((ext_vector_type(4))) float f32x4;

__device__ __forceinline__ void gload_lds16(const void* g, void* l) {
  __builtin_amdgcn_global_load_lds((const __attribute__((address_space(1))) void*)g,
                                   (__attribute__((address_space(3))) void*)l, 16, 0, 0);
}
__device__ __forceinline__ ushort f2bf(float x) {
  union { float f; unsigned u; } v; v.f = x;
  unsigned r = v.u + 0x7fffu + ((v.u >> 16) & 1u);   // RNE
  return (ushort)(r >> 16);
}
__device__ __forceinline__ float bf2f(ushort u) {
  union { unsigned i; float f; } v; v.i = ((unsigned)u) << 16; return v.f;
}
template<int CTRL>
__device__ __forceinline__ float dpp_ror(float x) {
  return __int_as_float(__builtin_amdgcn_mov_dpp(__float_as_int(x), CTRL, 0xF, 0xF, true));
}

// ---------------------------------------------------------------------------
// Split-K f32 GEMM, 128x128 tile, 8x8 microtile (exact vq path).
// ---------------------------------------------------------------------------
__global__ __launch_bounds__(256) void gemm_f32_sk(
    const float* __restrict__ A, int lda,
    const float* __restrict__ B, int ldb,
    float* __restrict__ Cp, int ldc, int M, int N, int Kchunk)
{
  __shared__ float As[16][128];
  __shared__ float Bs[16][128];
  const int t = threadIdx.x, tx = t & 15, ty = t >> 4;
  const int bm = blockIdx.y << 7, bn = blockIdx.x << 7;
  const int k0base = blockIdx.z * Kchunk;
  float acc[8][8];
#pragma unroll
  for (int i = 0; i < 8; ++i)
#pragma unroll
    for (int j = 0; j < 8; ++j) acc[i][j] = 0.f;
  for (int k0 = 0; k0 < Kchunk; k0 += 16) {
    __syncthreads();
    for (int i = t; i < 512; i += 256) {
      int rr = i >> 2, c4 = (i & 3) << 2;
      float4 av = *(const float4*)(A + (size_t)(bm + rr) * lda + k0base + k0 + c4);
      As[c4 + 0][rr] = av.x; As[c4 + 1][rr] = av.y;
      As[c4 + 2][rr] = av.z; As[c4 + 3][rr] = av.w;
    }
    for (int i = t; i < 512; i += 256) {
      int rr = i >> 5, c4 = (i & 31) << 2;
      *(float4*)(&Bs[rr][c4]) = *(const float4*)(B + (size_t)(k0base + k0 + rr) * ldb + bn + c4);
    }
    __syncthreads();
#pragma unroll
    for (int kk = 0; kk < 16; ++kk) {
      float4 a0 = *(const float4*)(&As[kk][ty * 8]);
      float4 a1 = *(const float4*)(&As[kk][ty * 8 + 4]);
      float4 b0 = *(const float4*)(&Bs[kk][tx * 8]);
      float4 b1 = *(const float4*)(&Bs[kk][tx * 8 + 4]);
      float av[8] = {a0.x, a0.y, a0.z, a0.w, a1.x, a1.y, a1.z, a1.w};
      float bv[8] = {b0.x, b0.y, b0.z, b0.w, b1.x, b1.y, b1.z, b1.w};
#pragma unroll
      for (int i = 0; i < 8; ++i)
#pragma unroll
        for (int j = 0; j < 8; ++j)
          acc[i][j] = fmaf(av[i], bv[j], acc[i][j]);
    }
  }
  float* C = Cp + (size_t)blockIdx.z * M * N;
#pragma unroll
  for (int i = 0; i < 8; ++i) {
    int row = bm + ty * 8 + i;
#pragma unroll
    for (int j4 = 0; j4 < 8; j4 += 4)
      *(float4*)(C + (size_t)row * ldc + bn + tx * 8 + j4) =
          make_float4(acc[i][j4], acc[i][j4+1], acc[i][j4+2], acc[i][j4+3]);
  }
}

__global__ __launch_bounds__(256) void reduce8_cvt(const float* __restrict__ Cp,
    float* __restrict__ vq, ushort* __restrict__ vq_bf)
{
  int i = (blockIdx.x * 256 + threadIdx.x) << 2;
  float4 s = make_float4(0.f, 0.f, 0.f, 0.f);
#pragma unroll
  for (int z = 0; z < 8; ++z) {
    float4 a = *(const float4*)(Cp + (size_t)z * 1048576 + i);
    s.x += a.x; s.y += a.y; s.z += a.z; s.w += a.w;
  }
  *(float4*)(vq + i) = s;
  ushort4 o; o.x = f2bf(s.x); o.y = f2bf(s.y); o.z = f2bf(s.z); o.w = f2bf(s.w);
  *(ushort4*)(vq_bf + i) = o;
}

// ---------------------------------------------------------------------------
// bf16 MFMA GEMM (z-batched): C = A @ Bt^T. 128x128 tile, BK=64.
// ---------------------------------------------------------------------------
template<int OUT_BF16>
__global__ __launch_bounds__(256) void gemm_bf16(
    const ushort* __restrict__ A0, int lda,
    const ushort* __restrict__ Bt0, int ldb,
    void* __restrict__ C0, int ldc, int Kd,
    size_t strA, size_t strB, size_t strC)
{
  const ushort* A  = A0  + blockIdx.z * strA;
  const ushort* Bt = Bt0 + blockIdx.z * strB;
  __shared__ ushort As[128 * 64];
  __shared__ ushort Bs[128 * 64];
  const int t = threadIdx.x, w = t >> 6, lane = t & 63;
  const int lr = lane & 15, lk = lane >> 4;
  const int bm = blockIdx.y << 7, bn = blockIdx.x << 7;
  const int wm = (w >> 1) << 6, wn = (w & 1) << 6;
  f32x4 acc[4][4];
#pragma unroll
  for (int i = 0; i < 4; ++i)
#pragma unroll
    for (int j = 0; j < 4; ++j) acc[i][j] = (f32x4){0.f, 0.f, 0.f, 0.f};

  for (int k0 = 0; k0 < Kd; k0 += 64) {
    __syncthreads();
#pragma unroll
    for (int qI = 0; qI < 4; ++qI) {
      int b = w * 4096 + qI * 1024 + lane * 16;
      int row = b >> 7, colb = b & 127;
      int src = colb ^ ((row & 7) << 4);
      gload_lds16((const char*)A + ((size_t)(bm + row) * lda + k0) * 2 + src,
                  (char*)As + w * 4096 + qI * 1024);
    }
#pragma unroll
    for (int qI = 0; qI < 4; ++qI) {
      int b = w * 4096 + qI * 1024 + lane * 16;
      int row = b >> 7, colb = b & 127;
      int src = colb ^ ((row & 7) << 4);
      gload_lds16((const char*)Bt + ((size_t)(bn + row) * ldb + k0) * 2 + src,
                  (char*)Bs + w * 4096 + qI * 1024);
    }
    __syncthreads();
#pragma unroll
    for (int kk = 0; kk < 2; ++kk) {
      bf16x8 af[4], bf[4];
#pragma unroll
      for (int mi = 0; mi < 4; ++mi) {
        int row = wm + mi * 16 + lr;
        af[mi] = *(const bf16x8*)((const char*)As + row * 128 + ((kk * 64 + lk * 16) ^ ((row & 7) << 4)));
      }
#pragma unroll
      for (int ni = 0; ni < 4; ++ni) {
        int row = wn + ni * 16 + lr;
        bf[ni] = *(const bf16x8*)((const char*)Bs + row * 128 + ((kk * 64 + lk * 16) ^ ((row & 7) << 4)));
      }
#pragma unroll
      for (int mi = 0; mi < 4; ++mi)
#pragma unroll
        for (int ni = 0; ni < 4; ++ni)
          acc[mi][ni] = __builtin_amdgcn_mfma_f32_16x16x32_bf16(af[mi], bf[ni], acc[mi][ni], 0, 0, 0);
    }
  }
#pragma unroll
  for (int mi = 0; mi < 4; ++mi)
#pragma unroll
    for (int j = 0; j < 4; ++j) {
      int row = bm + wm + mi * 16 + lk * 4 + j;
#pragma unroll
      for (int ni = 0; ni < 4; ++ni) {
        int col = bn + wn + ni * 16 + lr;
        if (OUT_BF16) ((ushort*)C0)[blockIdx.z * strC + (size_t)row * ldc + col] = f2bf(acc[mi][ni][j]);
        else          ((float*)C0)[blockIdx.z * strC + (size_t)row * ldc + col]  = acc[mi][ni][j];
      }
    }
}

// ---------------------------------------------------------------------------
// transpose + f32->bf16 (z-batched): dst[c][r] = src[r][c]
// ---------------------------------------------------------------------------
__global__ __launch_bounds__(256) void transpose_cvt(
    const float* __restrict__ src0, ushort* __restrict__ dst0, int R, int Cc,
    size_t zsrc, size_t zdst)
{
  const float* src = src0 + blockIdx.z * zsrc;
  ushort* dst = dst0 + blockIdx.z * zdst;
  __shared__ float tile[64][65];
  const int r0 = blockIdx.y << 6, c0 = blockIdx.x << 6;
  const int t = threadIdx.x;
  for (int i = t; i < 1024; i += 256) {
    int r = i >> 4, c = (i & 15) << 2;
    float4 v = *(const float4*)(src + (size_t)(r0 + r) * Cc + c0 + c);
    tile[r][c] = v.x; tile[r][c+1] = v.y; tile[r][c+2] = v.z; tile[r][c+3] = v.w;
  }
  __syncthreads();
  int c = t >> 2, rb = (t & 3) << 4;
#pragma unroll
  for (int u = 0; u < 16; u += 4) {
    ushort4 o;
    o.x = f2bf(tile[rb+u+0][c]); o.y = f2bf(tile[rb+u+1][c]);
    o.z = f2bf(tile[rb+u+2][c]); o.w = f2bf(tile[rb+u+3][c]);
    *(ushort4*)(dst + (size_t)(c0 + c) * R + r0 + rb + u) = o;
  }
}

// bf16 -> bf16 transpose (2048x2048)
__global__ __launch_bounds__(256) void transpose_bf(
    const ushort* __restrict__ src, ushort* __restrict__ dst)
{
  __shared__ ushort tile[64][66];
  const int r0 = blockIdx.y << 6, c0 = blockIdx.x << 6;
  const int t = threadIdx.x;
  for (int i = t; i < 512; i += 256) {
    int r = i >> 3, c8 = (i & 7) << 3;
    *(u16x8*)(&tile[r][c8]) = *(const u16x8*)(src + (size_t)(r0 + r) * 2048 + c0 + c8);
  }
  __syncthreads();
  for (int i = t; i < 512; i += 256) {
    int c = i >> 3, r8 = (i & 7) << 3;
    u16x8 o;
#pragma unroll
    for (int u = 0; u < 8; ++u) o[u] = tile[r8 + u][c];
    *(u16x8*)(dst + (size_t)(c0 + c) * 2048 + r0 + r8) = o;
  }
}

// two f32->bf16 conversions in one launch (4M elems each)
__global__ __launch_bounds__(256) void cvt2_bf16(const float* __restrict__ srcA,
    ushort* __restrict__ dstA, const float* __restrict__ srcB,
    ushort* __restrict__ dstB)
{
  int gid = blockIdx.x * 256 + threadIdx.x;
  const float* s; ushort* d; int i;
  if (gid < 1048576) { s = srcA; d = dstA; i = gid; }
  else               { s = srcB; d = dstB; i = gid - 1048576; }
  float4 v = ((const float4*)s)[i];
  ushort4 o; o.x = f2bf(v.x); o.y = f2bf(v.y); o.z = f2bf(v.z); o.w = f2bf(v.w);
  ((ushort4*)d)[i] = o;
}

// ---------------------------------------------------------------------------
// Candidate top-8 per sim row from bf16 sim (wave per row).
// ---------------------------------------------------------------------------
__global__ __launch_bounds__(256) void topk8(const ushort* __restrict__ sim,
                                             int* __restrict__ cand)
{
  const int row = blockIdx.x * 4 + (threadIdx.x >> 6);
  const int lane = threadIdx.x & 63;
  const ushort* r = sim + (size_t)row * 2048;
  float v[8]; int ix[8];
#pragma unroll
  for (int p = 0; p < 8; ++p) { v[p] = -FLT_MAX; ix[p] = 0x7fffffff; }
  for (int j = 0; j < 32; ++j) {
    int n = lane + (j << 6);
    float val = bf2f(r[n]);
    if (val > v[7]) {
      v[7] = val; ix[7] = n;
#pragma unroll
      for (int p = 7; p > 0; --p) {
        if (v[p] > v[p-1]) {
          float tv = v[p]; v[p] = v[p-1]; v[p-1] = tv;
          int   ti = ix[p]; ix[p] = ix[p-1]; ix[p-1] = ti;
        }
      }
    }
  }
  int head = 0;
  int out[8];
#pragma unroll
  for (int r8 = 0; r8 < 8; ++r8) {
    float cv = -FLT_MAX; int ci = 0x7fffffff;
#pragma unroll
    for (int p = 0; p < 8; ++p)
      if (p == head) { cv = v[p]; ci = ix[p]; }
#pragma unroll
    for (int d = 1; d < 64; d <<= 1) {
      float ov = __shfl_xor(cv, d); int oi = __shfl_xor(ci, d);
      if (ov > cv || (ov == cv && oi < ci)) { cv = ov; ci = oi; }
    }
    out[r8] = ci;
    bool mine = false;
#pragma unroll
    for (int p = 0; p < 8; ++p) if (p == head && ix[p] == ci) mine = true;
    if (mine) head++;
  }
  if (lane == 0) {
#pragma unroll
    for (int p = 0; p < 8; ++p) cand[(size_t)row * 8 + p] = out[p];
  }
}

// ---------------------------------------------------------------------------
// Exact f32 recompute of 8 candidates + exact top-4 (index tie-break).
// ---------------------------------------------------------------------------
__global__ __launch_bounds__(256) void recomp_sel(
    const float* __restrict__ vq, const float* __restrict__ vkeys,
    const int* __restrict__ cand, int* __restrict__ idxo)
{
  const int row = blockIdx.x * 4 + (threadIdx.x >> 6);
  const int hv = row >> 11, s = row & 2047;
  const int lane = threadIdx.x & 63;
  const int c = lane & 7, rc = lane >> 3;
  const int n = cand[(size_t)row * 8 + c];
  const float* vqr = vq + (size_t)s * 512 + hv * 128 + rc * 16;
  const float* vk  = vkeys + (size_t)hv * 262144 + (size_t)(rc * 16) * 2048 + n;
  float acc = 0.f;
#pragma unroll
  for (int u = 0; u < 16; ++u) acc = fmaf(vqr[u], vk[(size_t)u * 2048], acc);
  acc += __shfl_xor(acc, 8);
  acc += __shfl_xor(acc, 16);
  acc += __shfl_xor(acc, 32);
  float cv = acc; int ci = n;
  int picks[4];
#pragma unroll
  for (int p = 0; p < 4; ++p) {
    float bv = cv; int bi = ci;
#pragma unroll
    for (int d = 1; d < 8; d <<= 1) {
      float ov = __shfl_xor(bv, d); int oi = __shfl_xor(bi, d);
      if (ov > bv || (ov == bv && oi < bi)) { bv = ov; bi = oi; }
    }
    picks[p] = bi;
    if (bi == ci) cv = -FLT_MAX;
  }
  if (lane == 0) {
#pragma unroll
    for (int p = 0; p < 4; ++p) idxo[(size_t)row * 4 + p] = picks[p];
  }
}

// ---------------------------------------------------------------------------
__global__ __launch_bounds__(256) void gather_mul_bf(const float* __restrict__ hs,
    const ushort* __restrict__ vemb_bf, const int* __restrict__ idx,
    ushort* __restrict__ vb)
{
  const int s = blockIdx.x;
  const int t = threadIdx.x;
  __shared__ int id[16];
  if (t < 16) id[t] = idx[((size_t)(t >> 2) * 2048 + s) * 4 + (t & 3)];
  __syncthreads();
  int d0 = t << 3;
  float g[8] = {0.f, 0.f, 0.f, 0.f, 0.f, 0.f, 0.f, 0.f};
#pragma unroll
  for (int e = 0; e < 16; ++e) {
    u16x8 ve = *(const u16x8*)(vemb_bf + (size_t)id[e] * 2048 + d0);
#pragma unroll
    for (int u = 0; u < 8; ++u) g[u] += bf2f(ve[u]);
  }
  float4 h0 = *(const float4*)(hs + (size_t)s * 2048 + d0);
  float4 h1 = *(const float4*)(hs + (size_t)s * 2048 + d0 + 4);
  float hv[8] = {h0.x, h0.y, h0.z, h0.w, h1.x, h1.y, h1.z, h1.w};
  u16x8 o;
#pragma unroll
  for (int u = 0; u < 8; ++u) o[u] = f2bf(hv[u] * g[u]);
  *(u16x8*)(vb + (size_t)s * 2048 + d0) = o;
}

__global__ __launch_bounds__(256) void vmean_part(const ushort* __restrict__ vb,
                                                  float* __restrict__ part)
{
  const int h = blockIdx.y, chunk = blockIdx.x;
  const int t = threadIdx.x, d = t & 127, half = t >> 7;
  float s = 0.f;
  int r0 = chunk * 256 + half * 128;
  for (int r = r0; r < r0 + 128; ++r)
    s += bf2f(vb[(size_t)r * 2048 + h * 128 + d]);
  __shared__ float red[256];
  red[t] = s;
  __syncthreads();
  if (t < 128) part[(size_t)(h * 8 + chunk) * 128 + d] = red[t] + red[t + 128];
}

__global__ __launch_bounds__(128) void vmean_fin(const float* __restrict__ part,
                                                 float* __restrict__ vmean)
{
  const int h = blockIdx.x, d = threadIdx.x;
  float s = 0.f;
#pragma unroll
  for (int c = 0; c < 8; ++c) s += part[(size_t)(h * 8 + c) * 128 + d];
  vmean[h * 128 + d] = s * (1.f / 2048.f);
}

__global__ __launch_bounds__(256) void i0_scan(const float* __restrict__ amask,
    const float* __restrict__ dmask, int* __restrict__ i0)
{
  const int h = blockIdx.x, t = threadIdx.x;
  int best = 0x7fffffff;
  for (int j = t; j < 2048; j += 256) {
    if (amask[j] * dmask[h * 2048 + j] != 0.f) { best = j; break; }
  }
  __shared__ int red[256];
  red[t] = best;
  __syncthreads();
  for (int off = 128; off > 0; off >>= 1) {
    if (t < off) red[t] = min(red[t], red[t + off]);
    __syncthreads();
  }
  if (t == 0) i0[h] = red[0];
}

__global__ __launch_bounds__(256) void rope_q_bf(ushort* __restrict__ q,
    const float* __restrict__ cosb, const float* __restrict__ sinb, int ld)
{
  int tid = blockIdx.x * 256 + threadIdx.x;
  int d = tid & 63, h = (tid >> 6) & 15, s = tid >> 10;
  size_t base = (size_t)s * ld + h * 128;
  float c0 = cosb[s*128 + d],      s0 = sinb[s*128 + d];
  float c1 = cosb[s*128 + d + 64], s1 = sinb[s*128 + d + 64];
  float a = bf2f(q[base + d]), b = bf2f(q[base + d + 64]);
  q[base + d]      = f2bf(a * c0 - b * s0);
  q[base + d + 64] = f2bf(b * c1 + a * s1);
}

// ---------------------------------------------------------------------------
// MFMA flash attention, stripe-paired (balanced 33 tiles/block), K/V
// double-buffered with prefetch-before-compute, Q in registers.
// Block = pair p: stripes p and 31-p of one head, sequential. 256 blocks.
// ---------------------------------------------------------------------------
#define QLD 4096
__global__ __launch_bounds__(256) void attn_mfma(
    const ushort* __restrict__ qb, const ushort* __restrict__ kb,
    const ushort* __restrict__ vt, const float* __restrict__ amask,
    const float* __restrict__ dmask, const float* __restrict__ vmean,
    const int* __restrict__ i0, ushort* __restrict__ ao)
{
  const int h  = blockIdx.y;
  const int pr = blockIdx.x;                 // pair 0..15
  const int t  = threadIdx.x, w = t >> 6, lane = t & 63;
  const int lr = lane & 15, lk = lane >> 4;

  __shared__ ushort Ks[2][64 * 128];   // [buf][64 rows][256B], swizzled
  __shared__ ushort Vs[2][128 * 64];   // [buf][128 d][128B]
  __shared__ ushort Ps[64 * 64];

  const int i0h = i0[h];

  for (int sp = 0; sp < 2; ++sp) {
    const int stripe = (sp == 0) ? pr : 31 - pr;
    const int q0 = stripe << 6;
    const int ntiles = stripe + 1;

    __syncthreads();   // protect LDS from previous stripe's readers

    // Q fragments in registers (wave w owns rows q0+w*16..+15)
    const int qrow = q0 + w * 16 + lr;
    bf16x8 qf[4];
#pragma unroll
    for (int kk = 0; kk < 4; ++kk)
      qf[kk] = *(const bf16x8*)(qb + (size_t)qrow * QLD + h * 128 + kk * 32 + lk * 8);

    // stage K/V tile 0 into buf 0
#pragma unroll
    for (int qI = 0; qI < 4; ++qI) {
      int b = w * 4096 + qI * 1024 + lane * 16;
      int row = b >> 8, colb = b & 255;
      int src = colb ^ ((row & 7) << 4);
      gload_lds16((const char*)kb + ((size_t)row * QLD + h * 128) * 2 + src,
                  (char*)Ks[0] + w * 4096 + qI * 1024);
    }
#pragma unroll
    for (int qI = 0; qI < 4; ++qI) {
      int b = w * 4096 + qI * 1024 + lane * 16;
      int row = b >> 7, colb = b & 127;
      int src = colb ^ ((row & 7) << 4);
      gload_lds16((const char*)vt + ((size_t)(h * 128 + row) * 2048) * 2 + src,
                  (char*)Vs[0] + w * 4096 + qI * 1024);
    }

    float m[4], l[4];
    f32x4 acc_o[8];
#pragma unroll
    for (int j = 0; j < 4; ++j) { m[j] = -FLT_MAX; l[j] = 0.f; }
#pragma unroll
    for (int ni = 0; ni < 8; ++ni) acc_o[ni] = (f32x4){0.f, 0.f, 0.f, 0.f};

    int cur = 0;
    for (int ct = 0; ct < ntiles; ++ct) {
      const int c0 = ct << 6;
      __syncthreads();   // implicit vmcnt(0): buf[cur] loaded; prev compute done

      // mask columns -> registers (issued before next-tile stage loads)
      float mreg[4];
#pragma unroll
      for (int ni = 0; ni < 4; ++ni) {
        int c = c0 + ni * 16 + lr;
        mreg[ni] = amask[c] * dmask[h * 2048 + c];
      }

      // prefetch next tile into the other buffer (overlaps compute below)
      if (ct + 1 < ntiles) {
        const int cn = c0 + 64;
        const int nb = cur ^ 1;
#pragma unroll
        for (int qI = 0; qI < 4; ++qI) {
          int b = w * 4096 + qI * 1024 + lane * 16;
          int row = b >> 8, colb = b & 255;
          int src = colb ^ ((row & 7) << 4);
          gload_lds16((const char*)kb + ((size_t)(cn + row) * QLD + h * 128) * 2 + src,
                      (char*)Ks[nb] + w * 4096 + qI * 1024);
        }
#pragma unroll
        for (int qI = 0; qI < 4; ++qI) {
          int b = w * 4096 + qI * 1024 + lane * 16;
          int row = b >> 7, colb = b & 127;
          int src = colb ^ ((row & 7) << 4);
          gload_lds16((const char*)vt + ((size_t)(h * 128 + row) * 2048 + cn) * 2 + src,
                      (char*)Vs[nb] + w * 4096 + qI * 1024);
        }
      }

      // ---- S = Q K^T
      f32x4 sacc[4];
#pragma unroll
      for (int ni = 0; ni < 4; ++ni) sacc[ni] = (f32x4){0.f, 0.f, 0.f, 0.f};
#pragma unroll
      for (int kk = 0; kk < 4; ++kk) {
#pragma unroll
        for (int ni = 0; ni < 4; ++ni) {
          int krow = ni * 16 + lr;
          bf16x8 bfr = *(const bf16x8*)((const char*)Ks[cur] + krow * 256 + ((kk * 64 + lk * 16) ^ ((krow & 7) << 4)));
          sacc[ni] = __builtin_amdgcn_mfma_f32_16x16x32_bf16(qf[kk], bfr, sacc[ni], 0, 0, 0);
        }
      }

      // ---- mask + online softmax (DPP row reductions)
#pragma unroll
      for (int j = 0; j < 4; ++j) {
        int grow = q0 + w * 16 + lk * 4 + j;
        float x[4]; float tmax = -FLT_MAX;
#pragma unroll
        for (int ni = 0; ni < 4; ++ni) {
          int c = ni * 16 + lr;
          float v = sacc[ni][j] * INV_SQRT_HD;
          if (c0 + c > grow || mreg[ni] == 0.f) v = NEG_MIN;
          x[ni] = v; tmax = fmaxf(tmax, v);
        }
        tmax = fmaxf(tmax, dpp_ror<0x121>(tmax));
        tmax = fmaxf(tmax, dpp_ror<0x122>(tmax));
        tmax = fmaxf(tmax, dpp_ror<0x124>(tmax));
        tmax = fmaxf(tmax, dpp_ror<0x128>(tmax));
        float mn = fmaxf(m[j], tmax);
        float psum = 0.f;
        int prow = w * 16 + lk * 4 + j;
#pragma unroll
        for (int ni = 0; ni < 4; ++ni) {
          float p = __expf(x[ni] - mn);
          psum += p;
          *(ushort*)((char*)Ps + prow * 128 + ((2 * (ni * 16 + lr)) ^ ((prow & 7) << 4))) = f2bf(p);
        }
        psum += dpp_ror<0x121>(psum);
        psum += dpp_ror<0x122>(psum);
        psum += dpp_ror<0x124>(psum);
        psum += dpp_ror<0x128>(psum);
        if (mn > m[j]) {
          float sc = __expf(m[j] - mn);
          l[j] *= sc;
#pragma unroll
          for (int ni = 0; ni < 8; ++ni) acc_o[ni][j] *= sc;
          m[j] = mn;
        }
        l[j] += psum;
      }

      // ---- O += P V (same-wave Ps rows; no barrier needed)
#pragma unroll
      for (int kk = 0; kk < 2; ++kk) {
        int prow = w * 16 + lr;
        bf16x8 a = *(const bf16x8*)((const char*)Ps + prow * 128 + ((kk * 64 + lk * 16) ^ ((prow & 7) << 4)));
#pragma unroll
        for (int ni = 0; ni < 8; ++ni) {
          int vrow = ni * 16 + lr;
          bf16x8 bfr = *(const bf16x8*)((const char*)Vs[cur] + vrow * 128 + ((kk * 64 + lk * 16) ^ ((vrow & 7) << 4)));
          acc_o[ni] = __builtin_amdgcn_mfma_f32_16x16x32_bf16(a, bfr, acc_o[ni], 0, 0, 0);
        }
      }
      cur ^= 1;
    }

    // ---- epilogue for this stripe
#pragma unroll
    for (int j = 0; j < 4; ++j) {
      int row = q0 + w * 16 + lk * 4 + j;
      if (row < i0h) {
#pragma unroll
        for (int ni = 0; ni < 8; ++ni)
          ao[(size_t)row * 2048 + h * 128 + ni * 16 + lr] = f2bf(vmean[h * 128 + ni * 16 + lr]);
      } else {
        float inv = 1.f / l[j];
#pragma unroll
        for (int ni = 0; ni < 8; ++ni)
          ao[(size_t)row * 2048 + h * 128 + ni * 16 + lr] = f2bf(acc_o[ni][j] * inv);
      }
    }
  }
}

// ---------------------------------------------------------------------------
extern "C" void kernel_launch(void* const* d_in, const int* in_sizes, int n_in,
                              void* d_out, int out_size, void* d_ws, size_t ws_size,
                              hipStream_t stream)
{
  const float* hs    = (const float*)d_in[0];
  const float* amask = (const float*)d_in[1];
  const float* cosb  = (const float*)d_in[2];
  const float* sinb  = (const float*)d_in[3];
  const float* dmask = (const float*)d_in[4];
  const float* Wq    = (const float*)d_in[5];
  const float* Wk    = (const float*)d_in[6];
  const float* Wvq   = (const float*)d_in[7];
  const float* vkeys = (const float*)d_in[8];
  const float* vemb  = (const float*)d_in[9];
  const float* Wo    = (const float*)d_in[10];
  float* outp = (float*)d_out;

  char* ws = (char*)d_ws;
  const size_t MB = 1048576;
  float*  pvq     = (float*) (ws + 0);              // [0,32)
  float*  vq_f32  = (float*) (ws + 32*MB);          // [32,36)
  ushort* vq_bf   = (ushort*)(ws + 36*MB);          // [36,38)
  ushort* vkT     = (ushort*)(ws + 38*MB);          // [38,40)
  int*    cand    = (int*)   (ws + 40*MB);          // 256 KB
  int*    idx     = (int*)   (ws + 40*MB + 262144); // 128 KB
  float*  part    = (float*) (ws + 41*MB);          // 64 KB
  float*  vmean   = (float*) (ws + 41*MB + 65536);  // 8 KB
  int*    i0b     = (int*)   (ws + 41*MB + 73728);  // 64 B
  ushort* sim_bf  = (ushort*)(ws + 0);              // over dead pvq
  ushort* vb      = (ushort*)(ws + 0);
  ushort* vt      = (ushort*)(ws + 8*MB);
  ushort* hs_bf   = (ushort*)(ws + 16*MB);
  ushort* qkC     = (ushort*)(ws + 24*MB);          // fused q|k, ld 4096
  ushort* vemb_bf = (ushort*)(ws + 48*MB);
  ushort* WBig    = (ushort*)(ws + 48*MB);
  ushort* WoT     = (ushort*)(ws + 48*MB);
  ushort* ao      = (ushort*)(ws + 0);

  dim3 blk(256);
  // ---- routing path ----
  gemm_f32_sk<<<dim3(4, 16, 8), blk, 0, stream>>>(hs, 2048, Wvq, 512, pvq, 512, 2048, 512, 256);
  reduce8_cvt<<<dim3(1024), blk, 0, stream>>>(pvq, vq_f32, vq_bf);
  transpose_cvt<<<dim3(32, 2, 4), blk, 0, stream>>>(vkeys, vkT, 128, 2048, 262144, 262144);
  gemm_bf16<1><<<dim3(16, 16, 4), blk, 0, stream>>>(vq_bf, 512, vkT, 128,
      sim_bf, 2048, 128, 128, 262144, 4194304);
  topk8<<<dim3(2048), blk, 0, stream>>>(sim_bf, cand);
  recomp_sel<<<dim3(2048), blk, 0, stream>>>(vq_f32, vkeys, cand, idx);
  // ---- v construction ----
  cvt2_bf16<<<dim3(8192), blk, 0, stream>>>(vemb, vemb_bf, hs, hs_bf);
  gather_mul_bf<<<dim3(2048), blk, 0, stream>>>(hs, vemb_bf, idx, vb);
  transpose_bf<<<dim3(32, 32), blk, 0, stream>>>(vb, vt);
  vmean_part<<<dim3(8, 16), blk, 0, stream>>>(vb, part);
  vmean_fin<<<dim3(16), dim3(128), 0, stream>>>(part, vmean);
  i0_scan<<<dim3(16), blk, 0, stream>>>(amask, dmask, i0b);
  // ---- projections (fused q|k) ----
  transpose_cvt<<<dim3(32, 32, 1), blk, 0, stream>>>(Wq, WBig, 2048, 2048, 0, 0);
  transpose_cvt<<<dim3(32, 32, 1), blk, 0, stream>>>(Wk, WBig + (size_t)2048 * 2048, 2048, 2048, 0, 0);
  gemm_bf16<1><<<dim3(32, 16, 1), blk, 0, stream>>>(hs_bf, 2048, WBig, 2048, qkC, 4096, 2048, 0, 0, 0);
  rope_q_bf<<<dim3(8192), blk, 0, stream>>>(qkC, cosb, sinb, 4096);
  // ---- attention ----
  transpose_cvt<<<dim3(32, 32, 1), blk, 0, stream>>>(Wo, WoT, 2048, 2048, 0, 0);
  attn_mfma<<<dim3(16, 16), blk, 0, stream>>>(qkC, qkC + 2048, vt, amask, dmask, vmean, i0b, ao);
  // ---- output projection ----
  gemm_bf16<0><<<dim3(16, 16, 1), blk, 0, stream>>>(ao, 2048, WoT, 2048, outp, 2048, 2048, 0, 0, 0);
}

// Round 6
// 411.802 us; speedup vs baseline: 9.2563x; 1.0511x over previous
//
#include <hip/hip_runtime.h>
#include <float.h>

// B=1, S=2048, D=2048, H=16, HD=128, HV=4, R=128, NV=2048, K=4
#define NEG_MIN (-3.4028234663852886e38f)
#define INV_SQRT_HD 0.08838834764831845f

typedef __attribute__((ext_vector_type(8))) short bf16x8;
typedef __attribute__((ext_vector_type(8))) unsigned short u16x8;
typedef __attribute__((ext_vector_type(4))) float f32x4;

__device__ __forceinline__ void gload_lds16(const void* g, void* l) {
  __builtin_amdgcn_global_load_lds((const __attribute__((address_space(1))) void*)g,
                                   (__attribute__((address_space(3))) void*)l, 16, 0, 0);
}
__device__ __forceinline__ ushort f2bf(float x) {
  union { float f; unsigned u; } v; v.f = x;
  unsigned r = v.u + 0x7fffu + ((v.u >> 16) & 1u);   // RNE
  return (ushort)(r >> 16);
}
__device__ __forceinline__ float bf2f(ushort u) {
  union { unsigned i; float f; } v; v.i = ((unsigned)u) << 16; return v.f;
}
template<int CTRL>
__device__ __forceinline__ float dpp_ror(float x) {
  return __int_as_float(__builtin_amdgcn_mov_dpp(__float_as_int(x), CTRL, 0xF, 0xF, true));
}

// ---------------------------------------------------------------------------
// Split-K f32 GEMM, 128x128 tile, 8x8 microtile (exact vq path).
// ---------------------------------------------------------------------------
__global__ __launch_bounds__(256) void gemm_f32_sk(
    const float* __restrict__ A, int lda,
    const float* __restrict__ B, int ldb,
    float* __restrict__ Cp, int ldc, int M, int N, int Kchunk)
{
  __shared__ float As[16][128];
  __shared__ float Bs[16][128];
  const int t = threadIdx.x, tx = t & 15, ty = t >> 4;
  const int bm = blockIdx.y << 7, bn = blockIdx.x << 7;
  const int k0base = blockIdx.z * Kchunk;
  float acc[8][8];
#pragma unroll
  for (int i = 0; i < 8; ++i)
#pragma unroll
    for (int j = 0; j < 8; ++j) acc[i][j] = 0.f;
  for (int k0 = 0; k0 < Kchunk; k0 += 16) {
    __syncthreads();
    for (int i = t; i < 512; i += 256) {
      int rr = i >> 2, c4 = (i & 3) << 2;
      float4 av = *(const float4*)(A + (size_t)(bm + rr) * lda + k0base + k0 + c4);
      As[c4 + 0][rr] = av.x; As[c4 + 1][rr] = av.y;
      As[c4 + 2][rr] = av.z; As[c4 + 3][rr] = av.w;
    }
    for (int i = t; i < 512; i += 256) {
      int rr = i >> 5, c4 = (i & 31) << 2;
      *(float4*)(&Bs[rr][c4]) = *(const float4*)(B + (size_t)(k0base + k0 + rr) * ldb + bn + c4);
    }
    __syncthreads();
#pragma unroll
    for (int kk = 0; kk < 16; ++kk) {
      float4 a0 = *(const float4*)(&As[kk][ty * 8]);
      float4 a1 = *(const float4*)(&As[kk][ty * 8 + 4]);
      float4 b0 = *(const float4*)(&Bs[kk][tx * 8]);
      float4 b1 = *(const float4*)(&Bs[kk][tx * 8 + 4]);
      float av[8] = {a0.x, a0.y, a0.z, a0.w, a1.x, a1.y, a1.z, a1.w};
      float bv[8] = {b0.x, b0.y, b0.z, b0.w, b1.x, b1.y, b1.z, b1.w};
#pragma unroll
      for (int i = 0; i < 8; ++i)
#pragma unroll
        for (int j = 0; j < 8; ++j)
          acc[i][j] = fmaf(av[i], bv[j], acc[i][j]);
    }
  }
  float* C = Cp + (size_t)blockIdx.z * M * N;
#pragma unroll
  for (int i = 0; i < 8; ++i) {
    int row = bm + ty * 8 + i;
#pragma unroll
    for (int j4 = 0; j4 < 8; j4 += 4)
      *(float4*)(C + (size_t)row * ldc + bn + tx * 8 + j4) =
          make_float4(acc[i][j4], acc[i][j4+1], acc[i][j4+2], acc[i][j4+3]);
  }
}

__global__ __launch_bounds__(256) void reduce8_cvt(const float* __restrict__ Cp,
    float* __restrict__ vq, ushort* __restrict__ vq_bf)
{
  int i = (blockIdx.x * 256 + threadIdx.x) << 2;
  float4 s = make_float4(0.f, 0.f, 0.f, 0.f);
#pragma unroll
  for (int z = 0; z < 8; ++z) {
    float4 a = *(const float4*)(Cp + (size_t)z * 1048576 + i);
    s.x += a.x; s.y += a.y; s.z += a.z; s.w += a.w;
  }
  *(float4*)(vq + i) = s;
  ushort4 o; o.x = f2bf(s.x); o.y = f2bf(s.y); o.z = f2bf(s.z); o.w = f2bf(s.w);
  *(ushort4*)(vq_bf + i) = o;
}

// ---------------------------------------------------------------------------
// bf16 MFMA GEMM (z-batched): C = A @ Bt^T. 128x128 tile, BK=64.
// ---------------------------------------------------------------------------
template<int OUT_BF16>
__global__ __launch_bounds__(256) void gemm_bf16(
    const ushort* __restrict__ A0, int lda,
    const ushort* __restrict__ Bt0, int ldb,
    void* __restrict__ C0, int ldc, int Kd,
    size_t strA, size_t strB, size_t strC)
{
  const ushort* A  = A0  + blockIdx.z * strA;
  const ushort* Bt = Bt0 + blockIdx.z * strB;
  __shared__ ushort As[128 * 64];
  __shared__ ushort Bs[128 * 64];
  const int t = threadIdx.x, w = t >> 6, lane = t & 63;
  const int lr = lane & 15, lk = lane >> 4;
  const int bm = blockIdx.y << 7, bn = blockIdx.x << 7;
  const int wm = (w >> 1) << 6, wn = (w & 1) << 6;
  f32x4 acc[4][4];
#pragma unroll
  for (int i = 0; i < 4; ++i)
#pragma unroll
    for (int j = 0; j < 4; ++j) acc[i][j] = (f32x4){0.f, 0.f, 0.f, 0.f};

  for (int k0 = 0; k0 < Kd; k0 += 64) {
    __syncthreads();
#pragma unroll
    for (int qI = 0; qI < 4; ++qI) {
      int b = w * 4096 + qI * 1024 + lane * 16;
      int row = b >> 7, colb = b & 127;
      int src = colb ^ ((row & 7) << 4);
      gload_lds16((const char*)A + ((size_t)(bm + row) * lda + k0) * 2 + src,
                  (char*)As + w * 4096 + qI * 1024);
    }
#pragma unroll
    for (int qI = 0; qI < 4; ++qI) {
      int b = w * 4096 + qI * 1024 + lane * 16;
      int row = b >> 7, colb = b & 127;
      int src = colb ^ ((row & 7) << 4);
      gload_lds16((const char*)Bt + ((size_t)(bn + row) * ldb + k0) * 2 + src,
                  (char*)Bs + w * 4096 + qI * 1024);
    }
    __syncthreads();
#pragma unroll
    for (int kk = 0; kk < 2; ++kk) {
      bf16x8 af[4], bf[4];
#pragma unroll
      for (int mi = 0; mi < 4; ++mi) {
        int row = wm + mi * 16 + lr;
        af[mi] = *(const bf16x8*)((const char*)As + row * 128 + ((kk * 64 + lk * 16) ^ ((row & 7) << 4)));
      }
#pragma unroll
      for (int ni = 0; ni < 4; ++ni) {
        int row = wn + ni * 16 + lr;
        bf[ni] = *(const bf16x8*)((const char*)Bs + row * 128 + ((kk * 64 + lk * 16) ^ ((row & 7) << 4)));
      }
#pragma unroll
      for (int mi = 0; mi < 4; ++mi)
#pragma unroll
        for (int ni = 0; ni < 4; ++ni)
          acc[mi][ni] = __builtin_amdgcn_mfma_f32_16x16x32_bf16(af[mi], bf[ni], acc[mi][ni], 0, 0, 0);
    }
  }
#pragma unroll
  for (int mi = 0; mi < 4; ++mi)
#pragma unroll
    for (int j = 0; j < 4; ++j) {
      int row = bm + wm + mi * 16 + lk * 4 + j;
#pragma unroll
      for (int ni = 0; ni < 4; ++ni) {
        int col = bn + wn + ni * 16 + lr;
        if (OUT_BF16) ((ushort*)C0)[blockIdx.z * strC + (size_t)row * ldc + col] = f2bf(acc[mi][ni][j]);
        else          ((float*)C0)[blockIdx.z * strC + (size_t)row * ldc + col]  = acc[mi][ni][j];
      }
    }
}

// ---------------------------------------------------------------------------
// transpose + f32->bf16 (z-batched): dst[c][r] = src[r][c]
// ---------------------------------------------------------------------------
__global__ __launch_bounds__(256) void transpose_cvt(
    const float* __restrict__ src0, ushort* __restrict__ dst0, int R, int Cc,
    size_t zsrc, size_t zdst)
{
  const float* src = src0 + blockIdx.z * zsrc;
  ushort* dst = dst0 + blockIdx.z * zdst;
  __shared__ float tile[64][65];
  const int r0 = blockIdx.y << 6, c0 = blockIdx.x << 6;
  const int t = threadIdx.x;
  for (int i = t; i < 1024; i += 256) {
    int r = i >> 4, c = (i & 15) << 2;
    float4 v = *(const float4*)(src + (size_t)(r0 + r) * Cc + c0 + c);
    tile[r][c] = v.x; tile[r][c+1] = v.y; tile[r][c+2] = v.z; tile[r][c+3] = v.w;
  }
  __syncthreads();
  int c = t >> 2, rb = (t & 3) << 4;
#pragma unroll
  for (int u = 0; u < 16; u += 4) {
    ushort4 o;
    o.x = f2bf(tile[rb+u+0][c]); o.y = f2bf(tile[rb+u+1][c]);
    o.z = f2bf(tile[rb+u+2][c]); o.w = f2bf(tile[rb+u+3][c]);
    *(ushort4*)(dst + (size_t)(c0 + c) * R + r0 + rb + u) = o;
  }
}

// bf16 -> bf16 transpose (2048x2048)
__global__ __launch_bounds__(256) void transpose_bf(
    const ushort* __restrict__ src, ushort* __restrict__ dst)
{
  __shared__ ushort tile[64][66];
  const int r0 = blockIdx.y << 6, c0 = blockIdx.x << 6;
  const int t = threadIdx.x;
  for (int i = t; i < 512; i += 256) {
    int r = i >> 3, c8 = (i & 7) << 3;
    *(u16x8*)(&tile[r][c8]) = *(const u16x8*)(src + (size_t)(r0 + r) * 2048 + c0 + c8);
  }
  __syncthreads();
  for (int i = t; i < 512; i += 256) {
    int c = i >> 3, r8 = (i & 7) << 3;
    u16x8 o;
#pragma unroll
    for (int u = 0; u < 8; ++u) o[u] = tile[r8 + u][c];
    *(u16x8*)(dst + (size_t)(c0 + c) * 2048 + r0 + r8) = o;
  }
}

// two f32->bf16 conversions in one launch (4M elems each)
__global__ __launch_bounds__(256) void cvt2_bf16(const float* __restrict__ srcA,
    ushort* __restrict__ dstA, const float* __restrict__ srcB,
    ushort* __restrict__ dstB)
{
  int gid = blockIdx.x * 256 + threadIdx.x;
  const float* s; ushort* d; int i;
  if (gid < 1048576) { s = srcA; d = dstA; i = gid; }
  else               { s = srcB; d = dstB; i = gid - 1048576; }
  float4 v = ((const float4*)s)[i];
  ushort4 o; o.x = f2bf(v.x); o.y = f2bf(v.y); o.z = f2bf(v.z); o.w = f2bf(v.w);
  ((ushort4*)d)[i] = o;
}

// ---------------------------------------------------------------------------
// Candidate top-8 per sim row from bf16 sim (wave per row).
// ---------------------------------------------------------------------------
__global__ __launch_bounds__(256) void topk8(const ushort* __restrict__ sim,
                                             int* __restrict__ cand)
{
  const int row = blockIdx.x * 4 + (threadIdx.x >> 6);
  const int lane = threadIdx.x & 63;
  const ushort* r = sim + (size_t)row * 2048;
  float v[8]; int ix[8];
#pragma unroll
  for (int p = 0; p < 8; ++p) { v[p] = -FLT_MAX; ix[p] = 0x7fffffff; }
  for (int j = 0; j < 32; ++j) {
    int n = lane + (j << 6);
    float val = bf2f(r[n]);
    if (val > v[7]) {
      v[7] = val; ix[7] = n;
#pragma unroll
      for (int p = 7; p > 0; --p) {
        if (v[p] > v[p-1]) {
          float tv = v[p]; v[p] = v[p-1]; v[p-1] = tv;
          int   ti = ix[p]; ix[p] = ix[p-1]; ix[p-1] = ti;
        }
      }
    }
  }
  int head = 0;
  int out[8];
#pragma unroll
  for (int r8 = 0; r8 < 8; ++r8) {
    float cv = -FLT_MAX; int ci = 0x7fffffff;
#pragma unroll
    for (int p = 0; p < 8; ++p)
      if (p == head) { cv = v[p]; ci = ix[p]; }
#pragma unroll
    for (int d = 1; d < 64; d <<= 1) {
      float ov = __shfl_xor(cv, d); int oi = __shfl_xor(ci, d);
      if (ov > cv || (ov == cv && oi < ci)) { cv = ov; ci = oi; }
    }
    out[r8] = ci;
    bool mine = false;
#pragma unroll
    for (int p = 0; p < 8; ++p) if (p == head && ix[p] == ci) mine = true;
    if (mine) head++;
  }
  if (lane == 0) {
#pragma unroll
    for (int p = 0; p < 8; ++p) cand[(size_t)row * 8 + p] = out[p];
  }
}

// ---------------------------------------------------------------------------
// Exact f32 recompute of 8 candidates + exact top-4 (index tie-break).
// ---------------------------------------------------------------------------
__global__ __launch_bounds__(256) void recomp_sel(
    const float* __restrict__ vq, const float* __restrict__ vkeys,
    const int* __restrict__ cand, int* __restrict__ idxo)
{
  const int row = blockIdx.x * 4 + (threadIdx.x >> 6);
  const int hv = row >> 11, s = row & 2047;
  const int lane = threadIdx.x & 63;
  const int c = lane & 7, rc = lane >> 3;
  const int n = cand[(size_t)row * 8 + c];
  const float* vqr = vq + (size_t)s * 512 + hv * 128 + rc * 16;
  const float* vk  = vkeys + (size_t)hv * 262144 + (size_t)(rc * 16) * 2048 + n;
  float acc = 0.f;
#pragma unroll
  for (int u = 0; u < 16; ++u) acc = fmaf(vqr[u], vk[(size_t)u * 2048], acc);
  acc += __shfl_xor(acc, 8);
  acc += __shfl_xor(acc, 16);
  acc += __shfl_xor(acc, 32);
  float cv = acc; int ci = n;
  int picks[4];
#pragma unroll
  for (int p = 0; p < 4; ++p) {
    float bv = cv; int bi = ci;
#pragma unroll
    for (int d = 1; d < 8; d <<= 1) {
      float ov = __shfl_xor(bv, d); int oi = __shfl_xor(bi, d);
      if (ov > bv || (ov == bv && oi < bi)) { bv = ov; bi = oi; }
    }
    picks[p] = bi;
    if (bi == ci) cv = -FLT_MAX;
  }
  if (lane == 0) {
#pragma unroll
    for (int p = 0; p < 4; ++p) idxo[(size_t)row * 4 + p] = picks[p];
  }
}

// ---------------------------------------------------------------------------
__global__ __launch_bounds__(256) void gather_mul_bf(const float* __restrict__ hs,
    const ushort* __restrict__ vemb_bf, const int* __restrict__ idx,
    ushort* __restrict__ vb)
{
  const int s = blockIdx.x;
  const int t = threadIdx.x;
  __shared__ int id[16];
  if (t < 16) id[t] = idx[((size_t)(t >> 2) * 2048 + s) * 4 + (t & 3)];
  __syncthreads();
  int d0 = t << 3;
  float g[8] = {0.f, 0.f, 0.f, 0.f, 0.f, 0.f, 0.f, 0.f};
#pragma unroll
  for (int e = 0; e < 16; ++e) {
    u16x8 ve = *(const u16x8*)(vemb_bf + (size_t)id[e] * 2048 + d0);
#pragma unroll
    for (int u = 0; u < 8; ++u) g[u] += bf2f(ve[u]);
  }
  float4 h0 = *(const float4*)(hs + (size_t)s * 2048 + d0);
  float4 h1 = *(const float4*)(hs + (size_t)s * 2048 + d0 + 4);
  float hv[8] = {h0.x, h0.y, h0.z, h0.w, h1.x, h1.y, h1.z, h1.w};
  u16x8 o;
#pragma unroll
  for (int u = 0; u < 8; ++u) o[u] = f2bf(hv[u] * g[u]);
  *(u16x8*)(vb + (size_t)s * 2048 + d0) = o;
}

__global__ __launch_bounds__(256) void vmean_part(const ushort* __restrict__ vb,
                                                  float* __restrict__ part)
{
  const int h = blockIdx.y, chunk = blockIdx.x;
  const int t = threadIdx.x, d = t & 127, half = t >> 7;
  float s = 0.f;
  int r0 = chunk * 256 + half * 128;
  for (int r = r0; r < r0 + 128; ++r)
    s += bf2f(vb[(size_t)r * 2048 + h * 128 + d]);
  __shared__ float red[256];
  red[t] = s;
  __syncthreads();
  if (t < 128) part[(size_t)(h * 8 + chunk) * 128 + d] = red[t] + red[t + 128];
}

__global__ __launch_bounds__(128) void vmean_fin(const float* __restrict__ part,
                                                 float* __restrict__ vmean)
{
  const int h = blockIdx.x, d = threadIdx.x;
  float s = 0.f;
#pragma unroll
  for (int c = 0; c < 8; ++c) s += part[(size_t)(h * 8 + c) * 128 + d];
  vmean[h * 128 + d] = s * (1.f / 2048.f);
}

__global__ __launch_bounds__(256) void i0_scan(const float* __restrict__ amask,
    const float* __restrict__ dmask, int* __restrict__ i0)
{
  const int h = blockIdx.x, t = threadIdx.x;
  int best = 0x7fffffff;
  for (int j = t; j < 2048; j += 256) {
    if (amask[j] * dmask[h * 2048 + j] != 0.f) { best = j; break; }
  }
  __shared__ int red[256];
  red[t] = best;
  __syncthreads();
  for (int off = 128; off > 0; off >>= 1) {
    if (t < off) red[t] = min(red[t], red[t + off]);
    __syncthreads();
  }
  if (t == 0) i0[h] = red[0];
}

__global__ __launch_bounds__(256) void rope_q_bf(ushort* __restrict__ q,
    const float* __restrict__ cosb, const float* __restrict__ sinb, int ld)
{
  int tid = blockIdx.x * 256 + threadIdx.x;
  int d = tid & 63, h = (tid >> 6) & 15, s = tid >> 10;
  size_t base = (size_t)s * ld + h * 128;
  float c0 = cosb[s*128 + d],      s0 = sinb[s*128 + d];
  float c1 = cosb[s*128 + d + 64], s1 = sinb[s*128 + d + 64];
  float a = bf2f(q[base + d]), b = bf2f(q[base + d + 64]);
  q[base + d]      = f2bf(a * c0 - b * s0);
  q[base + d + 64] = f2bf(b * c1 + a * s1);
}

// ---------------------------------------------------------------------------
// MFMA flash attention, stripe-paired, 8 waves = 2 k-parity groups x 4 row
// waves. Each group: private double-buffered K/V LDS, partial (m,l,acc);
// in-LDS merge at stripe end. 256 blocks x 512 thr -> 2 waves/SIMD.
// ---------------------------------------------------------------------------
#define QLD 4096
__global__ __launch_bounds__(512) void attn_mfma(
    const ushort* __restrict__ qb, const ushort* __restrict__ kb,
    const ushort* __restrict__ vt, const float* __restrict__ amask,
    const float* __restrict__ dmask, const float* __restrict__ vmean,
    const int* __restrict__ i0, ushort* __restrict__ ao)
{
  const int h  = blockIdx.y;
  const int pr = blockIdx.x;                 // pair 0..15
  const int t  = threadIdx.x, w = t >> 6, lane = t & 63;
  const int g  = w >> 2, wg = w & 3;         // k-parity group, row-wave
  const int lr = lane & 15, lk = lane >> 4;

  // LDS: [0,64K) K tiles (g,buf); [64K,128K) V tiles; [128K,144K) Ps[g]
  __shared__ char smem[147456];
  float* accL = (float*)smem;                       // [64][132] f32 (merge)
  float* smv  = (float*)(smem + 33792);             // [2][64]
  float* slv  = (float*)(smem + 33792 + 512);       // [2][64]

  const int i0h = i0[h];

  for (int sp = 0; sp < 2; ++sp) {
    const int stripe = (sp == 0) ? pr : 31 - pr;
    const int q0 = stripe << 6;
    const int ntiles = stripe + 1;

    __syncthreads();   // LDS reusable (prev stripe fully done)

    // Q fragments in registers (both groups need the same rows)
    const int qrow = q0 + wg * 16 + lr;
    bf16x8 qf[4];
#pragma unroll
    for (int kk = 0; kk < 4; ++kk)
      qf[kk] = *(const bf16x8*)(qb + (size_t)qrow * QLD + h * 128 + kk * 32 + lk * 8);

    // stage tile g (if any) into buf 0 of group g
    if (g < ntiles) {
      const int c0 = g << 6;
#pragma unroll
      for (int qI = 0; qI < 4; ++qI) {
        int b = wg * 4096 + qI * 1024 + lane * 16;
        int row = b >> 8, colb = b & 255;
        int src = colb ^ ((row & 7) << 4);
        gload_lds16((const char*)kb + ((size_t)(c0 + row) * QLD + h * 128) * 2 + src,
                    smem + g * 32768 + b - lane * 16 + (lane * 16));
      }
      // (identical addressing, written explicitly below for V)
#pragma unroll
      for (int qI = 0; qI < 4; ++qI) {
        int b = wg * 4096 + qI * 1024 + lane * 16;
        int row = b >> 7, colb = b & 127;
        int src = colb ^ ((row & 7) << 4);
        gload_lds16((const char*)vt + ((size_t)(h * 128 + row) * 2048 + c0) * 2 + src,
                    smem + 65536 + g * 32768 + b);
      }
    }

    float m[4], l[4];
    f32x4 acc_o[8];
#pragma unroll
    for (int j = 0; j < 4; ++j) { m[j] = -FLT_MAX; l[j] = 0.f; }
#pragma unroll
    for (int ni = 0; ni < 8; ++ni) acc_o[ni] = (f32x4){0.f, 0.f, 0.f, 0.f};

    int cur = 0;
    const int niter = (ntiles + 1) >> 1;
    for (int it = 0; it < niter; ++it) {
      const int tile = 2 * it + g;
      const int c0 = tile << 6;
      __syncthreads();   // vmcnt(0) drain: buf[cur] ready for both groups

      float madd[4];
      if (tile < ntiles) {
#pragma unroll
        for (int ni = 0; ni < 4; ++ni) {
          int c = c0 + ni * 16 + lr;
          madd[ni] = (amask[c] * dmask[h * 2048 + c] == 0.f) ? NEG_MIN : 0.f;
        }
      }

      // prefetch tile+2 into buf cur^1
      if (tile + 2 < ntiles) {
        const int cn = c0 + 128;
        const int nb = cur ^ 1;
#pragma unroll
        for (int qI = 0; qI < 4; ++qI) {
          int b = wg * 4096 + qI * 1024 + lane * 16;
          int row = b >> 8, colb = b & 255;
          int src = colb ^ ((row & 7) << 4);
          gload_lds16((const char*)kb + ((size_t)(cn + row) * QLD + h * 128) * 2 + src,
                      smem + g * 32768 + nb * 16384 + b);
        }
#pragma unroll
        for (int qI = 0; qI < 4; ++qI) {
          int b = wg * 4096 + qI * 1024 + lane * 16;
          int row = b >> 7, colb = b & 127;
          int src = colb ^ ((row & 7) << 4);
          gload_lds16((const char*)vt + ((size_t)(h * 128 + row) * 2048 + cn) * 2 + src,
                      smem + 65536 + g * 32768 + nb * 16384 + b);
        }
      }

      if (tile < ntiles) {
        const bool diag = (tile == stripe);
        const char* Kbase = smem + g * 32768 + cur * 16384;
        const char* Vbase = smem + 65536 + g * 32768 + cur * 16384;
        char* Pbase = smem + 131072 + g * 8192;

        // ---- S = Q K^T
        f32x4 sacc[4];
#pragma unroll
        for (int ni = 0; ni < 4; ++ni) sacc[ni] = (f32x4){0.f, 0.f, 0.f, 0.f};
#pragma unroll
        for (int kk = 0; kk < 4; ++kk) {
#pragma unroll
          for (int ni = 0; ni < 4; ++ni) {
            int krow = ni * 16 + lr;
            bf16x8 bfr = *(const bf16x8*)(Kbase + krow * 256 + ((kk * 64 + lk * 16) ^ ((krow & 7) << 4)));
            sacc[ni] = __builtin_amdgcn_mfma_f32_16x16x32_bf16(qf[kk], bfr, sacc[ni], 0, 0, 0);
          }
        }

        // ---- mask + online softmax (additive mask; causal only on diag tile)
#pragma unroll
        for (int j = 0; j < 4; ++j) {
          int grow = q0 + wg * 16 + lk * 4 + j;
          float x[4]; float tmax = -FLT_MAX;
#pragma unroll
          for (int ni = 0; ni < 4; ++ni) {
            float v = fmaf(sacc[ni][j], INV_SQRT_HD, madd[ni]);
            if (diag && c0 + ni * 16 + lr > grow) v = NEG_MIN;
            x[ni] = v; tmax = fmaxf(tmax, v);
          }
          tmax = fmaxf(tmax, dpp_ror<0x121>(tmax));
          tmax = fmaxf(tmax, dpp_ror<0x122>(tmax));
          tmax = fmaxf(tmax, dpp_ror<0x124>(tmax));
          tmax = fmaxf(tmax, dpp_ror<0x128>(tmax));
          float mn = fmaxf(m[j], tmax);
          float psum = 0.f;
          int prow = wg * 16 + lk * 4 + j;
#pragma unroll
          for (int ni = 0; ni < 4; ++ni) {
            float p = __expf(x[ni] - mn);
            psum += p;
            *(ushort*)(Pbase + prow * 128 + ((2 * (ni * 16 + lr)) ^ ((prow & 7) << 4))) = f2bf(p);
          }
          psum += dpp_ror<0x121>(psum);
          psum += dpp_ror<0x122>(psum);
          psum += dpp_ror<0x124>(psum);
          psum += dpp_ror<0x128>(psum);
          if (mn > m[j]) {
            float sc = __expf(m[j] - mn);
            l[j] *= sc;
#pragma unroll
            for (int ni = 0; ni < 8; ++ni) acc_o[ni][j] *= sc;
            m[j] = mn;
          }
          l[j] += psum;
        }

        // ---- O += P V (same-wave Ps rows)
#pragma unroll
        for (int kk = 0; kk < 2; ++kk) {
          int prow = wg * 16 + lr;
          bf16x8 a = *(const bf16x8*)(Pbase + prow * 128 + ((kk * 64 + lk * 16) ^ ((prow & 7) << 4)));
#pragma unroll
          for (int ni = 0; ni < 8; ++ni) {
            int vrow = ni * 16 + lr;
            bf16x8 bfr = *(const bf16x8*)(Vbase + vrow * 128 + ((kk * 64 + lk * 16) ^ ((vrow & 7) << 4)));
            acc_o[ni] = __builtin_amdgcn_mfma_f32_16x16x32_bf16(a, bfr, acc_o[ni], 0, 0, 0);
          }
        }
      }
      cur ^= 1;
    }

    // ---- merge the two k-parity partials, write output (group 0)
    __syncthreads();   // all compute done; LDS reusable for merge
    if (lr == 0) {
#pragma unroll
      for (int j = 0; j < 4; ++j) {
        int r = wg * 16 + lk * 4 + j;
        smv[g * 64 + r] = m[j];
        slv[g * 64 + r] = l[j];
      }
    }
    __syncthreads();
    float myf[4], lcomb[4];
#pragma unroll
    for (int j = 0; j < 4; ++j) {
      int r = wg * 16 + lk * 4 + j;
      float m0 = smv[r], m1 = smv[64 + r];
      float l0 = slv[r], l1 = slv[64 + r];
      float mm = fmaxf(m0, m1);
      float f0 = __expf(m0 - mm), f1 = __expf(m1 - mm);
      lcomb[j] = l0 * f0 + l1 * f1;
      myf[j] = (g == 0) ? f0 : f1;
    }
    if (g == 1) {
#pragma unroll
      for (int j = 0; j < 4; ++j) {
        int r = wg * 16 + lk * 4 + j;
#pragma unroll
        for (int ni = 0; ni < 8; ++ni)
          accL[r * 132 + ni * 16 + lr] = acc_o[ni][j] * myf[j];
      }
    }
    __syncthreads();
    if (g == 0) {
#pragma unroll
      for (int j = 0; j < 4; ++j) {
        int row = q0 + wg * 16 + lk * 4 + j;
        int r = wg * 16 + lk * 4 + j;
        if (row < i0h) {
#pragma unroll
          for (int ni = 0; ni < 8; ++ni)
            ao[(size_t)row * 2048 + h * 128 + ni * 16 + lr] = f2bf(vmean[h * 128 + ni * 16 + lr]);
        } else {
          float inv = 1.f / lcomb[j];
#pragma unroll
          for (int ni = 0; ni < 8; ++ni) {
            float o = fmaf(acc_o[ni][j], myf[j], accL[r * 132 + ni * 16 + lr]);
            ao[(size_t)row * 2048 + h * 128 + ni * 16 + lr] = f2bf(o * inv);
          }
        }
      }
    }
  }
}

// ---------------------------------------------------------------------------
extern "C" void kernel_launch(void* const* d_in, const int* in_sizes, int n_in,
                              void* d_out, int out_size, void* d_ws, size_t ws_size,
                              hipStream_t stream)
{
  const float* hs    = (const float*)d_in[0];
  const float* amask = (const float*)d_in[1];
  const float* cosb  = (const float*)d_in[2];
  const float* sinb  = (const float*)d_in[3];
  const float* dmask = (const float*)d_in[4];
  const float* Wq    = (const float*)d_in[5];
  const float* Wk    = (const float*)d_in[6];
  const float* Wvq   = (const float*)d_in[7];
  const float* vkeys = (const float*)d_in[8];
  const float* vemb  = (const float*)d_in[9];
  const float* Wo    = (const float*)d_in[10];
  float* outp = (float*)d_out;

  char* ws = (char*)d_ws;
  const size_t MB = 1048576;
  float*  pvq     = (float*) (ws + 0);              // [0,32)
  float*  vq_f32  = (float*) (ws + 32*MB);          // [32,36)
  ushort* vq_bf   = (ushort*)(ws + 36*MB);          // [36,38)
  ushort* vkT     = (ushort*)(ws + 38*MB);          // [38,40)
  int*    cand    = (int*)   (ws + 40*MB);          // 256 KB
  int*    idx     = (int*)   (ws + 40*MB + 262144); // 128 KB
  float*  part    = (float*) (ws + 41*MB);          // 64 KB
  float*  vmean   = (float*) (ws + 41*MB + 65536);  // 8 KB
  int*    i0b     = (int*)   (ws + 41*MB + 73728);  // 64 B
  ushort* sim_bf  = (ushort*)(ws + 0);              // over dead pvq
  ushort* vb      = (ushort*)(ws + 0);
  ushort* vt      = (ushort*)(ws + 8*MB);
  ushort* hs_bf   = (ushort*)(ws + 16*MB);
  ushort* qkC     = (ushort*)(ws + 24*MB);          // fused q|k, ld 4096
  ushort* vemb_bf = (ushort*)(ws + 48*MB);
  ushort* WBig    = (ushort*)(ws + 48*MB);
  ushort* WoT     = (ushort*)(ws + 48*MB);
  ushort* ao      = (ushort*)(ws + 0);

  dim3 blk(256);
  // ---- routing path ----
  gemm_f32_sk<<<dim3(4, 16, 8), blk, 0, stream>>>(hs, 2048, Wvq, 512, pvq, 512, 2048, 512, 256);
  reduce8_cvt<<<dim3(1024), blk, 0, stream>>>(pvq, vq_f32, vq_bf);
  transpose_cvt<<<dim3(32, 2, 4), blk, 0, stream>>>(vkeys, vkT, 128, 2048, 262144, 262144);
  gemm_bf16<1><<<dim3(16, 16, 4), blk, 0, stream>>>(vq_bf, 512, vkT, 128,
      sim_bf, 2048, 128, 128, 262144, 4194304);
  topk8<<<dim3(2048), blk, 0, stream>>>(sim_bf, cand);
  recomp_sel<<<dim3(2048), blk, 0, stream>>>(vq_f32, vkeys, cand, idx);
  // ---- v construction ----
  cvt2_bf16<<<dim3(8192), blk, 0, stream>>>(vemb, vemb_bf, hs, hs_bf);
  gather_mul_bf<<<dim3(2048), blk, 0, stream>>>(hs, vemb_bf, idx, vb);
  transpose_bf<<<dim3(32, 32), blk, 0, stream>>>(vb, vt);
  vmean_part<<<dim3(8, 16), blk, 0, stream>>>(vb, part);
  vmean_fin<<<dim3(16), dim3(128), 0, stream>>>(part, vmean);
  i0_scan<<<dim3(16), blk, 0, stream>>>(amask, dmask, i0b);
  // ---- projections (fused q|k) ----
  transpose_cvt<<<dim3(32, 32, 1), blk, 0, stream>>>(Wq, WBig, 2048, 2048, 0, 0);
  transpose_cvt<<<dim3(32, 32, 1), blk, 0, stream>>>(Wk, WBig + (size_t)2048 * 2048, 2048, 2048, 0, 0);
  gemm_bf16<1><<<dim3(32, 16, 1), blk, 0, stream>>>(hs_bf, 2048, WBig, 2048, qkC, 4096, 2048, 0, 0, 0);
  rope_q_bf<<<dim3(8192), blk, 0, stream>>>(qkC, cosb, sinb, 4096);
  // ---- attention ----
  transpose_cvt<<<dim3(32, 32, 1), blk, 0, stream>>>(Wo, WoT, 2048, 2048, 0, 0);
  attn_mfma<<<dim3(16, 16), dim3(512), 0, stream>>>(qkC, qkC + 2048, vt, amask, dmask, vmean, i0b, ao);
  // ---- output projection ----
  gemm_bf16<0><<<dim3(16, 16, 1), blk, 0, stream>>>(ao, 2048, WoT, 2048, outp, 2048, 2048, 0, 0, 0);
}

// Round 7
// 397.170 us; speedup vs baseline: 9.5973x; 1.0368x over previous
//
#include <hip/hip_runtime.h>
#include <float.h>

// B=1, S=2048, D=2048, H=16, HD=128, HV=4, R=128, NV=2048, K=4
#define NEG_MIN (-3.4028234663852886e38f)
#define INV_SQRT_HD 0.08838834764831845f

typedef __attribute__((ext_vector_type(8))) short bf16x8;
typedef __attribute__((ext_vector_type(8))) unsigned short u16x8;
typedef __attribute__((ext_vector_type(4))) float f32x4;

__device__ __forceinline__ void gload_lds16(const void* g, void* l) {
  __builtin_amdgcn_global_load_lds((const __attribute__((address_space(1))) void*)g,
                                   (__attribute__((address_space(3))) void*)l, 16, 0, 0);
}
__device__ __forceinline__ ushort f2bf(float x) {
  union { float f; unsigned u; } v; v.f = x;
  unsigned r = v.u + 0x7fffu + ((v.u >> 16) & 1u);   // RNE
  return (ushort)(r >> 16);
}
__device__ __forceinline__ float bf2f(ushort u) {
  union { unsigned i; float f; } v; v.i = ((unsigned)u) << 16; return v.f;
}
template<int CTRL>
__device__ __forceinline__ float dpp_ror(float x) {
  return __int_as_float(__builtin_amdgcn_mov_dpp(__float_as_int(x), CTRL, 0xF, 0xF, true));
}

// ---------------------------------------------------------------------------
// Split-K f32 GEMM, 128x128 tile, 8x8 microtile, reg double-buffered staging.
// LDS rows padded to 132 (A-store 2-way); B columns split tx*4 / tx*4+64
// (2-way reads, free per m136). Exact-f32 path for vq.
// ---------------------------------------------------------------------------
__global__ __launch_bounds__(256) void gemm_f32_sk(
    const float* __restrict__ A, int lda,
    const float* __restrict__ B, int ldb,
    float* __restrict__ Cp, int ldc, int M, int N, int Kchunk)
{
  __shared__ float As[16][132];
  __shared__ float Bs[16][132];
  const int t = threadIdx.x, tx = t & 15, ty = t >> 4;
  const int bm = blockIdx.y << 7, bn = blockIdx.x << 7;
  const int k0base = blockIdx.z * Kchunk;
  const int arr = t >> 2, ac = (t & 3) << 2;       // A tile coords (row, k4)
  const int brr = t >> 5, bc = (t & 31) << 2;      // B tile coords (k, col4)

  float acc[8][8];
#pragma unroll
  for (int i = 0; i < 8; ++i)
#pragma unroll
    for (int j = 0; j < 8; ++j) acc[i][j] = 0.f;

  float4 pa0, pa1, pb0, pb1;
  // prologue load (k-slice 0)
  pa0 = *(const float4*)(A + (size_t)(bm + arr) * lda + k0base + ac);
  pa1 = *(const float4*)(A + (size_t)(bm + arr + 64) * lda + k0base + ac);
  pb0 = *(const float4*)(B + (size_t)(k0base + brr) * ldb + bn + bc);
  pb1 = *(const float4*)(B + (size_t)(k0base + brr + 8) * ldb + bn + bc);

  for (int k0 = 0; k0 < Kchunk; k0 += 16) {
    __syncthreads();   // previous iteration's readers done
    As[ac + 0][arr] = pa0.x; As[ac + 1][arr] = pa0.y;
    As[ac + 2][arr] = pa0.z; As[ac + 3][arr] = pa0.w;
    As[ac + 0][arr + 64] = pa1.x; As[ac + 1][arr + 64] = pa1.y;
    As[ac + 2][arr + 64] = pa1.z; As[ac + 3][arr + 64] = pa1.w;
    *(float4*)(&Bs[brr][bc])     = pb0;
    *(float4*)(&Bs[brr + 8][bc]) = pb1;
    __syncthreads();
    if (k0 + 16 < Kchunk) {      // prefetch next k-slice (overlaps compute)
      int kn = k0base + k0 + 16;
      pa0 = *(const float4*)(A + (size_t)(bm + arr) * lda + kn + ac);
      pa1 = *(const float4*)(A + (size_t)(bm + arr + 64) * lda + kn + ac);
      pb0 = *(const float4*)(B + (size_t)(kn + brr) * ldb + bn + bc);
      pb1 = *(const float4*)(B + (size_t)(kn + brr + 8) * ldb + bn + bc);
    }
#pragma unroll
    for (int kk = 0; kk < 16; ++kk) {
      float4 a0 = *(const float4*)(&As[kk][ty * 8]);
      float4 a1 = *(const float4*)(&As[kk][ty * 8 + 4]);
      float4 b0 = *(const float4*)(&Bs[kk][tx * 4]);
      float4 b1 = *(const float4*)(&Bs[kk][tx * 4 + 64]);
      float av[8] = {a0.x, a0.y, a0.z, a0.w, a1.x, a1.y, a1.z, a1.w};
      float bv[8] = {b0.x, b0.y, b0.z, b0.w, b1.x, b1.y, b1.z, b1.w};
#pragma unroll
      for (int i = 0; i < 8; ++i)
#pragma unroll
        for (int j = 0; j < 8; ++j)
          acc[i][j] = fmaf(av[i], bv[j], acc[i][j]);
    }
  }
  float* C = Cp + (size_t)blockIdx.z * M * N;
#pragma unroll
  for (int i = 0; i < 8; ++i) {
    int row = bm + ty * 8 + i;
    *(float4*)(C + (size_t)row * ldc + bn + tx * 4) =
        make_float4(acc[i][0], acc[i][1], acc[i][2], acc[i][3]);
    *(float4*)(C + (size_t)row * ldc + bn + tx * 4 + 64) =
        make_float4(acc[i][4], acc[i][5], acc[i][6], acc[i][7]);
  }
}

__global__ __launch_bounds__(256) void reduce8_cvt(const float* __restrict__ Cp,
    float* __restrict__ vq, ushort* __restrict__ vq_bf)
{
  int i = (blockIdx.x * 256 + threadIdx.x) << 2;
  float4 s = make_float4(0.f, 0.f, 0.f, 0.f);
#pragma unroll
  for (int z = 0; z < 8; ++z) {
    float4 a = *(const float4*)(Cp + (size_t)z * 1048576 + i);
    s.x += a.x; s.y += a.y; s.z += a.z; s.w += a.w;
  }
  *(float4*)(vq + i) = s;
  ushort4 o; o.x = f2bf(s.x); o.y = f2bf(s.y); o.z = f2bf(s.z); o.w = f2bf(s.w);
  *(ushort4*)(vq_bf + i) = o;
}

// ---------------------------------------------------------------------------
// bf16 MFMA GEMM (z-batched): C = A @ Bt^T. 128x128 tile, BK=64.
// ---------------------------------------------------------------------------
template<int OUT_BF16>
__global__ __launch_bounds__(256) void gemm_bf16(
    const ushort* __restrict__ A0, int lda,
    const ushort* __restrict__ Bt0, int ldb,
    void* __restrict__ C0, int ldc, int Kd,
    size_t strA, size_t strB, size_t strC)
{
  const ushort* A  = A0  + blockIdx.z * strA;
  const ushort* Bt = Bt0 + blockIdx.z * strB;
  __shared__ ushort As[128 * 64];
  __shared__ ushort Bs[128 * 64];
  const int t = threadIdx.x, w = t >> 6, lane = t & 63;
  const int lr = lane & 15, lk = lane >> 4;
  const int bm = blockIdx.y << 7, bn = blockIdx.x << 7;
  const int wm = (w >> 1) << 6, wn = (w & 1) << 6;
  f32x4 acc[4][4];
#pragma unroll
  for (int i = 0; i < 4; ++i)
#pragma unroll
    for (int j = 0; j < 4; ++j) acc[i][j] = (f32x4){0.f, 0.f, 0.f, 0.f};

  for (int k0 = 0; k0 < Kd; k0 += 64) {
    __syncthreads();
#pragma unroll
    for (int qI = 0; qI < 4; ++qI) {
      int b = w * 4096 + qI * 1024 + lane * 16;
      int row = b >> 7, colb = b & 127;
      int src = colb ^ ((row & 7) << 4);
      gload_lds16((const char*)A + ((size_t)(bm + row) * lda + k0) * 2 + src,
                  (char*)As + w * 4096 + qI * 1024);
    }
#pragma unroll
    for (int qI = 0; qI < 4; ++qI) {
      int b = w * 4096 + qI * 1024 + lane * 16;
      int row = b >> 7, colb = b & 127;
      int src = colb ^ ((row & 7) << 4);
      gload_lds16((const char*)Bt + ((size_t)(bn + row) * ldb + k0) * 2 + src,
                  (char*)Bs + w * 4096 + qI * 1024);
    }
    __syncthreads();
#pragma unroll
    for (int kk = 0; kk < 2; ++kk) {
      bf16x8 af[4], bf[4];
#pragma unroll
      for (int mi = 0; mi < 4; ++mi) {
        int row = wm + mi * 16 + lr;
        af[mi] = *(const bf16x8*)((const char*)As + row * 128 + ((kk * 64 + lk * 16) ^ ((row & 7) << 4)));
      }
#pragma unroll
      for (int ni = 0; ni < 4; ++ni) {
        int row = wn + ni * 16 + lr;
        bf[ni] = *(const bf16x8*)((const char*)Bs + row * 128 + ((kk * 64 + lk * 16) ^ ((row & 7) << 4)));
      }
#pragma unroll
      for (int mi = 0; mi < 4; ++mi)
#pragma unroll
        for (int ni = 0; ni < 4; ++ni)
          acc[mi][ni] = __builtin_amdgcn_mfma_f32_16x16x32_bf16(af[mi], bf[ni], acc[mi][ni], 0, 0, 0);
    }
  }
#pragma unroll
  for (int mi = 0; mi < 4; ++mi)
#pragma unroll
    for (int j = 0; j < 4; ++j) {
      int row = bm + wm + mi * 16 + lk * 4 + j;
#pragma unroll
      for (int ni = 0; ni < 4; ++ni) {
        int col = bn + wn + ni * 16 + lr;
        if (OUT_BF16) ((ushort*)C0)[blockIdx.z * strC + (size_t)row * ldc + col] = f2bf(acc[mi][ni][j]);
        else          ((float*)C0)[blockIdx.z * strC + (size_t)row * ldc + col]  = acc[mi][ni][j];
      }
    }
}

// ---------------------------------------------------------------------------
// transpose + f32->bf16 (z-batched): dst[c][r] = src[r][c]
// ---------------------------------------------------------------------------
__global__ __launch_bounds__(256) void transpose_cvt(
    const float* __restrict__ src0, ushort* __restrict__ dst0, int R, int Cc,
    size_t zsrc, size_t zdst)
{
  const float* src = src0 + blockIdx.z * zsrc;
  ushort* dst = dst0 + blockIdx.z * zdst;
  __shared__ float tile[64][65];
  const int r0 = blockIdx.y << 6, c0 = blockIdx.x << 6;
  const int t = threadIdx.x;
  for (int i = t; i < 1024; i += 256) {
    int r = i >> 4, c = (i & 15) << 2;
    float4 v = *(const float4*)(src + (size_t)(r0 + r) * Cc + c0 + c);
    tile[r][c] = v.x; tile[r][c+1] = v.y; tile[r][c+2] = v.z; tile[r][c+3] = v.w;
  }
  __syncthreads();
  int c = t >> 2, rb = (t & 3) << 4;
#pragma unroll
  for (int u = 0; u < 16; u += 4) {
    ushort4 o;
    o.x = f2bf(tile[rb+u+0][c]); o.y = f2bf(tile[rb+u+1][c]);
    o.z = f2bf(tile[rb+u+2][c]); o.w = f2bf(tile[rb+u+3][c]);
    *(ushort4*)(dst + (size_t)(c0 + c) * R + r0 + rb + u) = o;
  }
}

// bf16 -> bf16 transpose (2048x2048)
__global__ __launch_bounds__(256) void transpose_bf(
    const ushort* __restrict__ src, ushort* __restrict__ dst)
{
  __shared__ ushort tile[64][66];
  const int r0 = blockIdx.y << 6, c0 = blockIdx.x << 6;
  const int t = threadIdx.x;
  for (int i = t; i < 512; i += 256) {
    int r = i >> 3, c8 = (i & 7) << 3;
    *(u16x8*)(&tile[r][c8]) = *(const u16x8*)(src + (size_t)(r0 + r) * 2048 + c0 + c8);
  }
  __syncthreads();
  for (int i = t; i < 512; i += 256) {
    int c = i >> 3, r8 = (i & 7) << 3;
    u16x8 o;
#pragma unroll
    for (int u = 0; u < 8; ++u) o[u] = tile[r8 + u][c];
    *(u16x8*)(dst + (size_t)(c0 + c) * 2048 + r0 + r8) = o;
  }
}

// two f32->bf16 conversions in one launch (4M elems each)
__global__ __launch_bounds__(256) void cvt2_bf16(const float* __restrict__ srcA,
    ushort* __restrict__ dstA, const float* __restrict__ srcB,
    ushort* __restrict__ dstB)
{
  int gid = blockIdx.x * 256 + threadIdx.x;
  const float* s; ushort* d; int i;
  if (gid < 1048576) { s = srcA; d = dstA; i = gid; }
  else               { s = srcB; d = dstB; i = gid - 1048576; }
  float4 v = ((const float4*)s)[i];
  ushort4 o; o.x = f2bf(v.x); o.y = f2bf(v.y); o.z = f2bf(v.z); o.w = f2bf(v.w);
  ((ushort4*)d)[i] = o;
}

// ---------------------------------------------------------------------------
// Candidate top-8 per sim row from bf16 sim (wave per row).
// ---------------------------------------------------------------------------
__global__ __launch_bounds__(256) void topk8(const ushort* __restrict__ sim,
                                             int* __restrict__ cand)
{
  const int row = blockIdx.x * 4 + (threadIdx.x >> 6);
  const int lane = threadIdx.x & 63;
  const ushort* r = sim + (size_t)row * 2048;
  float v[8]; int ix[8];
#pragma unroll
  for (int p = 0; p < 8; ++p) { v[p] = -FLT_MAX; ix[p] = 0x7fffffff; }
  for (int j = 0; j < 32; ++j) {
    int n = lane + (j << 6);
    float val = bf2f(r[n]);
    if (val > v[7]) {
      v[7] = val; ix[7] = n;
#pragma unroll
      for (int p = 7; p > 0; --p) {
        if (v[p] > v[p-1]) {
          float tv = v[p]; v[p] = v[p-1]; v[p-1] = tv;
          int   ti = ix[p]; ix[p] = ix[p-1]; ix[p-1] = ti;
        }
      }
    }
  }
  int head = 0;
  int out[8];
#pragma unroll
  for (int r8 = 0; r8 < 8; ++r8) {
    float cv = -FLT_MAX; int ci = 0x7fffffff;
#pragma unroll
    for (int p = 0; p < 8; ++p)
      if (p == head) { cv = v[p]; ci = ix[p]; }
#pragma unroll
    for (int d = 1; d < 64; d <<= 1) {
      float ov = __shfl_xor(cv, d); int oi = __shfl_xor(ci, d);
      if (ov > cv || (ov == cv && oi < ci)) { cv = ov; ci = oi; }
    }
    out[r8] = ci;
    bool mine = false;
#pragma unroll
    for (int p = 0; p < 8; ++p) if (p == head && ix[p] == ci) mine = true;
    if (mine) head++;
  }
  if (lane == 0) {
#pragma unroll
    for (int p = 0; p < 8; ++p) cand[(size_t)row * 8 + p] = out[p];
  }
}

// ---------------------------------------------------------------------------
// Exact f32 recompute of 8 candidates + exact top-4 (index tie-break).
// ---------------------------------------------------------------------------
__global__ __launch_bounds__(256) void recomp_sel(
    const float* __restrict__ vq, const float* __restrict__ vkeys,
    const int* __restrict__ cand, int* __restrict__ idxo)
{
  const int row = blockIdx.x * 4 + (threadIdx.x >> 6);
  const int hv = row >> 11, s = row & 2047;
  const int lane = threadIdx.x & 63;
  const int c = lane & 7, rc = lane >> 3;
  const int n = cand[(size_t)row * 8 + c];
  const float* vqr = vq + (size_t)s * 512 + hv * 128 + rc * 16;
  const float* vk  = vkeys + (size_t)hv * 262144 + (size_t)(rc * 16) * 2048 + n;
  float acc = 0.f;
#pragma unroll
  for (int u = 0; u < 16; ++u) acc = fmaf(vqr[u], vk[(size_t)u * 2048], acc);
  acc += __shfl_xor(acc, 8);
  acc += __shfl_xor(acc, 16);
  acc += __shfl_xor(acc, 32);
  float cv = acc; int ci = n;
  int picks[4];
#pragma unroll
  for (int p = 0; p < 4; ++p) {
    float bv = cv; int bi = ci;
#pragma unroll
    for (int d = 1; d < 8; d <<= 1) {
      float ov = __shfl_xor(bv, d); int oi = __shfl_xor(bi, d);
      if (ov > bv || (ov == bv && oi < bi)) { bv = ov; bi = oi; }
    }
    picks[p] = bi;
    if (bi == ci) cv = -FLT_MAX;
  }
  if (lane == 0) {
#pragma unroll
    for (int p = 0; p < 4; ++p) idxo[(size_t)row * 4 + p] = picks[p];
  }
}

// ---------------------------------------------------------------------------
__global__ __launch_bounds__(256) void gather_mul_bf(const float* __restrict__ hs,
    const ushort* __restrict__ vemb_bf, const int* __restrict__ idx,
    ushort* __restrict__ vb)
{
  const int s = blockIdx.x;
  const int t = threadIdx.x;
  __shared__ int id[16];
  if (t < 16) id[t] = idx[((size_t)(t >> 2) * 2048 + s) * 4 + (t & 3)];
  __syncthreads();
  int d0 = t << 3;
  float g[8] = {0.f, 0.f, 0.f, 0.f, 0.f, 0.f, 0.f, 0.f};
#pragma unroll
  for (int e = 0; e < 16; ++e) {
    u16x8 ve = *(const u16x8*)(vemb_bf + (size_t)id[e] * 2048 + d0);
#pragma unroll
    for (int u = 0; u < 8; ++u) g[u] += bf2f(ve[u]);
  }
  float4 h0 = *(const float4*)(hs + (size_t)s * 2048 + d0);
  float4 h1 = *(const float4*)(hs + (size_t)s * 2048 + d0 + 4);
  float hv[8] = {h0.x, h0.y, h0.z, h0.w, h1.x, h1.y, h1.z, h1.w};
  u16x8 o;
#pragma unroll
  for (int u = 0; u < 8; ++u) o[u] = f2bf(hv[u] * g[u]);
  *(u16x8*)(vb + (size_t)s * 2048 + d0) = o;
}

__global__ __launch_bounds__(256) void vmean_part(const ushort* __restrict__ vb,
                                                  float* __restrict__ part)
{
  const int h = blockIdx.y, chunk = blockIdx.x;
  const int t = threadIdx.x, d = t & 127, half = t >> 7;
  float s = 0.f;
  int r0 = chunk * 256 + half * 128;
  for (int r = r0; r < r0 + 128; ++r)
    s += bf2f(vb[(size_t)r * 2048 + h * 128 + d]);
  __shared__ float red[256];
  red[t] = s;
  __syncthreads();
  if (t < 128) part[(size_t)(h * 8 + chunk) * 128 + d] = red[t] + red[t + 128];
}

// fused: vmean finalize + first-unmasked-column scan (one block per head)
__global__ __launch_bounds__(256) void vmean_i0(const float* __restrict__ part,
    const float* __restrict__ amask, const float* __restrict__ dmask,
    float* __restrict__ vmean, int* __restrict__ i0)
{
  const int h = blockIdx.x, t = threadIdx.x;
  if (t < 128) {
    float s = 0.f;
#pragma unroll
    for (int c = 0; c < 8; ++c) s += part[(size_t)(h * 8 + c) * 128 + t];
    vmean[h * 128 + t] = s * (1.f / 2048.f);
  }
  int best = 0x7fffffff;
  for (int j = t; j < 2048; j += 256) {
    if (amask[j] * dmask[h * 2048 + j] != 0.f) { best = j; break; }
  }
  __shared__ int red[256];
  red[t] = best;
  __syncthreads();
  for (int off = 128; off > 0; off >>= 1) {
    if (t < off) red[t] = min(red[t], red[t + off]);
    __syncthreads();
  }
  if (t == 0) i0[h] = red[0];
}

__global__ __launch_bounds__(256) void rope_q_bf(ushort* __restrict__ q,
    const float* __restrict__ cosb, const float* __restrict__ sinb, int ld)
{
  int tid = blockIdx.x * 256 + threadIdx.x;
  int d = tid & 63, h = (tid >> 6) & 15, s = tid >> 10;
  size_t base = (size_t)s * ld + h * 128;
  float c0 = cosb[s*128 + d],      s0 = sinb[s*128 + d];
  float c1 = cosb[s*128 + d + 64], s1 = sinb[s*128 + d + 64];
  float a = bf2f(q[base + d]), b = bf2f(q[base + d + 64]);
  q[base + d]      = f2bf(a * c0 - b * s0);
  q[base + d + 64] = f2bf(b * c1 + a * s1);
}

// ---------------------------------------------------------------------------
// MFMA flash attention, stripe-paired, 8 waves = 2 k-parity groups x 4 row
// waves. Private double-buffered K/V LDS per group; in-LDS merge at stripe
// end. 256 blocks x 512 thr -> 2 waves/SIMD. s_setprio around MFMA (T5).
// ---------------------------------------------------------------------------
#define QLD 4096
__global__ __launch_bounds__(512) void attn_mfma(
    const ushort* __restrict__ qb, const ushort* __restrict__ kb,
    const ushort* __restrict__ vt, const float* __restrict__ amask,
    const float* __restrict__ dmask, const float* __restrict__ vmean,
    const int* __restrict__ i0, ushort* __restrict__ ao)
{
  const int h  = blockIdx.y;
  const int pr = blockIdx.x;                 // pair 0..15
  const int t  = threadIdx.x, w = t >> 6, lane = t & 63;
  const int g  = w >> 2, wg = w & 3;         // k-parity group, row-wave
  const int lr = lane & 15, lk = lane >> 4;

  // LDS: [0,64K) K tiles (g,buf); [64K,128K) V tiles; [128K,144K) Ps[g]
  __shared__ char smem[147456];
  float* accL = (float*)smem;                       // [64][132] f32 (merge)
  float* smv  = (float*)(smem + 33792);             // [2][64]
  float* slv  = (float*)(smem + 33792 + 512);       // [2][64]

  const int i0h = i0[h];

  for (int sp = 0; sp < 2; ++sp) {
    const int stripe = (sp == 0) ? pr : 31 - pr;
    const int q0 = stripe << 6;
    const int ntiles = stripe + 1;

    __syncthreads();   // LDS reusable (prev stripe fully done)

    // Q fragments in registers (both groups need the same rows)
    const int qrow = q0 + wg * 16 + lr;
    bf16x8 qf[4];
#pragma unroll
    for (int kk = 0; kk < 4; ++kk)
      qf[kk] = *(const bf16x8*)(qb + (size_t)qrow * QLD + h * 128 + kk * 32 + lk * 8);

    // stage tile g (if any) into buf 0 of group g
    if (g < ntiles) {
      const int c0 = g << 6;
#pragma unroll
      for (int qI = 0; qI < 4; ++qI) {
        int b = wg * 4096 + qI * 1024 + lane * 16;
        int row = b >> 8, colb = b & 255;
        int src = colb ^ ((row & 7) << 4);
        gload_lds16((const char*)kb + ((size_t)(c0 + row) * QLD + h * 128) * 2 + src,
                    smem + g * 32768 + b);
      }
#pragma unroll
      for (int qI = 0; qI < 4; ++qI) {
        int b = wg * 4096 + qI * 1024 + lane * 16;
        int row = b >> 7, colb = b & 127;
        int src = colb ^ ((row & 7) << 4);
        gload_lds16((const char*)vt + ((size_t)(h * 128 + row) * 2048 + c0) * 2 + src,
                    smem + 65536 + g * 32768 + b);
      }
    }

    float m[4], l[4];
    f32x4 acc_o[8];
#pragma unroll
    for (int j = 0; j < 4; ++j) { m[j] = -FLT_MAX; l[j] = 0.f; }
#pragma unroll
    for (int ni = 0; ni < 8; ++ni) acc_o[ni] = (f32x4){0.f, 0.f, 0.f, 0.f};

    int cur = 0;
    const int niter = (ntiles + 1) >> 1;
    for (int it = 0; it < niter; ++it) {
      const int tile = 2 * it + g;
      const int c0 = tile << 6;
      __syncthreads();   // vmcnt(0) drain: buf[cur] ready for both groups

      float madd[4];
      if (tile < ntiles) {
#pragma unroll
        for (int ni = 0; ni < 4; ++ni) {
          int c = c0 + ni * 16 + lr;
          madd[ni] = (amask[c] * dmask[h * 2048 + c] == 0.f) ? NEG_MIN : 0.f;
        }
      }

      // prefetch tile+2 into buf cur^1
      if (tile + 2 < ntiles) {
        const int cn = c0 + 128;
        const int nb = cur ^ 1;
#pragma unroll
        for (int qI = 0; qI < 4; ++qI) {
          int b = wg * 4096 + qI * 1024 + lane * 16;
          int row = b >> 8, colb = b & 255;
          int src = colb ^ ((row & 7) << 4);
          gload_lds16((const char*)kb + ((size_t)(cn + row) * QLD + h * 128) * 2 + src,
                      smem + g * 32768 + nb * 16384 + b);
        }
#pragma unroll
        for (int qI = 0; qI < 4; ++qI) {
          int b = wg * 4096 + qI * 1024 + lane * 16;
          int row = b >> 7, colb = b & 127;
          int src = colb ^ ((row & 7) << 4);
          gload_lds16((const char*)vt + ((size_t)(h * 128 + row) * 2048 + cn) * 2 + src,
                      smem + 65536 + g * 32768 + nb * 16384 + b);
        }
      }

      if (tile < ntiles) {
        const bool diag = (tile == stripe);
        const char* Kbase = smem + g * 32768 + cur * 16384;
        const char* Vbase = smem + 65536 + g * 32768 + cur * 16384;
        char* Pbase = smem + 131072 + g * 8192;

        // ---- S = Q K^T
        f32x4 sacc[4];
#pragma unroll
        for (int ni = 0; ni < 4; ++ni) sacc[ni] = (f32x4){0.f, 0.f, 0.f, 0.f};
        __builtin_amdgcn_s_setprio(1);
#pragma unroll
        for (int kk = 0; kk < 4; ++kk) {
#pragma unroll
          for (int ni = 0; ni < 4; ++ni) {
            int krow = ni * 16 + lr;
            bf16x8 bfr = *(const bf16x8*)(Kbase + krow * 256 + ((kk * 64 + lk * 16) ^ ((krow & 7) << 4)));
            sacc[ni] = __builtin_amdgcn_mfma_f32_16x16x32_bf16(qf[kk], bfr, sacc[ni], 0, 0, 0);
          }
        }
        __builtin_amdgcn_s_setprio(0);

        // ---- mask + online softmax (additive mask; causal only on diag tile)
#pragma unroll
        for (int j = 0; j < 4; ++j) {
          int grow = q0 + wg * 16 + lk * 4 + j;
          float x[4]; float tmax = -FLT_MAX;
#pragma unroll
          for (int ni = 0; ni < 4; ++ni) {
            float v = fmaf(sacc[ni][j], INV_SQRT_HD, madd[ni]);
            if (diag && c0 + ni * 16 + lr > grow) v = NEG_MIN;
            x[ni] = v; tmax = fmaxf(tmax, v);
          }
          tmax = fmaxf(tmax, dpp_ror<0x121>(tmax));
          tmax = fmaxf(tmax, dpp_ror<0x122>(tmax));
          tmax = fmaxf(tmax, dpp_ror<0x124>(tmax));
          tmax = fmaxf(tmax, dpp_ror<0x128>(tmax));
          float mn = fmaxf(m[j], tmax);
          float psum = 0.f;
          int prow = wg * 16 + lk * 4 + j;
#pragma unroll
          for (int ni = 0; ni < 4; ++ni) {
            float p = __expf(x[ni] - mn);
            psum += p;
            *(ushort*)(Pbase + prow * 128 + ((2 * (ni * 16 + lr)) ^ ((prow & 7) << 4))) = f2bf(p);
          }
          psum += dpp_ror<0x121>(psum);
          psum += dpp_ror<0x122>(psum);
          psum += dpp_ror<0x124>(psum);
          psum += dpp_ror<0x128>(psum);
          if (mn > m[j]) {
            float sc = __expf(m[j] - mn);
            l[j] *= sc;
#pragma unroll
            for (int ni = 0; ni < 8; ++ni) acc_o[ni][j] *= sc;
            m[j] = mn;
          }
          l[j] += psum;
        }

        // ---- O += P V (same-wave Ps rows)
        __builtin_amdgcn_s_setprio(1);
#pragma unroll
        for (int kk = 0; kk < 2; ++kk) {
          int prow = wg * 16 + lr;
          bf16x8 a = *(const bf16x8*)(Pbase + prow * 128 + ((kk * 64 + lk * 16) ^ ((prow & 7) << 4)));
#pragma unroll
          for (int ni = 0; ni < 8; ++ni) {
            int vrow = ni * 16 + lr;
            bf16x8 bfr = *(const bf16x8*)(Vbase + vrow * 128 + ((kk * 64 + lk * 16) ^ ((vrow & 7) << 4)));
            acc_o[ni] = __builtin_amdgcn_mfma_f32_16x16x32_bf16(a, bfr, acc_o[ni], 0, 0, 0);
          }
        }
        __builtin_amdgcn_s_setprio(0);
      }
      cur ^= 1;
    }

    // ---- merge the two k-parity partials, write output (group 0)
    __syncthreads();   // all compute done; LDS reusable for merge
    if (lr == 0) {
#pragma unroll
      for (int j = 0; j < 4; ++j) {
        int r = wg * 16 + lk * 4 + j;
        smv[g * 64 + r] = m[j];
        slv[g * 64 + r] = l[j];
      }
    }
    __syncthreads();
    float myf[4], lcomb[4];
#pragma unroll
    for (int j = 0; j < 4; ++j) {
      int r = wg * 16 + lk * 4 + j;
      float m0 = smv[r], m1 = smv[64 + r];
      float l0 = slv[r], l1 = slv[64 + r];
      float mm = fmaxf(m0, m1);
      float f0 = __expf(m0 - mm), f1 = __expf(m1 - mm);
      lcomb[j] = l0 * f0 + l1 * f1;
      myf[j] = (g == 0) ? f0 : f1;
    }
    if (g == 1) {
#pragma unroll
      for (int j = 0; j < 4; ++j) {
        int r = wg * 16 + lk * 4 + j;
#pragma unroll
        for (int ni = 0; ni < 8; ++ni)
          accL[r * 132 + ni * 16 + lr] = acc_o[ni][j] * myf[j];
      }
    }
    __syncthreads();
    if (g == 0) {
#pragma unroll
      for (int j = 0; j < 4; ++j) {
        int row = q0 + wg * 16 + lk * 4 + j;
        int r = wg * 16 + lk * 4 + j;
        if (row < i0h) {
#pragma unroll
          for (int ni = 0; ni < 8; ++ni)
            ao[(size_t)row * 2048 + h * 128 + ni * 16 + lr] = f2bf(vmean[h * 128 + ni * 16 + lr]);
        } else {
          float inv = 1.f / lcomb[j];
#pragma unroll
          for (int ni = 0; ni < 8; ++ni) {
            float o = fmaf(acc_o[ni][j], myf[j], accL[r * 132 + ni * 16 + lr]);
            ao[(size_t)row * 2048 + h * 128 + ni * 16 + lr] = f2bf(o * inv);
          }
        }
      }
    }
  }
}

// ---------------------------------------------------------------------------
extern "C" void kernel_launch(void* const* d_in, const int* in_sizes, int n_in,
                              void* d_out, int out_size, void* d_ws, size_t ws_size,
                              hipStream_t stream)
{
  const float* hs    = (const float*)d_in[0];
  const float* amask = (const float*)d_in[1];
  const float* cosb  = (const float*)d_in[2];
  const float* sinb  = (const float*)d_in[3];
  const float* dmask = (const float*)d_in[4];
  const float* Wq    = (const float*)d_in[5];
  const float* Wk    = (const float*)d_in[6];
  const float* Wvq   = (const float*)d_in[7];
  const float* vkeys = (const float*)d_in[8];
  const float* vemb  = (const float*)d_in[9];
  const float* Wo    = (const float*)d_in[10];
  float* outp = (float*)d_out;

  char* ws = (char*)d_ws;
  const size_t MB = 1048576;
  float*  pvq     = (float*) (ws + 0);              // [0,32)
  float*  vq_f32  = (float*) (ws + 32*MB);          // [32,36)
  ushort* vq_bf   = (ushort*)(ws + 36*MB);          // [36,38)
  ushort* vkT     = (ushort*)(ws + 38*MB);          // [38,40)
  int*    cand    = (int*)   (ws + 40*MB);          // 256 KB
  int*    idx     = (int*)   (ws + 40*MB + 262144); // 128 KB
  float*  part    = (float*) (ws + 41*MB);          // 64 KB
  float*  vmean   = (float*) (ws + 41*MB + 65536);  // 8 KB
  int*    i0b     = (int*)   (ws + 41*MB + 73728);  // 64 B
  ushort* sim_bf  = (ushort*)(ws + 0);              // over dead pvq
  ushort* vb      = (ushort*)(ws + 0);
  ushort* vt      = (ushort*)(ws + 8*MB);
  ushort* hs_bf   = (ushort*)(ws + 16*MB);
  ushort* qkC     = (ushort*)(ws + 24*MB);          // fused q|k, ld 4096
  ushort* vemb_bf = (ushort*)(ws + 48*MB);
  ushort* WBig    = (ushort*)(ws + 48*MB);
  ushort* WoT     = (ushort*)(ws + 48*MB);
  ushort* ao      = (ushort*)(ws + 0);

  dim3 blk(256);
  // ---- routing path ----
  gemm_f32_sk<<<dim3(4, 16, 8), blk, 0, stream>>>(hs, 2048, Wvq, 512, pvq, 512, 2048, 512, 256);
  reduce8_cvt<<<dim3(1024), blk, 0, stream>>>(pvq, vq_f32, vq_bf);
  transpose_cvt<<<dim3(32, 2, 4), blk, 0, stream>>>(vkeys, vkT, 128, 2048, 262144, 262144);
  gemm_bf16<1><<<dim3(16, 16, 4), blk, 0, stream>>>(vq_bf, 512, vkT, 128,
      sim_bf, 2048, 128, 128, 262144, 4194304);
  topk8<<<dim3(2048), blk, 0, stream>>>(sim_bf, cand);
  recomp_sel<<<dim3(2048), blk, 0, stream>>>(vq_f32, vkeys, cand, idx);
  // ---- v construction ----
  cvt2_bf16<<<dim3(8192), blk, 0, stream>>>(vemb, vemb_bf, hs, hs_bf);
  gather_mul_bf<<<dim3(2048), blk, 0, stream>>>(hs, vemb_bf, idx, vb);
  transpose_bf<<<dim3(32, 32), blk, 0, stream>>>(vb, vt);
  vmean_part<<<dim3(8, 16), blk, 0, stream>>>(vb, part);
  vmean_i0<<<dim3(16), blk, 0, stream>>>(part, amask, dmask, vmean, i0b);
  // ---- projections (fused q|k) ----
  transpose_cvt<<<dim3(32, 32, 1), blk, 0, stream>>>(Wq, WBig, 2048, 2048, 0, 0);
  transpose_cvt<<<dim3(32, 32, 1), blk, 0, stream>>>(Wk, WBig + (size_t)2048 * 2048, 2048, 2048, 0, 0);
  gemm_bf16<1><<<dim3(32, 16, 1), blk, 0, stream>>>(hs_bf, 2048, WBig, 2048, qkC, 4096, 2048, 0, 0, 0);
  rope_q_bf<<<dim3(8192), blk, 0, stream>>>(qkC, cosb, sinb, 4096);
  // ---- attention ----
  transpose_cvt<<<dim3(32, 32, 1), blk, 0, stream>>>(Wo, WoT, 2048, 2048, 0, 0);
  attn_mfma<<<dim3(16, 16), dim3(512), 0, stream>>>(qkC, qkC + 2048, vt, amask, dmask, vmean, i0b, ao);
  // ---- output projection ----
  gemm_bf16<0><<<dim3(16, 16, 1), blk, 0, stream>>>(ao, 2048, WoT, 2048, outp, 2048, 2048, 0, 0, 0);
}

// Round 8
// 388.426 us; speedup vs baseline: 9.8133x; 1.0225x over previous
//
#include <hip/hip_runtime.h>
#include <float.h>

// B=1, S=2048, D=2048, H=16, HD=128, HV=4, R=128, NV=2048, K=4
#define NEG_MIN (-3.4028234663852886e38f)
#define INV_SQRT_HD 0.08838834764831845f

typedef __attribute__((ext_vector_type(8))) short bf16x8;
typedef __attribute__((ext_vector_type(8))) unsigned short u16x8;
typedef __attribute__((ext_vector_type(4))) float f32x4;

__device__ __forceinline__ void gload_lds16(const void* g, void* l) {
  __builtin_amdgcn_global_load_lds((const __attribute__((address_space(1))) void*)g,
                                   (__attribute__((address_space(3))) void*)l, 16, 0, 0);
}
__device__ __forceinline__ ushort f2bf(float x) {
  union { float f; unsigned u; } v; v.f = x;
  unsigned r = v.u + 0x7fffu + ((v.u >> 16) & 1u);   // RNE
  return (ushort)(r >> 16);
}
__device__ __forceinline__ float bf2f(ushort u) {
  union { unsigned i; float f; } v; v.i = ((unsigned)u) << 16; return v.f;
}
template<int CTRL>
__device__ __forceinline__ float dpp_ror(float x) {
  return __int_as_float(__builtin_amdgcn_mov_dpp(__float_as_int(x), CTRL, 0xF, 0xF, true));
}

// ---------------------------------------------------------------------------
// Split-K f32 GEMM, 128x128 tile, 8x8 microtile, reg double-buffered staging.
// ---------------------------------------------------------------------------
__global__ __launch_bounds__(256) void gemm_f32_sk(
    const float* __restrict__ A, int lda,
    const float* __restrict__ B, int ldb,
    float* __restrict__ Cp, int ldc, int M, int N, int Kchunk)
{
  __shared__ float As[16][132];
  __shared__ float Bs[16][132];
  const int t = threadIdx.x, tx = t & 15, ty = t >> 4;
  const int bm = blockIdx.y << 7, bn = blockIdx.x << 7;
  const int k0base = blockIdx.z * Kchunk;
  const int arr = t >> 2, ac = (t & 3) << 2;
  const int brr = t >> 5, bc = (t & 31) << 2;

  float acc[8][8];
#pragma unroll
  for (int i = 0; i < 8; ++i)
#pragma unroll
    for (int j = 0; j < 8; ++j) acc[i][j] = 0.f;

  float4 pa0, pa1, pb0, pb1;
  pa0 = *(const float4*)(A + (size_t)(bm + arr) * lda + k0base + ac);
  pa1 = *(const float4*)(A + (size_t)(bm + arr + 64) * lda + k0base + ac);
  pb0 = *(const float4*)(B + (size_t)(k0base + brr) * ldb + bn + bc);
  pb1 = *(const float4*)(B + (size_t)(k0base + brr + 8) * ldb + bn + bc);

  for (int k0 = 0; k0 < Kchunk; k0 += 16) {
    __syncthreads();
    As[ac + 0][arr] = pa0.x; As[ac + 1][arr] = pa0.y;
    As[ac + 2][arr] = pa0.z; As[ac + 3][arr] = pa0.w;
    As[ac + 0][arr + 64] = pa1.x; As[ac + 1][arr + 64] = pa1.y;
    As[ac + 2][arr + 64] = pa1.z; As[ac + 3][arr + 64] = pa1.w;
    *(float4*)(&Bs[brr][bc])     = pb0;
    *(float4*)(&Bs[brr + 8][bc]) = pb1;
    __syncthreads();
    if (k0 + 16 < Kchunk) {
      int kn = k0base + k0 + 16;
      pa0 = *(const float4*)(A + (size_t)(bm + arr) * lda + kn + ac);
      pa1 = *(const float4*)(A + (size_t)(bm + arr + 64) * lda + kn + ac);
      pb0 = *(const float4*)(B + (size_t)(kn + brr) * ldb + bn + bc);
      pb1 = *(const float4*)(B + (size_t)(kn + brr + 8) * ldb + bn + bc);
    }
#pragma unroll
    for (int kk = 0; kk < 16; ++kk) {
      float4 a0 = *(const float4*)(&As[kk][ty * 8]);
      float4 a1 = *(const float4*)(&As[kk][ty * 8 + 4]);
      float4 b0 = *(const float4*)(&Bs[kk][tx * 4]);
      float4 b1 = *(const float4*)(&Bs[kk][tx * 4 + 64]);
      float av[8] = {a0.x, a0.y, a0.z, a0.w, a1.x, a1.y, a1.z, a1.w};
      float bv[8] = {b0.x, b0.y, b0.z, b0.w, b1.x, b1.y, b1.z, b1.w};
#pragma unroll
      for (int i = 0; i < 8; ++i)
#pragma unroll
        for (int j = 0; j < 8; ++j)
          acc[i][j] = fmaf(av[i], bv[j], acc[i][j]);
    }
  }
  float* C = Cp + (size_t)blockIdx.z * M * N;
#pragma unroll
  for (int i = 0; i < 8; ++i) {
    int row = bm + ty * 8 + i;
    *(float4*)(C + (size_t)row * ldc + bn + tx * 4) =
        make_float4(acc[i][0], acc[i][1], acc[i][2], acc[i][3]);
    *(float4*)(C + (size_t)row * ldc + bn + tx * 4 + 64) =
        make_float4(acc[i][4], acc[i][5], acc[i][6], acc[i][7]);
  }
}

__global__ __launch_bounds__(256) void reduce8_cvt(const float* __restrict__ Cp,
    float* __restrict__ vq, ushort* __restrict__ vq_bf)
{
  int i = (blockIdx.x * 256 + threadIdx.x) << 2;
  float4 s = make_float4(0.f, 0.f, 0.f, 0.f);
#pragma unroll
  for (int z = 0; z < 8; ++z) {
    float4 a = *(const float4*)(Cp + (size_t)z * 1048576 + i);
    s.x += a.x; s.y += a.y; s.z += a.z; s.w += a.w;
  }
  *(float4*)(vq + i) = s;
  ushort4 o; o.x = f2bf(s.x); o.y = f2bf(s.y); o.z = f2bf(s.z); o.w = f2bf(s.w);
  *(ushort4*)(vq_bf + i) = o;
}

// ---------------------------------------------------------------------------
// bf16 MFMA GEMM (z-batched): C = A @ Bt^T. 128x128 tile, BK=64.
// ---------------------------------------------------------------------------
template<int OUT_BF16>
__global__ __launch_bounds__(256) void gemm_bf16(
    const ushort* __restrict__ A0, int lda,
    const ushort* __restrict__ Bt0, int ldb,
    void* __restrict__ C0, int ldc, int Kd,
    size_t strA, size_t strB, size_t strC)
{
  const ushort* A  = A0  + blockIdx.z * strA;
  const ushort* Bt = Bt0 + blockIdx.z * strB;
  __shared__ ushort As[128 * 64];
  __shared__ ushort Bs[128 * 64];
  const int t = threadIdx.x, w = t >> 6, lane = t & 63;
  const int lr = lane & 15, lk = lane >> 4;
  const int bm = blockIdx.y << 7, bn = blockIdx.x << 7;
  const int wm = (w >> 1) << 6, wn = (w & 1) << 6;
  f32x4 acc[4][4];
#pragma unroll
  for (int i = 0; i < 4; ++i)
#pragma unroll
    for (int j = 0; j < 4; ++j) acc[i][j] = (f32x4){0.f, 0.f, 0.f, 0.f};

  for (int k0 = 0; k0 < Kd; k0 += 64) {
    __syncthreads();
#pragma unroll
    for (int qI = 0; qI < 4; ++qI) {
      int b = w * 4096 + qI * 1024 + lane * 16;
      int row = b >> 7, colb = b & 127;
      int src = colb ^ ((row & 7) << 4);
      gload_lds16((const char*)A + ((size_t)(bm + row) * lda + k0) * 2 + src,
                  (char*)As + w * 4096 + qI * 1024);
    }
#pragma unroll
    for (int qI = 0; qI < 4; ++qI) {
      int b = w * 4096 + qI * 1024 + lane * 16;
      int row = b >> 7, colb = b & 127;
      int src = colb ^ ((row & 7) << 4);
      gload_lds16((const char*)Bt + ((size_t)(bn + row) * ldb + k0) * 2 + src,
                  (char*)Bs + w * 4096 + qI * 1024);
    }
    __syncthreads();
#pragma unroll
    for (int kk = 0; kk < 2; ++kk) {
      bf16x8 af[4], bf[4];
#pragma unroll
      for (int mi = 0; mi < 4; ++mi) {
        int row = wm + mi * 16 + lr;
        af[mi] = *(const bf16x8*)((const char*)As + row * 128 + ((kk * 64 + lk * 16) ^ ((row & 7) << 4)));
      }
#pragma unroll
      for (int ni = 0; ni < 4; ++ni) {
        int row = wn + ni * 16 + lr;
        bf[ni] = *(const bf16x8*)((const char*)Bs + row * 128 + ((kk * 64 + lk * 16) ^ ((row & 7) << 4)));
      }
#pragma unroll
      for (int mi = 0; mi < 4; ++mi)
#pragma unroll
        for (int ni = 0; ni < 4; ++ni)
          acc[mi][ni] = __builtin_amdgcn_mfma_f32_16x16x32_bf16(af[mi], bf[ni], acc[mi][ni], 0, 0, 0);
    }
  }
#pragma unroll
  for (int mi = 0; mi < 4; ++mi)
#pragma unroll
    for (int j = 0; j < 4; ++j) {
      int row = bm + wm + mi * 16 + lk * 4 + j;
#pragma unroll
      for (int ni = 0; ni < 4; ++ni) {
        int col = bn + wn + ni * 16 + lr;
        if (OUT_BF16) ((ushort*)C0)[blockIdx.z * strC + (size_t)row * ldc + col] = f2bf(acc[mi][ni][j]);
        else          ((float*)C0)[blockIdx.z * strC + (size_t)row * ldc + col]  = acc[mi][ni][j];
      }
    }
}

// ---------------------------------------------------------------------------
// transpose + f32->bf16 (z-batched, single source): dst[c][r] = src[r][c]
// ---------------------------------------------------------------------------
__global__ __launch_bounds__(256) void transpose_cvt(
    const float* __restrict__ src0, ushort* __restrict__ dst0, int R, int Cc,
    size_t zsrc, size_t zdst)
{
  const float* src = src0 + blockIdx.z * zsrc;
  ushort* dst = dst0 + blockIdx.z * zdst;
  __shared__ float tile[64][65];
  const int r0 = blockIdx.y << 6, c0 = blockIdx.x << 6;
  const int t = threadIdx.x;
  for (int i = t; i < 1024; i += 256) {
    int r = i >> 4, c = (i & 15) << 2;
    float4 v = *(const float4*)(src + (size_t)(r0 + r) * Cc + c0 + c);
    tile[r][c] = v.x; tile[r][c+1] = v.y; tile[r][c+2] = v.z; tile[r][c+3] = v.w;
  }
  __syncthreads();
  int c = t >> 2, rb = (t & 3) << 4;
#pragma unroll
  for (int u = 0; u < 16; u += 4) {
    ushort4 o;
    o.x = f2bf(tile[rb+u+0][c]); o.y = f2bf(tile[rb+u+1][c]);
    o.z = f2bf(tile[rb+u+2][c]); o.w = f2bf(tile[rb+u+3][c]);
    *(ushort4*)(dst + (size_t)(c0 + c) * R + r0 + rb + u) = o;
  }
}

// dual-source variant: z=0 -> srcA, z=1 -> srcB (2048x2048 each)
__global__ __launch_bounds__(256) void transpose_cvt_qk(
    const float* __restrict__ srcA, const float* __restrict__ srcB,
    ushort* __restrict__ dst0)
{
  const float* src = blockIdx.z ? srcB : srcA;
  ushort* dst = dst0 + (size_t)blockIdx.z * 4194304;
  __shared__ float tile[64][65];
  const int r0 = blockIdx.y << 6, c0 = blockIdx.x << 6;
  const int t = threadIdx.x;
  for (int i = t; i < 1024; i += 256) {
    int r = i >> 4, c = (i & 15) << 2;
    float4 v = *(const float4*)(src + (size_t)(r0 + r) * 2048 + c0 + c);
    tile[r][c] = v.x; tile[r][c+1] = v.y; tile[r][c+2] = v.z; tile[r][c+3] = v.w;
  }
  __syncthreads();
  int c = t >> 2, rb = (t & 3) << 4;
#pragma unroll
  for (int u = 0; u < 16; u += 4) {
    ushort4 o;
    o.x = f2bf(tile[rb+u+0][c]); o.y = f2bf(tile[rb+u+1][c]);
    o.z = f2bf(tile[rb+u+2][c]); o.w = f2bf(tile[rb+u+3][c]);
    *(ushort4*)(dst + (size_t)(c0 + c) * 2048 + r0 + rb + u) = o;
  }
}

// bf16 -> bf16 transpose (2048x2048)
__global__ __launch_bounds__(256) void transpose_bf(
    const ushort* __restrict__ src, ushort* __restrict__ dst)
{
  __shared__ ushort tile[64][66];
  const int r0 = blockIdx.y << 6, c0 = blockIdx.x << 6;
  const int t = threadIdx.x;
  for (int i = t; i < 512; i += 256) {
    int r = i >> 3, c8 = (i & 7) << 3;
    *(u16x8*)(&tile[r][c8]) = *(const u16x8*)(src + (size_t)(r0 + r) * 2048 + c0 + c8);
  }
  __syncthreads();
  for (int i = t; i < 512; i += 256) {
    int c = i >> 3, r8 = (i & 7) << 3;
    u16x8 o;
#pragma unroll
    for (int u = 0; u < 8; ++u) o[u] = tile[r8 + u][c];
    *(u16x8*)(dst + (size_t)(c0 + c) * 2048 + r0 + r8) = o;
  }
}

// two f32->bf16 conversions in one launch (4M elems each)
__global__ __launch_bounds__(256) void cvt2_bf16(const float* __restrict__ srcA,
    ushort* __restrict__ dstA, const float* __restrict__ srcB,
    ushort* __restrict__ dstB)
{
  int gid = blockIdx.x * 256 + threadIdx.x;
  const float* s; ushort* d; int i;
  if (gid < 1048576) { s = srcA; d = dstA; i = gid; }
  else               { s = srcB; d = dstB; i = gid - 1048576; }
  float4 v = ((const float4*)s)[i];
  ushort4 o; o.x = f2bf(v.x); o.y = f2bf(v.y); o.z = f2bf(v.z); o.w = f2bf(v.w);
  ((ushort4*)d)[i] = o;
}

// ---------------------------------------------------------------------------
// Candidate top-8 per sim row from bf16 sim (wave per row).
// ---------------------------------------------------------------------------
__global__ __launch_bounds__(256) void topk8(const ushort* __restrict__ sim,
                                             int* __restrict__ cand)
{
  const int row = blockIdx.x * 4 + (threadIdx.x >> 6);
  const int lane = threadIdx.x & 63;
  const ushort* r = sim + (size_t)row * 2048;
  float v[8]; int ix[8];
#pragma unroll
  for (int p = 0; p < 8; ++p) { v[p] = -FLT_MAX; ix[p] = 0x7fffffff; }
  for (int j = 0; j < 32; ++j) {
    int n = lane + (j << 6);
    float val = bf2f(r[n]);
    if (val > v[7]) {
      v[7] = val; ix[7] = n;
#pragma unroll
      for (int p = 7; p > 0; --p) {
        if (v[p] > v[p-1]) {
          float tv = v[p]; v[p] = v[p-1]; v[p-1] = tv;
          int   ti = ix[p]; ix[p] = ix[p-1]; ix[p-1] = ti;
        }
      }
    }
  }
  int head = 0;
  int out[8];
#pragma unroll
  for (int r8 = 0; r8 < 8; ++r8) {
    float cv = -FLT_MAX; int ci = 0x7fffffff;
#pragma unroll
    for (int p = 0; p < 8; ++p)
      if (p == head) { cv = v[p]; ci = ix[p]; }
#pragma unroll
    for (int d = 1; d < 64; d <<= 1) {
      float ov = __shfl_xor(cv, d); int oi = __shfl_xor(ci, d);
      if (ov > cv || (ov == cv && oi < ci)) { cv = ov; ci = oi; }
    }
    out[r8] = ci;
    bool mine = false;
#pragma unroll
    for (int p = 0; p < 8; ++p) if (p == head && ix[p] == ci) mine = true;
    if (mine) head++;
  }
  if (lane == 0) {
#pragma unroll
    for (int p = 0; p < 8; ++p) cand[(size_t)row * 8 + p] = out[p];
  }
}

// ---------------------------------------------------------------------------
// Exact f32 recompute of 8 candidates + exact top-4 (index tie-break).
// ---------------------------------------------------------------------------
__global__ __launch_bounds__(256) void recomp_sel(
    const float* __restrict__ vq, const float* __restrict__ vkeys,
    const int* __restrict__ cand, int* __restrict__ idxo)
{
  const int row = blockIdx.x * 4 + (threadIdx.x >> 6);
  const int hv = row >> 11, s = row & 2047;
  const int lane = threadIdx.x & 63;
  const int c = lane & 7, rc = lane >> 3;
  const int n = cand[(size_t)row * 8 + c];
  const float* vqr = vq + (size_t)s * 512 + hv * 128 + rc * 16;
  const float* vk  = vkeys + (size_t)hv * 262144 + (size_t)(rc * 16) * 2048 + n;
  float acc = 0.f;
#pragma unroll
  for (int u = 0; u < 16; ++u) acc = fmaf(vqr[u], vk[(size_t)u * 2048], acc);
  acc += __shfl_xor(acc, 8);
  acc += __shfl_xor(acc, 16);
  acc += __shfl_xor(acc, 32);
  float cv = acc; int ci = n;
  int picks[4];
#pragma unroll
  for (int p = 0; p < 4; ++p) {
    float bv = cv; int bi = ci;
#pragma unroll
    for (int d = 1; d < 8; d <<= 1) {
      float ov = __shfl_xor(bv, d); int oi = __shfl_xor(bi, d);
      if (ov > bv || (ov == bv && oi < bi)) { bv = ov; bi = oi; }
    }
    picks[p] = bi;
    if (bi == ci) cv = -FLT_MAX;
  }
  if (lane == 0) {
#pragma unroll
    for (int p = 0; p < 4; ++p) idxo[(size_t)row * 4 + p] = picks[p];
  }
}

// ---------------------------------------------------------------------------
__global__ __launch_bounds__(256) void gather_mul_bf(const float* __restrict__ hs,
    const ushort* __restrict__ vemb_bf, const int* __restrict__ idx,
    ushort* __restrict__ vb)
{
  const int s = blockIdx.x;
  const int t = threadIdx.x;
  __shared__ int id[16];
  if (t < 16) id[t] = idx[((size_t)(t >> 2) * 2048 + s) * 4 + (t & 3)];
  __syncthreads();
  int d0 = t << 3;
  float g[8] = {0.f, 0.f, 0.f, 0.f, 0.f, 0.f, 0.f, 0.f};
#pragma unroll
  for (int e = 0; e < 16; ++e) {
    u16x8 ve = *(const u16x8*)(vemb_bf + (size_t)id[e] * 2048 + d0);
#pragma unroll
    for (int u = 0; u < 8; ++u) g[u] += bf2f(ve[u]);
  }
  float4 h0 = *(const float4*)(hs + (size_t)s * 2048 + d0);
  float4 h1 = *(const float4*)(hs + (size_t)s * 2048 + d0 + 4);
  float hv[8] = {h0.x, h0.y, h0.z, h0.w, h1.x, h1.y, h1.z, h1.w};
  u16x8 o;
#pragma unroll
  for (int u = 0; u < 8; ++u) o[u] = f2bf(hv[u] * g[u]);
  *(u16x8*)(vb + (size_t)s * 2048 + d0) = o;
}

__global__ __launch_bounds__(256) void vmean_part(const ushort* __restrict__ vb,
                                                  float* __restrict__ part)
{
  const int h = blockIdx.y, chunk = blockIdx.x;
  const int t = threadIdx.x, d = t & 127, half = t >> 7;
  float s = 0.f;
  int r0 = chunk * 256 + half * 128;
  for (int r = r0; r < r0 + 128; ++r)
    s += bf2f(vb[(size_t)r * 2048 + h * 128 + d]);
  __shared__ float red[256];
  red[t] = s;
  __syncthreads();
  if (t < 128) part[(size_t)(h * 8 + chunk) * 128 + d] = red[t] + red[t + 128];
}

// fused: vmean finalize + first-unmasked-column scan (one block per head)
__global__ __launch_bounds__(256) void vmean_i0(const float* __restrict__ part,
    const float* __restrict__ amask, const float* __restrict__ dmask,
    float* __restrict__ vmean, int* __restrict__ i0)
{
  const int h = blockIdx.x, t = threadIdx.x;
  if (t < 128) {
    float s = 0.f;
#pragma unroll
    for (int c = 0; c < 8; ++c) s += part[(size_t)(h * 8 + c) * 128 + t];
    vmean[h * 128 + t] = s * (1.f / 2048.f);
  }
  int best = 0x7fffffff;
  for (int j = t; j < 2048; j += 256) {
    if (amask[j] * dmask[h * 2048 + j] != 0.f) { best = j; break; }
  }
  __shared__ int red[256];
  red[t] = best;
  __syncthreads();
  for (int off = 128; off > 0; off >>= 1) {
    if (t < off) red[t] = min(red[t], red[t + off]);
    __syncthreads();
  }
  if (t == 0) i0[h] = red[0];
}

__global__ __launch_bounds__(256) void rope_q_bf(ushort* __restrict__ q,
    const float* __restrict__ cosb, const float* __restrict__ sinb, int ld)
{
  int tid = blockIdx.x * 256 + threadIdx.x;
  int d = tid & 63, h = (tid >> 6) & 15, s = tid >> 10;
  size_t base = (size_t)s * ld + h * 128;
  float c0 = cosb[s*128 + d],      s0 = sinb[s*128 + d];
  float c1 = cosb[s*128 + d + 64], s1 = sinb[s*128 + d + 64];
  float a = bf2f(q[base + d]), b = bf2f(q[base + d + 64]);
  q[base + d]      = f2bf(a * c0 - b * s0);
  q[base + d + 64] = f2bf(b * c1 + a * s1);
}

// ---------------------------------------------------------------------------
// MFMA flash attention, stripe-paired, 8 waves = 2 k-parity groups x 4 row
// waves. XCD-aware block swizzle: all 16 pair-blocks of head h live on
// XCD h&7 (L%8 round-robin assumption) -> K/V L2-resident per XCD.
// Additive mask precomputed in LDS once per block.
// ---------------------------------------------------------------------------
#define QLD 4096
__global__ __launch_bounds__(512) void attn_mfma(
    const ushort* __restrict__ qb, const ushort* __restrict__ kb,
    const ushort* __restrict__ vt, const float* __restrict__ amask,
    const float* __restrict__ dmask, const float* __restrict__ vmean,
    const int* __restrict__ i0, ushort* __restrict__ ao)
{
  const int L  = blockIdx.x;
  const int pr = L >> 4;                               // pair 0..15
  const int h  = (L & 7) | (((L >> 3) & 1) << 3);      // head; L%8 == h%8
  const int t  = threadIdx.x, w = t >> 6, lane = t & 63;
  const int g  = w >> 2, wg = w & 3;                   // k-parity group, row-wave
  const int lr = lane & 15, lk = lane >> 4;

  // LDS: [0,64K) K tiles (g,buf); [64K,128K) V tiles; [128K,144K) Ps[g];
  //      [144K,152K) additive mask madd[2048]
  __shared__ char smem[155648];
  float* accL  = (float*)smem;                      // [64][132] f32 (merge)
  float* smv   = (float*)(smem + 33792);            // [2][64]
  float* slv   = (float*)(smem + 33792 + 512);      // [2][64]
  float* maddL = (float*)(smem + 147456);           // [2048]

  const int i0h = i0[h];

  // additive mask once per block
  for (int j = t; j < 2048; j += 512)
    maddL[j] = (amask[j] * dmask[h * 2048 + j] == 0.f) ? NEG_MIN : 0.f;

  for (int sp = 0; sp < 2; ++sp) {
    const int stripe = (sp == 0) ? pr : 31 - pr;
    const int q0 = stripe << 6;
    const int ntiles = stripe + 1;

    __syncthreads();   // LDS reusable (prev stripe done; maddL written)

    // Q fragments in registers (both groups need the same rows)
    const int qrow = q0 + wg * 16 + lr;
    bf16x8 qf[4];
#pragma unroll
    for (int kk = 0; kk < 4; ++kk)
      qf[kk] = *(const bf16x8*)(qb + (size_t)qrow * QLD + h * 128 + kk * 32 + lk * 8);

    // stage tile g (if any) into buf 0 of group g
    if (g < ntiles) {
      const int c0 = g << 6;
#pragma unroll
      for (int qI = 0; qI < 4; ++qI) {
        int b = wg * 4096 + qI * 1024 + lane * 16;
        int row = b >> 8, colb = b & 255;
        int src = colb ^ ((row & 7) << 4);
        gload_lds16((const char*)kb + ((size_t)(c0 + row) * QLD + h * 128) * 2 + src,
                    smem + g * 32768 + b);
      }
#pragma unroll
      for (int qI = 0; qI < 4; ++qI) {
        int b = wg * 4096 + qI * 1024 + lane * 16;
        int row = b >> 7, colb = b & 127;
        int src = colb ^ ((row & 7) << 4);
        gload_lds16((const char*)vt + ((size_t)(h * 128 + row) * 2048 + c0) * 2 + src,
                    smem + 65536 + g * 32768 + b);
      }
    }

    float m[4], l[4];
    f32x4 acc_o[8];
#pragma unroll
    for (int j = 0; j < 4; ++j) { m[j] = -FLT_MAX; l[j] = 0.f; }
#pragma unroll
    for (int ni = 0; ni < 8; ++ni) acc_o[ni] = (f32x4){0.f, 0.f, 0.f, 0.f};

    int cur = 0;
    const int niter = (ntiles + 1) >> 1;
    for (int it = 0; it < niter; ++it) {
      const int tile = 2 * it + g;
      const int c0 = tile << 6;
      __syncthreads();   // vmcnt(0) drain: buf[cur] ready for both groups

      float madd[4];
      if (tile < ntiles) {
#pragma unroll
        for (int ni = 0; ni < 4; ++ni)
          madd[ni] = maddL[c0 + ni * 16 + lr];
      }

      // prefetch tile+2 into buf cur^1
      if (tile + 2 < ntiles) {
        const int cn = c0 + 128;
        const int nb = cur ^ 1;
#pragma unroll
        for (int qI = 0; qI < 4; ++qI) {
          int b = wg * 4096 + qI * 1024 + lane * 16;
          int row = b >> 8, colb = b & 255;
          int src = colb ^ ((row & 7) << 4);
          gload_lds16((const char*)kb + ((size_t)(cn + row) * QLD + h * 128) * 2 + src,
                      smem + g * 32768 + nb * 16384 + b);
        }
#pragma unroll
        for (int qI = 0; qI < 4; ++qI) {
          int b = wg * 4096 + qI * 1024 + lane * 16;
          int row = b >> 7, colb = b & 127;
          int src = colb ^ ((row & 7) << 4);
          gload_lds16((const char*)vt + ((size_t)(h * 128 + row) * 2048 + cn) * 2 + src,
                      smem + 65536 + g * 32768 + nb * 16384 + b);
        }
      }

      if (tile < ntiles) {
        const bool diag = (tile == stripe);
        const char* Kbase = smem + g * 32768 + cur * 16384;
        const char* Vbase = smem + 65536 + g * 32768 + cur * 16384;
        char* Pbase = smem + 131072 + g * 8192;

        // ---- S = Q K^T
        f32x4 sacc[4];
#pragma unroll
        for (int ni = 0; ni < 4; ++ni) sacc[ni] = (f32x4){0.f, 0.f, 0.f, 0.f};
        __builtin_amdgcn_s_setprio(1);
#pragma unroll
        for (int kk = 0; kk < 4; ++kk) {
#pragma unroll
          for (int ni = 0; ni < 4; ++ni) {
            int krow = ni * 16 + lr;
            bf16x8 bfr = *(const bf16x8*)(Kbase + krow * 256 + ((kk * 64 + lk * 16) ^ ((krow & 7) << 4)));
            sacc[ni] = __builtin_amdgcn_mfma_f32_16x16x32_bf16(qf[kk], bfr, sacc[ni], 0, 0, 0);
          }
        }
        __builtin_amdgcn_s_setprio(0);

        // ---- mask + online softmax (additive mask; causal only on diag tile)
#pragma unroll
        for (int j = 0; j < 4; ++j) {
          int grow = q0 + wg * 16 + lk * 4 + j;
          float x[4]; float tmax = -FLT_MAX;
#pragma unroll
          for (int ni = 0; ni < 4; ++ni) {
            float v = fmaf(sacc[ni][j], INV_SQRT_HD, madd[ni]);
            if (diag && c0 + ni * 16 + lr > grow) v = NEG_MIN;
            x[ni] = v; tmax = fmaxf(tmax, v);
          }
          tmax = fmaxf(tmax, dpp_ror<0x121>(tmax));
          tmax = fmaxf(tmax, dpp_ror<0x122>(tmax));
          tmax = fmaxf(tmax, dpp_ror<0x124>(tmax));
          tmax = fmaxf(tmax, dpp_ror<0x128>(tmax));
          float mn = fmaxf(m[j], tmax);
          float psum = 0.f;
          int prow = wg * 16 + lk * 4 + j;
#pragma unroll
          for (int ni = 0; ni < 4; ++ni) {
            float p = __expf(x[ni] - mn);
            psum += p;
            *(ushort*)(Pbase + prow * 128 + ((2 * (ni * 16 + lr)) ^ ((prow & 7) << 4))) = f2bf(p);
          }
          psum += dpp_ror<0x121>(psum);
          psum += dpp_ror<0x122>(psum);
          psum += dpp_ror<0x124>(psum);
          psum += dpp_ror<0x128>(psum);
          if (mn > m[j]) {
            float sc = __expf(m[j] - mn);
            l[j] *= sc;
#pragma unroll
            for (int ni = 0; ni < 8; ++ni) acc_o[ni][j] *= sc;
            m[j] = mn;
          }
          l[j] += psum;
        }

        // ---- O += P V (same-wave Ps rows)
        __builtin_amdgcn_s_setprio(1);
#pragma unroll
        for (int kk = 0; kk < 2; ++kk) {
          int prow = wg * 16 + lr;
          bf16x8 a = *(const bf16x8*)(Pbase + prow * 128 + ((kk * 64 + lk * 16) ^ ((prow & 7) << 4)));
#pragma unroll
          for (int ni = 0; ni < 8; ++ni) {
            int vrow = ni * 16 + lr;
            bf16x8 bfr = *(const bf16x8*)(Vbase + vrow * 128 + ((kk * 64 + lk * 16) ^ ((vrow & 7) << 4)));
            acc_o[ni] = __builtin_amdgcn_mfma_f32_16x16x32_bf16(a, bfr, acc_o[ni], 0, 0, 0);
          }
        }
        __builtin_amdgcn_s_setprio(0);
      }
      cur ^= 1;
    }

    // ---- merge the two k-parity partials, write output (group 0)
    __syncthreads();
    if (lr == 0) {
#pragma unroll
      for (int j = 0; j < 4; ++j) {
        int r = wg * 16 + lk * 4 + j;
        smv[g * 64 + r] = m[j];
        slv[g * 64 + r] = l[j];
      }
    }
    __syncthreads();
    float myf[4], lcomb[4];
#pragma unroll
    for (int j = 0; j < 4; ++j) {
      int r = wg * 16 + lk * 4 + j;
      float m0 = smv[r], m1 = smv[64 + r];
      float l0 = slv[r], l1 = slv[64 + r];
      float mm = fmaxf(m0, m1);
      float f0 = __expf(m0 - mm), f1 = __expf(m1 - mm);
      lcomb[j] = l0 * f0 + l1 * f1;
      myf[j] = (g == 0) ? f0 : f1;
    }
    if (g == 1) {
#pragma unroll
      for (int j = 0; j < 4; ++j) {
        int r = wg * 16 + lk * 4 + j;
#pragma unroll
        for (int ni = 0; ni < 8; ++ni)
          accL[r * 132 + ni * 16 + lr] = acc_o[ni][j] * myf[j];
      }
    }
    __syncthreads();
    if (g == 0) {
#pragma unroll
      for (int j = 0; j < 4; ++j) {
        int row = q0 + wg * 16 + lk * 4 + j;
        int r = wg * 16 + lk * 4 + j;
        if (row < i0h) {
#pragma unroll
          for (int ni = 0; ni < 8; ++ni)
            ao[(size_t)row * 2048 + h * 128 + ni * 16 + lr] = f2bf(vmean[h * 128 + ni * 16 + lr]);
        } else {
          float inv = 1.f / lcomb[j];
#pragma unroll
          for (int ni = 0; ni < 8; ++ni) {
            float o = fmaf(acc_o[ni][j], myf[j], accL[r * 132 + ni * 16 + lr]);
            ao[(size_t)row * 2048 + h * 128 + ni * 16 + lr] = f2bf(o * inv);
          }
        }
      }
    }
  }
}

// ---------------------------------------------------------------------------
extern "C" void kernel_launch(void* const* d_in, const int* in_sizes, int n_in,
                              void* d_out, int out_size, void* d_ws, size_t ws_size,
                              hipStream_t stream)
{
  const float* hs    = (const float*)d_in[0];
  const float* amask = (const float*)d_in[1];
  const float* cosb  = (const float*)d_in[2];
  const float* sinb  = (const float*)d_in[3];
  const float* dmask = (const float*)d_in[4];
  const float* Wq    = (const float*)d_in[5];
  const float* Wk    = (const float*)d_in[6];
  const float* Wvq   = (const float*)d_in[7];
  const float* vkeys = (const float*)d_in[8];
  const float* vemb  = (const float*)d_in[9];
  const float* Wo    = (const float*)d_in[10];
  float* outp = (float*)d_out;

  char* ws = (char*)d_ws;
  const size_t MB = 1048576;
  float*  pvq     = (float*) (ws + 0);              // [0,32)
  float*  vq_f32  = (float*) (ws + 32*MB);          // [32,36)
  ushort* vq_bf   = (ushort*)(ws + 36*MB);          // [36,38)
  ushort* vkT     = (ushort*)(ws + 38*MB);          // [38,40)
  int*    cand    = (int*)   (ws + 40*MB);          // 256 KB
  int*    idx     = (int*)   (ws + 40*MB + 262144); // 128 KB
  float*  part    = (float*) (ws + 41*MB);          // 64 KB
  float*  vmean   = (float*) (ws + 41*MB + 65536);  // 8 KB
  int*    i0b     = (int*)   (ws + 41*MB + 73728);  // 64 B
  ushort* sim_bf  = (ushort*)(ws + 0);              // over dead pvq
  ushort* vb      = (ushort*)(ws + 0);
  ushort* vt      = (ushort*)(ws + 8*MB);
  ushort* hs_bf   = (ushort*)(ws + 16*MB);
  ushort* qkC     = (ushort*)(ws + 24*MB);          // fused q|k, ld 4096
  ushort* vemb_bf = (ushort*)(ws + 48*MB);
  ushort* WBig    = (ushort*)(ws + 48*MB);
  ushort* WoT     = (ushort*)(ws + 48*MB);
  ushort* ao      = (ushort*)(ws + 0);

  dim3 blk(256);
  // ---- routing path ----
  gemm_f32_sk<<<dim3(4, 16, 8), blk, 0, stream>>>(hs, 2048, Wvq, 512, pvq, 512, 2048, 512, 256);
  reduce8_cvt<<<dim3(1024), blk, 0, stream>>>(pvq, vq_f32, vq_bf);
  transpose_cvt<<<dim3(32, 2, 4), blk, 0, stream>>>(vkeys, vkT, 128, 2048, 262144, 262144);
  gemm_bf16<1><<<dim3(16, 16, 4), blk, 0, stream>>>(vq_bf, 512, vkT, 128,
      sim_bf, 2048, 128, 128, 262144, 4194304);
  topk8<<<dim3(2048), blk, 0, stream>>>(sim_bf, cand);
  recomp_sel<<<dim3(2048), blk, 0, stream>>>(vq_f32, vkeys, cand, idx);
  // ---- v construction ----
  cvt2_bf16<<<dim3(8192), blk, 0, stream>>>(vemb, vemb_bf, hs, hs_bf);
  gather_mul_bf<<<dim3(2048), blk, 0, stream>>>(hs, vemb_bf, idx, vb);
  transpose_bf<<<dim3(32, 32), blk, 0, stream>>>(vb, vt);
  vmean_part<<<dim3(8, 16), blk, 0, stream>>>(vb, part);
  vmean_i0<<<dim3(16), blk, 0, stream>>>(part, amask, dmask, vmean, i0b);
  // ---- projections (fused q|k; Wq+Wk transposed in one z=2 launch) ----
  transpose_cvt_qk<<<dim3(32, 32, 2), blk, 0, stream>>>(Wq, Wk, WBig);
  gemm_bf16<1><<<dim3(32, 16, 1), blk, 0, stream>>>(hs_bf, 2048, WBig, 2048, qkC, 4096, 2048, 0, 0, 0);
  rope_q_bf<<<dim3(8192), blk, 0, stream>>>(qkC, cosb, sinb, 4096);
  // ---- attention (XCD-swizzled 1D grid) ----
  transpose_cvt<<<dim3(32, 32, 1), blk, 0, stream>>>(Wo, WoT, 2048, 2048, 0, 0);
  attn_mfma<<<dim3(256), dim3(512), 0, stream>>>(qkC, qkC + 2048, vt, amask, dmask, vmean, i0b, ao);
  // ---- output projection ----
  gemm_bf16<0><<<dim3(16, 16, 1), blk, 0, stream>>>(ao, 2048, WoT, 2048, outp, 2048, 2048, 0, 0, 0);
}

// Round 9
// 382.922 us; speedup vs baseline: 9.9544x; 1.0144x over previous
//
#include <hip/hip_runtime.h>
#include <float.h>

// B=1, S=2048, D=2048, H=16, HD=128, HV=4, R=128, NV=2048, K=4
#define NEG_MIN (-3.4028234663852886e38f)
#define INV_SQRT_HD 0.08838834764831845f
#define SCALE_L2E 0.12751791437968458f    // INV_SQRT_HD * log2(e)

typedef __attribute__((ext_vector_type(8))) short bf16x8;
typedef __attribute__((ext_vector_type(8))) unsigned short u16x8;
typedef __attribute__((ext_vector_type(4))) float f32x4;

__device__ __forceinline__ void gload_lds16(const void* g, void* l) {
  __builtin_amdgcn_global_load_lds((const __attribute__((address_space(1))) void*)g,
                                   (__attribute__((address_space(3))) void*)l, 16, 0, 0);
}
__device__ __forceinline__ ushort f2bf(float x) {
  union { float f; unsigned u; } v; v.f = x;
  unsigned r = v.u + 0x7fffu + ((v.u >> 16) & 1u);   // RNE
  return (ushort)(r >> 16);
}
__device__ __forceinline__ float bf2f(ushort u) {
  union { unsigned i; float f; } v; v.i = ((unsigned)u) << 16; return v.f;
}
template<int CTRL>
__device__ __forceinline__ float dpp_ror(float x) {
  return __int_as_float(__builtin_amdgcn_mov_dpp(__float_as_int(x), CTRL, 0xF, 0xF, true));
}

// ---------------------------------------------------------------------------
// Split-K f32 GEMM, 128x128 tile, 8x8 microtile, reg double-buffered staging.
// z=16 K-split (Kchunk=128) -> 1024 blocks, 4 waves/SIMD (R8: 512 blocks was
// the occupancy limiter). Exact-f32 path for vq.
// ---------------------------------------------------------------------------
__global__ __launch_bounds__(256) void gemm_f32_sk(
    const float* __restrict__ A, int lda,
    const float* __restrict__ B, int ldb,
    float* __restrict__ Cp, int ldc, int M, int N, int Kchunk)
{
  __shared__ float As[16][132];
  __shared__ float Bs[16][132];
  const int t = threadIdx.x, tx = t & 15, ty = t >> 4;
  const int bm = blockIdx.y << 7, bn = blockIdx.x << 7;
  const int k0base = blockIdx.z * Kchunk;
  const int arr = t >> 2, ac = (t & 3) << 2;
  const int brr = t >> 5, bc = (t & 31) << 2;

  float acc[8][8];
#pragma unroll
  for (int i = 0; i < 8; ++i)
#pragma unroll
    for (int j = 0; j < 8; ++j) acc[i][j] = 0.f;

  float4 pa0, pa1, pb0, pb1;
  pa0 = *(const float4*)(A + (size_t)(bm + arr) * lda + k0base + ac);
  pa1 = *(const float4*)(A + (size_t)(bm + arr + 64) * lda + k0base + ac);
  pb0 = *(const float4*)(B + (size_t)(k0base + brr) * ldb + bn + bc);
  pb1 = *(const float4*)(B + (size_t)(k0base + brr + 8) * ldb + bn + bc);

  for (int k0 = 0; k0 < Kchunk; k0 += 16) {
    __syncthreads();
    As[ac + 0][arr] = pa0.x; As[ac + 1][arr] = pa0.y;
    As[ac + 2][arr] = pa0.z; As[ac + 3][arr] = pa0.w;
    As[ac + 0][arr + 64] = pa1.x; As[ac + 1][arr + 64] = pa1.y;
    As[ac + 2][arr + 64] = pa1.z; As[ac + 3][arr + 64] = pa1.w;
    *(float4*)(&Bs[brr][bc])     = pb0;
    *(float4*)(&Bs[brr + 8][bc]) = pb1;
    __syncthreads();
    if (k0 + 16 < Kchunk) {
      int kn = k0base + k0 + 16;
      pa0 = *(const float4*)(A + (size_t)(bm + arr) * lda + kn + ac);
      pa1 = *(const float4*)(A + (size_t)(bm + arr + 64) * lda + kn + ac);
      pb0 = *(const float4*)(B + (size_t)(kn + brr) * ldb + bn + bc);
      pb1 = *(const float4*)(B + (size_t)(kn + brr + 8) * ldb + bn + bc);
    }
#pragma unroll
    for (int kk = 0; kk < 16; ++kk) {
      float4 a0 = *(const float4*)(&As[kk][ty * 8]);
      float4 a1 = *(const float4*)(&As[kk][ty * 8 + 4]);
      float4 b0 = *(const float4*)(&Bs[kk][tx * 4]);
      float4 b1 = *(const float4*)(&Bs[kk][tx * 4 + 64]);
      float av[8] = {a0.x, a0.y, a0.z, a0.w, a1.x, a1.y, a1.z, a1.w};
      float bv[8] = {b0.x, b0.y, b0.z, b0.w, b1.x, b1.y, b1.z, b1.w};
#pragma unroll
      for (int i = 0; i < 8; ++i)
#pragma unroll
        for (int j = 0; j < 8; ++j)
          acc[i][j] = fmaf(av[i], bv[j], acc[i][j]);
    }
  }
  float* C = Cp + (size_t)blockIdx.z * M * N;
#pragma unroll
  for (int i = 0; i < 8; ++i) {
    int row = bm + ty * 8 + i;
    *(float4*)(C + (size_t)row * ldc + bn + tx * 4) =
        make_float4(acc[i][0], acc[i][1], acc[i][2], acc[i][3]);
    *(float4*)(C + (size_t)row * ldc + bn + tx * 4 + 64) =
        make_float4(acc[i][4], acc[i][5], acc[i][6], acc[i][7]);
  }
}

// deterministic 16-way reduce of split-K partials + bf16 copy (1M floats)
__global__ __launch_bounds__(256) void reduce16_cvt(const float* __restrict__ Cp,
    float* __restrict__ vq, ushort* __restrict__ vq_bf)
{
  int i = (blockIdx.x * 256 + threadIdx.x) << 2;
  float4 s = make_float4(0.f, 0.f, 0.f, 0.f);
#pragma unroll
  for (int z = 0; z < 16; ++z) {
    float4 a = *(const float4*)(Cp + (size_t)z * 1048576 + i);
    s.x += a.x; s.y += a.y; s.z += a.z; s.w += a.w;
  }
  *(float4*)(vq + i) = s;
  ushort4 o; o.x = f2bf(s.x); o.y = f2bf(s.y); o.z = f2bf(s.z); o.w = f2bf(s.w);
  *(ushort4*)(vq_bf + i) = o;
}

// ---------------------------------------------------------------------------
// bf16 MFMA GEMM (z-batched): C = A @ Bt^T. 128x128 tile, BK=64.
// ROPE=1: fused RoPE epilogue for q-region blocks (bn<16); tile == one head.
// ---------------------------------------------------------------------------
template<int OUT_BF16, int ROPE>
__global__ __launch_bounds__(256) void gemm_bf16(
    const ushort* __restrict__ A0, int lda,
    const ushort* __restrict__ Bt0, int ldb,
    void* __restrict__ C0, int ldc, int Kd,
    size_t strA, size_t strB, size_t strC,
    const float* __restrict__ cosb, const float* __restrict__ sinb)
{
  const ushort* A  = A0  + blockIdx.z * strA;
  const ushort* Bt = Bt0 + blockIdx.z * strB;
  __shared__ ushort smem_g[2 * 128 * 64];     // As | Bs ; reused as rope buffer
  ushort* As = smem_g;
  ushort* Bs = smem_g + 128 * 64;
  const int t = threadIdx.x, w = t >> 6, lane = t & 63;
  const int lr = lane & 15, lk = lane >> 4;
  const int bm = blockIdx.y << 7, bn = blockIdx.x << 7;
  const int wm = (w >> 1) << 6, wn = (w & 1) << 6;
  f32x4 acc[4][4];
#pragma unroll
  for (int i = 0; i < 4; ++i)
#pragma unroll
    for (int j = 0; j < 4; ++j) acc[i][j] = (f32x4){0.f, 0.f, 0.f, 0.f};

  for (int k0 = 0; k0 < Kd; k0 += 64) {
    __syncthreads();
#pragma unroll
    for (int qI = 0; qI < 4; ++qI) {
      int b = w * 4096 + qI * 1024 + lane * 16;
      int row = b >> 7, colb = b & 127;
      int src = colb ^ ((row & 7) << 4);
      gload_lds16((const char*)A + ((size_t)(bm + row) * lda + k0) * 2 + src,
                  (char*)As + w * 4096 + qI * 1024);
    }
#pragma unroll
    for (int qI = 0; qI < 4; ++qI) {
      int b = w * 4096 + qI * 1024 + lane * 16;
      int row = b >> 7, colb = b & 127;
      int src = colb ^ ((row & 7) << 4);
      gload_lds16((const char*)Bt + ((size_t)(bn + row) * ldb + k0) * 2 + src,
                  (char*)Bs + w * 4096 + qI * 1024);
    }
    __syncthreads();
#pragma unroll
    for (int kk = 0; kk < 2; ++kk) {
      bf16x8 af[4], bf[4];
#pragma unroll
      for (int mi = 0; mi < 4; ++mi) {
        int row = wm + mi * 16 + lr;
        af[mi] = *(const bf16x8*)((const char*)As + row * 128 + ((kk * 64 + lk * 16) ^ ((row & 7) << 4)));
      }
#pragma unroll
      for (int ni = 0; ni < 4; ++ni) {
        int row = wn + ni * 16 + lr;
        bf[ni] = *(const bf16x8*)((const char*)Bs + row * 128 + ((kk * 64 + lk * 16) ^ ((row & 7) << 4)));
      }
#pragma unroll
      for (int mi = 0; mi < 4; ++mi)
#pragma unroll
        for (int ni = 0; ni < 4; ++ni)
          acc[mi][ni] = __builtin_amdgcn_mfma_f32_16x16x32_bf16(af[mi], bf[ni], acc[mi][ni], 0, 0, 0);
    }
  }

  if (ROPE && blockIdx.x < 16) {
    // q-region: tile = head blockIdx.x, cols = d 0..127. RoPE via LDS exchange.
    __syncthreads();
    ushort* Pl = smem_g;    // [128][128] bf16 = 32 KB
#pragma unroll
    for (int mi = 0; mi < 4; ++mi)
#pragma unroll
      for (int j = 0; j < 4; ++j) {
        int rl = wm + mi * 16 + lk * 4 + j;
#pragma unroll
        for (int ni = 0; ni < 4; ++ni)
          Pl[rl * 128 + wn + ni * 16 + lr] = f2bf(acc[mi][ni][j]);
      }
    __syncthreads();
    const bool lo = (wn == 0);    // wave-uniform: d < 64
#pragma unroll
    for (int mi = 0; mi < 4; ++mi)
#pragma unroll
      for (int j = 0; j < 4; ++j) {
        int rl = wm + mi * 16 + lk * 4 + j;
        int row = bm + rl;
#pragma unroll
        for (int ni = 0; ni < 4; ++ni) {
          int d = wn + ni * 16 + lr;
          float a = bf2f(Pl[rl * 128 + d]);
          float b = bf2f(Pl[rl * 128 + (d ^ 64)]);
          float cs = cosb[row * 128 + d], sn = sinb[row * 128 + d];
          float v = lo ? (a * cs - b * sn) : (a * cs + b * sn);
          ((ushort*)C0)[(size_t)row * ldc + bn + d] = f2bf(v);
        }
      }
    return;
  }

#pragma unroll
  for (int mi = 0; mi < 4; ++mi)
#pragma unroll
    for (int j = 0; j < 4; ++j) {
      int row = bm + wm + mi * 16 + lk * 4 + j;
#pragma unroll
      for (int ni = 0; ni < 4; ++ni) {
        int col = bn + wn + ni * 16 + lr;
        if (OUT_BF16) ((ushort*)C0)[blockIdx.z * strC + (size_t)row * ldc + col] = f2bf(acc[mi][ni][j]);
        else          ((float*)C0)[blockIdx.z * strC + (size_t)row * ldc + col]  = acc[mi][ni][j];
      }
    }
}

// ---------------------------------------------------------------------------
// transpose + f32->bf16 (z-batched, single source): dst[c][r] = src[r][c]
// ---------------------------------------------------------------------------
__global__ __launch_bounds__(256) void transpose_cvt(
    const float* __restrict__ src0, ushort* __restrict__ dst0, int R, int Cc,
    size_t zsrc, size_t zdst)
{
  const float* src = src0 + blockIdx.z * zsrc;
  ushort* dst = dst0 + blockIdx.z * zdst;
  __shared__ float tile[64][65];
  const int r0 = blockIdx.y << 6, c0 = blockIdx.x << 6;
  const int t = threadIdx.x;
  for (int i = t; i < 1024; i += 256) {
    int r = i >> 4, c = (i & 15) << 2;
    float4 v = *(const float4*)(src + (size_t)(r0 + r) * Cc + c0 + c);
    tile[r][c] = v.x; tile[r][c+1] = v.y; tile[r][c+2] = v.z; tile[r][c+3] = v.w;
  }
  __syncthreads();
  int c = t >> 2, rb = (t & 3) << 4;
#pragma unroll
  for (int u = 0; u < 16; u += 4) {
    ushort4 o;
    o.x = f2bf(tile[rb+u+0][c]); o.y = f2bf(tile[rb+u+1][c]);
    o.z = f2bf(tile[rb+u+2][c]); o.w = f2bf(tile[rb+u+3][c]);
    *(ushort4*)(dst + (size_t)(c0 + c) * R + r0 + rb + u) = o;
  }
}

// triple-source weight transpose: z=0 Wq, z=1 Wk, z=2 Wo (2048x2048 each)
__global__ __launch_bounds__(256) void transpose_cvt_w3(
    const float* __restrict__ srcA, const float* __restrict__ srcB,
    const float* __restrict__ srcC, ushort* __restrict__ dst0)
{
  const float* src = (blockIdx.z == 0) ? srcA : (blockIdx.z == 1) ? srcB : srcC;
  ushort* dst = dst0 + (size_t)blockIdx.z * 4194304;
  __shared__ float tile[64][65];
  const int r0 = blockIdx.y << 6, c0 = blockIdx.x << 6;
  const int t = threadIdx.x;
  for (int i = t; i < 1024; i += 256) {
    int r = i >> 4, c = (i & 15) << 2;
    float4 v = *(const float4*)(src + (size_t)(r0 + r) * 2048 + c0 + c);
    tile[r][c] = v.x; tile[r][c+1] = v.y; tile[r][c+2] = v.z; tile[r][c+3] = v.w;
  }
  __syncthreads();
  int c = t >> 2, rb = (t & 3) << 4;
#pragma unroll
  for (int u = 0; u < 16; u += 4) {
    ushort4 o;
    o.x = f2bf(tile[rb+u+0][c]); o.y = f2bf(tile[rb+u+1][c]);
    o.z = f2bf(tile[rb+u+2][c]); o.w = f2bf(tile[rb+u+3][c]);
    *(ushort4*)(dst + (size_t)(c0 + c) * 2048 + r0 + rb + u) = o;
  }
}

// bf16 -> bf16 transpose (2048x2048)
__global__ __launch_bounds__(256) void transpose_bf(
    const ushort* __restrict__ src, ushort* __restrict__ dst)
{
  __shared__ ushort tile[64][66];
  const int r0 = blockIdx.y << 6, c0 = blockIdx.x << 6;
  const int t = threadIdx.x;
  for (int i = t; i < 512; i += 256) {
    int r = i >> 3, c8 = (i & 7) << 3;
    *(u16x8*)(&tile[r][c8]) = *(const u16x8*)(src + (size_t)(r0 + r) * 2048 + c0 + c8);
  }
  __syncthreads();
  for (int i = t; i < 512; i += 256) {
    int c = i >> 3, r8 = (i & 7) << 3;
    u16x8 o;
#pragma unroll
    for (int u = 0; u < 8; ++u) o[u] = tile[r8 + u][c];
    *(u16x8*)(dst + (size_t)(c0 + c) * 2048 + r0 + r8) = o;
  }
}

// two f32->bf16 conversions in one launch (4M elems each)
__global__ __launch_bounds__(256) void cvt2_bf16(const float* __restrict__ srcA,
    ushort* __restrict__ dstA, const float* __restrict__ srcB,
    ushort* __restrict__ dstB)
{
  int gid = blockIdx.x * 256 + threadIdx.x;
  const float* s; ushort* d; int i;
  if (gid < 1048576) { s = srcA; d = dstA; i = gid; }
  else               { s = srcB; d = dstB; i = gid - 1048576; }
  float4 v = ((const float4*)s)[i];
  ushort4 o; o.x = f2bf(v.x); o.y = f2bf(v.y); o.z = f2bf(v.z); o.w = f2bf(v.w);
  ((ushort4*)d)[i] = o;
}

// ---------------------------------------------------------------------------
// Fused: top-8 candidates from bf16 sim + exact f32 recompute + exact top-4.
// One wave per row. Tie-break lower index (matches jax.lax.top_k).
// ---------------------------------------------------------------------------
__global__ __launch_bounds__(256) void topk_sel(const ushort* __restrict__ sim,
    const float* __restrict__ vq, const float* __restrict__ vkeys,
    int* __restrict__ idxo)
{
  const int row = blockIdx.x * 4 + (threadIdx.x >> 6);
  const int hv = row >> 11, s = row & 2047;
  const int lane = threadIdx.x & 63;
  const ushort* r = sim + (size_t)row * 2048;
  // ---- phase 1: per-lane top-8 + wave-merge (all lanes end with out[0..7])
  float v[8]; int ix[8];
#pragma unroll
  for (int p = 0; p < 8; ++p) { v[p] = -FLT_MAX; ix[p] = 0x7fffffff; }
  for (int j = 0; j < 32; ++j) {
    int n = lane + (j << 6);
    float val = bf2f(r[n]);
    if (val > v[7]) {
      v[7] = val; ix[7] = n;
#pragma unroll
      for (int p = 7; p > 0; --p) {
        if (v[p] > v[p-1]) {
          float tv = v[p]; v[p] = v[p-1]; v[p-1] = tv;
          int   ti = ix[p]; ix[p] = ix[p-1]; ix[p-1] = ti;
        }
      }
    }
  }
  int head = 0;
  int out[8];
#pragma unroll
  for (int r8 = 0; r8 < 8; ++r8) {
    float cv = -FLT_MAX; int ci = 0x7fffffff;
#pragma unroll
    for (int p = 0; p < 8; ++p)
      if (p == head) { cv = v[p]; ci = ix[p]; }
#pragma unroll
    for (int d = 1; d < 64; d <<= 1) {
      float ov = __shfl_xor(cv, d); int oi = __shfl_xor(ci, d);
      if (ov > cv || (ov == cv && oi < ci)) { cv = ov; ci = oi; }
    }
    out[r8] = ci;
    bool mine = false;
#pragma unroll
    for (int p = 0; p < 8; ++p) if (p == head && ix[p] == ci) mine = true;
    if (mine) head++;
  }
  // ---- phase 2: exact f32 recompute of the 8 candidates + exact top-4
  const int c = lane & 7, rc = lane >> 3;
  int n = 0x7fffffff;
#pragma unroll
  for (int p = 0; p < 8; ++p) if (p == c) n = out[p];
  const float* vqr = vq + (size_t)s * 512 + hv * 128 + rc * 16;
  const float* vk  = vkeys + (size_t)hv * 262144 + (size_t)(rc * 16) * 2048 + n;
  float acc = 0.f;
#pragma unroll
  for (int u = 0; u < 16; ++u) acc = fmaf(vqr[u], vk[(size_t)u * 2048], acc);
  acc += __shfl_xor(acc, 8);
  acc += __shfl_xor(acc, 16);
  acc += __shfl_xor(acc, 32);
  float cv = acc; int ci = n;
  int picks[4];
#pragma unroll
  for (int p = 0; p < 4; ++p) {
    float bv = cv; int bi = ci;
#pragma unroll
    for (int d = 1; d < 8; d <<= 1) {
      float ov = __shfl_xor(bv, d); int oi = __shfl_xor(bi, d);
      if (ov > bv || (ov == bv && oi < bi)) { bv = ov; bi = oi; }
    }
    picks[p] = bi;
    if (bi == ci) cv = -FLT_MAX;
  }
  if (lane == 0) {
#pragma unroll
    for (int p = 0; p < 4; ++p) idxo[(size_t)row * 4 + p] = picks[p];
  }
}

// ---------------------------------------------------------------------------
__global__ __launch_bounds__(256) void gather_mul_bf(const float* __restrict__ hs,
    const ushort* __restrict__ vemb_bf, const int* __restrict__ idx,
    ushort* __restrict__ vb)
{
  const int s = blockIdx.x;
  const int t = threadIdx.x;
  __shared__ int id[16];
  if (t < 16) id[t] = idx[((size_t)(t >> 2) * 2048 + s) * 4 + (t & 3)];
  __syncthreads();
  int d0 = t << 3;
  float g[8] = {0.f, 0.f, 0.f, 0.f, 0.f, 0.f, 0.f, 0.f};
#pragma unroll
  for (int e = 0; e < 16; ++e) {
    u16x8 ve = *(const u16x8*)(vemb_bf + (size_t)id[e] * 2048 + d0);
#pragma unroll
    for (int u = 0; u < 8; ++u) g[u] += bf2f(ve[u]);
  }
  float4 h0 = *(const float4*)(hs + (size_t)s * 2048 + d0);
  float4 h1 = *(const float4*)(hs + (size_t)s * 2048 + d0 + 4);
  float hv[8] = {h0.x, h0.y, h0.z, h0.w, h1.x, h1.y, h1.z, h1.w};
  u16x8 o;
#pragma unroll
  for (int u = 0; u < 8; ++u) o[u] = f2bf(hv[u] * g[u]);
  *(u16x8*)(vb + (size_t)s * 2048 + d0) = o;
}

__global__ __launch_bounds__(256) void vmean_part(const ushort* __restrict__ vb,
                                                  float* __restrict__ part)
{
  const int h = blockIdx.y, chunk = blockIdx.x;
  const int t = threadIdx.x, d = t & 127, half = t >> 7;
  float s = 0.f;
  int r0 = chunk * 256 + half * 128;
  for (int r = r0; r < r0 + 128; ++r)
    s += bf2f(vb[(size_t)r * 2048 + h * 128 + d]);
  __shared__ float red[256];
  red[t] = s;
  __syncthreads();
  if (t < 128) part[(size_t)(h * 8 + chunk) * 128 + d] = red[t] + red[t + 128];
}

__global__ __launch_bounds__(256) void vmean_i0(const float* __restrict__ part,
    const float* __restrict__ amask, const float* __restrict__ dmask,
    float* __restrict__ vmean, int* __restrict__ i0)
{
  const int h = blockIdx.x, t = threadIdx.x;
  if (t < 128) {
    float s = 0.f;
#pragma unroll
    for (int c = 0; c < 8; ++c) s += part[(size_t)(h * 8 + c) * 128 + t];
    vmean[h * 128 + t] = s * (1.f / 2048.f);
  }
  int best = 0x7fffffff;
  for (int j = t; j < 2048; j += 256) {
    if (amask[j] * dmask[h * 2048 + j] != 0.f) { best = j; break; }
  }
  __shared__ int red[256];
  red[t] = best;
  __syncthreads();
  for (int off = 128; off > 0; off >>= 1) {
    if (t < off) red[t] = min(red[t], red[t + off]);
    __syncthreads();
  }
  if (t == 0) i0[h] = red[0];
}

// ---------------------------------------------------------------------------
// MFMA flash attention, stripe-paired, 8 waves = 2 k-parity groups x 4 row
// waves, XCD-swizzled grid, exp2-domain online softmax.
// ---------------------------------------------------------------------------
#define QLD 4096
__global__ __launch_bounds__(512) void attn_mfma(
    const ushort* __restrict__ qb, const ushort* __restrict__ kb,
    const ushort* __restrict__ vt, const float* __restrict__ amask,
    const float* __restrict__ dmask, const float* __restrict__ vmean,
    const int* __restrict__ i0, ushort* __restrict__ ao)
{
  const int L  = blockIdx.x;
  const int pr = L >> 4;                               // pair 0..15
  const int h  = (L & 7) | (((L >> 3) & 1) << 3);      // head; L%8 == h%8
  const int t  = threadIdx.x, w = t >> 6, lane = t & 63;
  const int g  = w >> 2, wg = w & 3;
  const int lr = lane & 15, lk = lane >> 4;

  __shared__ char smem[155648];
  float* accL  = (float*)smem;                      // [64][132] f32 (merge)
  float* smv   = (float*)(smem + 33792);            // [2][64]
  float* slv   = (float*)(smem + 33792 + 512);      // [2][64]
  float* maddL = (float*)(smem + 147456);           // [2048]

  const int i0h = i0[h];

  for (int j = t; j < 2048; j += 512)
    maddL[j] = (amask[j] * dmask[h * 2048 + j] == 0.f) ? NEG_MIN : 0.f;

  for (int sp = 0; sp < 2; ++sp) {
    const int stripe = (sp == 0) ? pr : 31 - pr;
    const int q0 = stripe << 6;
    const int ntiles = stripe + 1;

    __syncthreads();

    const int qrow = q0 + wg * 16 + lr;
    bf16x8 qf[4];
#pragma unroll
    for (int kk = 0; kk < 4; ++kk)
      qf[kk] = *(const bf16x8*)(qb + (size_t)qrow * QLD + h * 128 + kk * 32 + lk * 8);

    if (g < ntiles) {
      const int c0 = g << 6;
#pragma unroll
      for (int qI = 0; qI < 4; ++qI) {
        int b = wg * 4096 + qI * 1024 + lane * 16;
        int row = b >> 8, colb = b & 255;
        int src = colb ^ ((row & 7) << 4);
        gload_lds16((const char*)kb + ((size_t)(c0 + row) * QLD + h * 128) * 2 + src,
                    smem + g * 32768 + b);
      }
#pragma unroll
      for (int qI = 0; qI < 4; ++qI) {
        int b = wg * 4096 + qI * 1024 + lane * 16;
        int row = b >> 7, colb = b & 127;
        int src = colb ^ ((row & 7) << 4);
        gload_lds16((const char*)vt + ((size_t)(h * 128 + row) * 2048 + c0) * 2 + src,
                    smem + 65536 + g * 32768 + b);
      }
    }

    float m[4], l[4];
    f32x4 acc_o[8];
#pragma unroll
    for (int j = 0; j < 4; ++j) { m[j] = -FLT_MAX; l[j] = 0.f; }
#pragma unroll
    for (int ni = 0; ni < 8; ++ni) acc_o[ni] = (f32x4){0.f, 0.f, 0.f, 0.f};

    int cur = 0;
    const int niter = (ntiles + 1) >> 1;
    for (int it = 0; it < niter; ++it) {
      const int tile = 2 * it + g;
      const int c0 = tile << 6;
      __syncthreads();

      float madd[4];
      if (tile < ntiles) {
#pragma unroll
        for (int ni = 0; ni < 4; ++ni)
          madd[ni] = maddL[c0 + ni * 16 + lr];
      }

      if (tile + 2 < ntiles) {
        const int cn = c0 + 128;
        const int nb = cur ^ 1;
#pragma unroll
        for (int qI = 0; qI < 4; ++qI) {
          int b = wg * 4096 + qI * 1024 + lane * 16;
          int row = b >> 8, colb = b & 255;
          int src = colb ^ ((row & 7) << 4);
          gload_lds16((const char*)kb + ((size_t)(cn + row) * QLD + h * 128) * 2 + src,
                      smem + g * 32768 + nb * 16384 + b);
        }
#pragma unroll
        for (int qI = 0; qI < 4; ++qI) {
          int b = wg * 4096 + qI * 1024 + lane * 16;
          int row = b >> 7, colb = b & 127;
          int src = colb ^ ((row & 7) << 4);
          gload_lds16((const char*)vt + ((size_t)(h * 128 + row) * 2048 + cn) * 2 + src,
                      smem + 65536 + g * 32768 + nb * 16384 + b);
        }
      }

      if (tile < ntiles) {
        const bool diag = (tile == stripe);
        const char* Kbase = smem + g * 32768 + cur * 16384;
        const char* Vbase = smem + 65536 + g * 32768 + cur * 16384;
        char* Pbase = smem + 131072 + g * 8192;

        f32x4 sacc[4];
#pragma unroll
        for (int ni = 0; ni < 4; ++ni) sacc[ni] = (f32x4){0.f, 0.f, 0.f, 0.f};
        __builtin_amdgcn_s_setprio(1);
#pragma unroll
        for (int kk = 0; kk < 4; ++kk) {
#pragma unroll
          for (int ni = 0; ni < 4; ++ni) {
            int krow = ni * 16 + lr;
            bf16x8 bfr = *(const bf16x8*)(Kbase + krow * 256 + ((kk * 64 + lk * 16) ^ ((krow & 7) << 4)));
            sacc[ni] = __builtin_amdgcn_mfma_f32_16x16x32_bf16(qf[kk], bfr, sacc[ni], 0, 0, 0);
          }
        }
        __builtin_amdgcn_s_setprio(0);

        // ---- exp2-domain online softmax
#pragma unroll
        for (int j = 0; j < 4; ++j) {
          int grow = q0 + wg * 16 + lk * 4 + j;
          float x[4]; float tmax = -FLT_MAX;
#pragma unroll
          for (int ni = 0; ni < 4; ++ni) {
            float v = fmaf(sacc[ni][j], SCALE_L2E, madd[ni]);
            if (diag && c0 + ni * 16 + lr > grow) v = NEG_MIN;
            x[ni] = v; tmax = fmaxf(tmax, v);
          }
          tmax = fmaxf(tmax, dpp_ror<0x121>(tmax));
          tmax = fmaxf(tmax, dpp_ror<0x122>(tmax));
          tmax = fmaxf(tmax, dpp_ror<0x124>(tmax));
          tmax = fmaxf(tmax, dpp_ror<0x128>(tmax));
          float mn = fmaxf(m[j], tmax);
          float psum = 0.f;
          int prow = wg * 16 + lk * 4 + j;
#pragma unroll
          for (int ni = 0; ni < 4; ++ni) {
            float p = exp2f(x[ni] - mn);
            psum += p;
            *(ushort*)(Pbase + prow * 128 + ((2 * (ni * 16 + lr)) ^ ((prow & 7) << 4))) = f2bf(p);
          }
          psum += dpp_ror<0x121>(psum);
          psum += dpp_ror<0x122>(psum);
          psum += dpp_ror<0x124>(psum);
          psum += dpp_ror<0x128>(psum);
          if (mn > m[j]) {
            float sc = exp2f(m[j] - mn);
            l[j] *= sc;
#pragma unroll
            for (int ni = 0; ni < 8; ++ni) acc_o[ni][j] *= sc;
            m[j] = mn;
          }
          l[j] += psum;
        }

        __builtin_amdgcn_s_setprio(1);
#pragma unroll
        for (int kk = 0; kk < 2; ++kk) {
          int prow = wg * 16 + lr;
          bf16x8 a = *(const bf16x8*)(Pbase + prow * 128 + ((kk * 64 + lk * 16) ^ ((prow & 7) << 4)));
#pragma unroll
          for (int ni = 0; ni < 8; ++ni) {
            int vrow = ni * 16 + lr;
            bf16x8 bfr = *(const bf16x8*)(Vbase + vrow * 128 + ((kk * 64 + lk * 16) ^ ((vrow & 7) << 4)));
            acc_o[ni] = __builtin_amdgcn_mfma_f32_16x16x32_bf16(a, bfr, acc_o[ni], 0, 0, 0);
          }
        }
        __builtin_amdgcn_s_setprio(0);
      }
      cur ^= 1;
    }

    __syncthreads();
    if (lr == 0) {
#pragma unroll
      for (int j = 0; j < 4; ++j) {
        int r = wg * 16 + lk * 4 + j;
        smv[g * 64 + r] = m[j];
        slv[g * 64 + r] = l[j];
      }
    }
    __syncthreads();
    float myf[4], lcomb[4];
#pragma unroll
    for (int j = 0; j < 4; ++j) {
      int r = wg * 16 + lk * 4 + j;
      float m0 = smv[r], m1 = smv[64 + r];
      float l0 = slv[r], l1 = slv[64 + r];
      float mm = fmaxf(m0, m1);
      float f0 = exp2f(m0 - mm), f1 = exp2f(m1 - mm);
      lcomb[j] = l0 * f0 + l1 * f1;
      myf[j] = (g == 0) ? f0 : f1;
    }
    if (g == 1) {
#pragma unroll
      for (int j = 0; j < 4; ++j) {
        int r = wg * 16 + lk * 4 + j;
#pragma unroll
        for (int ni = 0; ni < 8; ++ni)
          accL[r * 132 + ni * 16 + lr] = acc_o[ni][j] * myf[j];
      }
    }
    __syncthreads();
    if (g == 0) {
#pragma unroll
      for (int j = 0; j < 4; ++j) {
        int row = q0 + wg * 16 + lk * 4 + j;
        int r = wg * 16 + lk * 4 + j;
        if (row < i0h) {
#pragma unroll
          for (int ni = 0; ni < 8; ++ni)
            ao[(size_t)row * 2048 + h * 128 + ni * 16 + lr] = f2bf(vmean[h * 128 + ni * 16 + lr]);
        } else {
          float inv = 1.f / lcomb[j];
#pragma unroll
          for (int ni = 0; ni < 8; ++ni) {
            float o = fmaf(acc_o[ni][j], myf[j], accL[r * 132 + ni * 16 + lr]);
            ao[(size_t)row * 2048 + h * 128 + ni * 16 + lr] = f2bf(o * inv);
          }
        }
      }
    }
  }
}

// ---------------------------------------------------------------------------
extern "C" void kernel_launch(void* const* d_in, const int* in_sizes, int n_in,
                              void* d_out, int out_size, void* d_ws, size_t ws_size,
                              hipStream_t stream)
{
  const float* hs    = (const float*)d_in[0];
  const float* amask = (const float*)d_in[1];
  const float* cosb  = (const float*)d_in[2];
  const float* sinb  = (const float*)d_in[3];
  const float* dmask = (const float*)d_in[4];
  const float* Wq    = (const float*)d_in[5];
  const float* Wk    = (const float*)d_in[6];
  const float* Wvq   = (const float*)d_in[7];
  const float* vkeys = (const float*)d_in[8];
  const float* vemb  = (const float*)d_in[9];
  const float* Wo    = (const float*)d_in[10];
  float* outp = (float*)d_out;

  char* ws = (char*)d_ws;
  const size_t MB = 1048576;
  // Lifetimes (phases A..E); high-water 70 MB (validated >= 71.4 in R2).
  float*  pvq     = (float*) (ws + 0);              // A: [0,64) 16 partials
  float*  vq_f32  = (float*) (ws + 64*MB);          // A-B: [64,68)
  ushort* vq_bf   = (ushort*)(ws + 68*MB);          // A-B: [68,70)
  ushort* vkT     = (ushort*)(ws + 0);              // B: [0,2)   over dead pvq
  ushort* sim_bf  = (ushort*)(ws + 2*MB);           // B: [2,34)
  int*    idx     = (int*)   (ws + 34*MB);          // B-C: 128 KB
  ushort* vemb_bf = (ushort*)(ws + 35*MB);          // C: [35,43)
  ushort* hs_bf   = (ushort*)(ws + 43*MB);          // C-D: [43,51)
  ushort* vb      = (ushort*)(ws + 0);              // C: [0,8)   over dead vkT/sim
  ushort* vt      = (ushort*)(ws + 8*MB);           // C-E: [8,16)
  float*  part    = (float*) (ws + 51*MB);          // C: 64 KB
  float*  vmean   = (float*) (ws + 51*MB + 65536);  // C-E: 8 KB
  int*    i0b     = (int*)   (ws + 51*MB + 73728);  // C-E: 64 B
  ushort* WBig    = (ushort*)(ws + 16*MB);          // D-E: [16,40) Wq|Wk|Wo^T
  ushort* WoT     = (ushort*)(ws + 32*MB);          // = WBig + 16MB
  ushort* qkC     = (ushort*)(ws + 52*MB);          // D-E: [52,68) q|k, ld 4096
  ushort* ao      = (ushort*)(ws + 0);              // E: [0,8)   over dead vb

  dim3 blk(256);
  // ---- routing path ----
  gemm_f32_sk<<<dim3(4, 16, 16), blk, 0, stream>>>(hs, 2048, Wvq, 512, pvq, 512, 2048, 512, 128);
  reduce16_cvt<<<dim3(1024), blk, 0, stream>>>(pvq, vq_f32, vq_bf);
  transpose_cvt<<<dim3(32, 2, 4), blk, 0, stream>>>(vkeys, vkT, 128, 2048, 262144, 262144);
  gemm_bf16<1, 0><<<dim3(16, 16, 4), blk, 0, stream>>>(vq_bf, 512, vkT, 128,
      sim_bf, 2048, 128, 128, 262144, 4194304, nullptr, nullptr);
  topk_sel<<<dim3(2048), blk, 0, stream>>>(sim_bf, vq_f32, vkeys, idx);
  // ---- v construction ----
  cvt2_bf16<<<dim3(8192), blk, 0, stream>>>(vemb, vemb_bf, hs, hs_bf);
  gather_mul_bf<<<dim3(2048), blk, 0, stream>>>(hs, vemb_bf, idx, vb);
  transpose_bf<<<dim3(32, 32), blk, 0, stream>>>(vb, vt);
  vmean_part<<<dim3(8, 16), blk, 0, stream>>>(vb, part);
  vmean_i0<<<dim3(16), blk, 0, stream>>>(part, amask, dmask, vmean, i0b);
  // ---- projections: Wq|Wk|Wo transpose (z=3), fused qk GEMM + RoPE ----
  transpose_cvt_w3<<<dim3(32, 32, 3), blk, 0, stream>>>(Wq, Wk, Wo, WBig);
  gemm_bf16<1, 1><<<dim3(32, 16, 1), blk, 0, stream>>>(hs_bf, 2048, WBig, 2048,
      qkC, 4096, 2048, 0, 0, 0, cosb, sinb);
  // ---- attention (XCD-swizzled 1D grid) ----
  attn_mfma<<<dim3(256), dim3(512), 0, stream>>>(qkC, qkC + 2048, vt, amask, dmask, vmean, i0b, ao);
  // ---- output projection ----
  gemm_bf16<0, 0><<<dim3(16, 16, 1), blk, 0, stream>>>(ao, 2048, WoT, 2048,
      outp, 2048, 2048, 0, 0, 0, nullptr, nullptr);
}

// Round 10
// 337.522 us; speedup vs baseline: 11.2933x; 1.1345x over previous
//
#include <hip/hip_runtime.h>
#include <float.h>

// B=1, S=2048, D=2048, H=16, HD=128, HV=4, R=128, NV=2048, K=4
#define NEG_MIN (-3.4028234663852886e38f)
#define INV_SQRT_HD 0.08838834764831845f
#define SCALE_L2E 0.12751791437968458f    // INV_SQRT_HD * log2(e)

typedef __attribute__((ext_vector_type(8))) short bf16x8;
typedef __attribute__((ext_vector_type(8))) unsigned short u16x8;
typedef __attribute__((ext_vector_type(4))) float f32x4;

__device__ __forceinline__ void gload_lds16(const void* g, void* l) {
  __builtin_amdgcn_global_load_lds((const __attribute__((address_space(1))) void*)g,
                                   (__attribute__((address_space(3))) void*)l, 16, 0, 0);
}
__device__ __forceinline__ ushort f2bf(float x) {
  union { float f; unsigned u; } v; v.f = x;
  unsigned r = v.u + 0x7fffu + ((v.u >> 16) & 1u);   // RNE
  return (ushort)(r >> 16);
}
__device__ __forceinline__ float bf2f(ushort u) {
  union { unsigned i; float f; } v; v.i = ((unsigned)u) << 16; return v.f;
}
template<int CTRL>
__device__ __forceinline__ float dpp_ror(float x) {
  return __int_as_float(__builtin_amdgcn_mov_dpp(__float_as_int(x), CTRL, 0xF, 0xF, true));
}
template<int CTRL>
__device__ __forceinline__ unsigned dpp_ror_u(unsigned x) {
  return (unsigned)__builtin_amdgcn_mov_dpp((int)x, CTRL, 0xF, 0xF, true);
}
// 64-lane unsigned max: 4 DPP row_ror (VALU) + 2 shfl (cross-row/half)
__device__ __forceinline__ unsigned wave_umax64(unsigned x) {
  x = max(x, dpp_ror_u<0x121>(x));
  x = max(x, dpp_ror_u<0x122>(x));
  x = max(x, dpp_ror_u<0x124>(x));
  x = max(x, dpp_ror_u<0x128>(x));
  x = max(x, (unsigned)__shfl_xor((int)x, 16));
  x = max(x, (unsigned)__shfl_xor((int)x, 32));
  return x;
}
// monotonic bf16 -> u16 transform (total order, -inf..inf ascending)
__device__ __forceinline__ unsigned bf_sortable(ushort b) {
  return (b & 0x8000u) ? (unsigned)(b ^ 0xFFFFu) : (unsigned)(b | 0x8000u);
}

// ---------------------------------------------------------------------------
// Split-K f32 GEMM, 128x128 tile, 8x8 microtile, reg double-buffered staging.
// ---------------------------------------------------------------------------
__global__ __launch_bounds__(256) void gemm_f32_sk(
    const float* __restrict__ A, int lda,
    const float* __restrict__ B, int ldb,
    float* __restrict__ Cp, int ldc, int M, int N, int Kchunk)
{
  __shared__ float As[16][132];
  __shared__ float Bs[16][132];
  const int t = threadIdx.x, tx = t & 15, ty = t >> 4;
  const int bm = blockIdx.y << 7, bn = blockIdx.x << 7;
  const int k0base = blockIdx.z * Kchunk;
  const int arr = t >> 2, ac = (t & 3) << 2;
  const int brr = t >> 5, bc = (t & 31) << 2;

  float acc[8][8];
#pragma unroll
  for (int i = 0; i < 8; ++i)
#pragma unroll
    for (int j = 0; j < 8; ++j) acc[i][j] = 0.f;

  float4 pa0, pa1, pb0, pb1;
  pa0 = *(const float4*)(A + (size_t)(bm + arr) * lda + k0base + ac);
  pa1 = *(const float4*)(A + (size_t)(bm + arr + 64) * lda + k0base + ac);
  pb0 = *(const float4*)(B + (size_t)(k0base + brr) * ldb + bn + bc);
  pb1 = *(const float4*)(B + (size_t)(k0base + brr + 8) * ldb + bn + bc);

  for (int k0 = 0; k0 < Kchunk; k0 += 16) {
    __syncthreads();
    As[ac + 0][arr] = pa0.x; As[ac + 1][arr] = pa0.y;
    As[ac + 2][arr] = pa0.z; As[ac + 3][arr] = pa0.w;
    As[ac + 0][arr + 64] = pa1.x; As[ac + 1][arr + 64] = pa1.y;
    As[ac + 2][arr + 64] = pa1.z; As[ac + 3][arr + 64] = pa1.w;
    *(float4*)(&Bs[brr][bc])     = pb0;
    *(float4*)(&Bs[brr + 8][bc]) = pb1;
    __syncthreads();
    if (k0 + 16 < Kchunk) {
      int kn = k0base + k0 + 16;
      pa0 = *(const float4*)(A + (size_t)(bm + arr) * lda + kn + ac);
      pa1 = *(const float4*)(A + (size_t)(bm + arr + 64) * lda + kn + ac);
      pb0 = *(const float4*)(B + (size_t)(kn + brr) * ldb + bn + bc);
      pb1 = *(const float4*)(B + (size_t)(kn + brr + 8) * ldb + bn + bc);
    }
#pragma unroll
    for (int kk = 0; kk < 16; ++kk) {
      float4 a0 = *(const float4*)(&As[kk][ty * 8]);
      float4 a1 = *(const float4*)(&As[kk][ty * 8 + 4]);
      float4 b0 = *(const float4*)(&Bs[kk][tx * 4]);
      float4 b1 = *(const float4*)(&Bs[kk][tx * 4 + 64]);
      float av[8] = {a0.x, a0.y, a0.z, a0.w, a1.x, a1.y, a1.z, a1.w};
      float bv[8] = {b0.x, b0.y, b0.z, b0.w, b1.x, b1.y, b1.z, b1.w};
#pragma unroll
      for (int i = 0; i < 8; ++i)
#pragma unroll
        for (int j = 0; j < 8; ++j)
          acc[i][j] = fmaf(av[i], bv[j], acc[i][j]);
    }
  }
  float* C = Cp + (size_t)blockIdx.z * M * N;
#pragma unroll
  for (int i = 0; i < 8; ++i) {
    int row = bm + ty * 8 + i;
    *(float4*)(C + (size_t)row * ldc + bn + tx * 4) =
        make_float4(acc[i][0], acc[i][1], acc[i][2], acc[i][3]);
    *(float4*)(C + (size_t)row * ldc + bn + tx * 4 + 64) =
        make_float4(acc[i][4], acc[i][5], acc[i][6], acc[i][7]);
  }
}

// deterministic 16-way reduce of split-K partials + bf16 copy (1M floats)
__global__ __launch_bounds__(256) void reduce16_cvt(const float* __restrict__ Cp,
    float* __restrict__ vq, ushort* __restrict__ vq_bf)
{
  int i = (blockIdx.x * 256 + threadIdx.x) << 2;
  float4 s = make_float4(0.f, 0.f, 0.f, 0.f);
#pragma unroll
  for (int z = 0; z < 16; ++z) {
    float4 a = *(const float4*)(Cp + (size_t)z * 1048576 + i);
    s.x += a.x; s.y += a.y; s.z += a.z; s.w += a.w;
  }
  *(float4*)(vq + i) = s;
  ushort4 o; o.x = f2bf(s.x); o.y = f2bf(s.y); o.z = f2bf(s.z); o.w = f2bf(s.w);
  *(ushort4*)(vq_bf + i) = o;
}

// ---------------------------------------------------------------------------
// bf16 MFMA GEMM (z-batched): C = A @ Bt^T. 128x128 tile, BK=64.
// ROPE=1: fused RoPE epilogue for q-region blocks (bn<16); tile == one head.
// ---------------------------------------------------------------------------
template<int OUT_BF16, int ROPE>
__global__ __launch_bounds__(256) void gemm_bf16(
    const ushort* __restrict__ A0, int lda,
    const ushort* __restrict__ Bt0, int ldb,
    void* __restrict__ C0, int ldc, int Kd,
    size_t strA, size_t strB, size_t strC,
    const float* __restrict__ cosb, const float* __restrict__ sinb)
{
  const ushort* A  = A0  + blockIdx.z * strA;
  const ushort* Bt = Bt0 + blockIdx.z * strB;
  __shared__ ushort smem_g[2 * 128 * 64];     // As | Bs ; reused as rope buffer
  ushort* As = smem_g;
  ushort* Bs = smem_g + 128 * 64;
  const int t = threadIdx.x, w = t >> 6, lane = t & 63;
  const int lr = lane & 15, lk = lane >> 4;
  const int bm = blockIdx.y << 7, bn = blockIdx.x << 7;
  const int wm = (w >> 1) << 6, wn = (w & 1) << 6;
  f32x4 acc[4][4];
#pragma unroll
  for (int i = 0; i < 4; ++i)
#pragma unroll
    for (int j = 0; j < 4; ++j) acc[i][j] = (f32x4){0.f, 0.f, 0.f, 0.f};

  for (int k0 = 0; k0 < Kd; k0 += 64) {
    __syncthreads();
#pragma unroll
    for (int qI = 0; qI < 4; ++qI) {
      int b = w * 4096 + qI * 1024 + lane * 16;
      int row = b >> 7, colb = b & 127;
      int src = colb ^ ((row & 7) << 4);
      gload_lds16((const char*)A + ((size_t)(bm + row) * lda + k0) * 2 + src,
                  (char*)As + w * 4096 + qI * 1024);
    }
#pragma unroll
    for (int qI = 0; qI < 4; ++qI) {
      int b = w * 4096 + qI * 1024 + lane * 16;
      int row = b >> 7, colb = b & 127;
      int src = colb ^ ((row & 7) << 4);
      gload_lds16((const char*)Bt + ((size_t)(bn + row) * ldb + k0) * 2 + src,
                  (char*)Bs + w * 4096 + qI * 1024);
    }
    __syncthreads();
#pragma unroll
    for (int kk = 0; kk < 2; ++kk) {
      bf16x8 af[4], bf[4];
#pragma unroll
      for (int mi = 0; mi < 4; ++mi) {
        int row = wm + mi * 16 + lr;
        af[mi] = *(const bf16x8*)((const char*)As + row * 128 + ((kk * 64 + lk * 16) ^ ((row & 7) << 4)));
      }
#pragma unroll
      for (int ni = 0; ni < 4; ++ni) {
        int row = wn + ni * 16 + lr;
        bf[ni] = *(const bf16x8*)((const char*)Bs + row * 128 + ((kk * 64 + lk * 16) ^ ((row & 7) << 4)));
      }
#pragma unroll
      for (int mi = 0; mi < 4; ++mi)
#pragma unroll
        for (int ni = 0; ni < 4; ++ni)
          acc[mi][ni] = __builtin_amdgcn_mfma_f32_16x16x32_bf16(af[mi], bf[ni], acc[mi][ni], 0, 0, 0);
    }
  }

  if (ROPE && blockIdx.x < 16) {
    __syncthreads();
    ushort* Pl = smem_g;    // [128][128] bf16 = 32 KB
#pragma unroll
    for (int mi = 0; mi < 4; ++mi)
#pragma unroll
      for (int j = 0; j < 4; ++j) {
        int rl = wm + mi * 16 + lk * 4 + j;
#pragma unroll
        for (int ni = 0; ni < 4; ++ni)
          Pl[rl * 128 + wn + ni * 16 + lr] = f2bf(acc[mi][ni][j]);
      }
    __syncthreads();
    const bool lo = (wn == 0);    // wave-uniform: d < 64
#pragma unroll
    for (int mi = 0; mi < 4; ++mi)
#pragma unroll
      for (int j = 0; j < 4; ++j) {
        int rl = wm + mi * 16 + lk * 4 + j;
        int row = bm + rl;
#pragma unroll
        for (int ni = 0; ni < 4; ++ni) {
          int d = wn + ni * 16 + lr;
          float a = bf2f(Pl[rl * 128 + d]);
          float b = bf2f(Pl[rl * 128 + (d ^ 64)]);
          float cs = cosb[row * 128 + d], sn = sinb[row * 128 + d];
          float v = lo ? (a * cs - b * sn) : (a * cs + b * sn);
          ((ushort*)C0)[(size_t)row * ldc + bn + d] = f2bf(v);
        }
      }
    return;
  }

#pragma unroll
  for (int mi = 0; mi < 4; ++mi)
#pragma unroll
    for (int j = 0; j < 4; ++j) {
      int row = bm + wm + mi * 16 + lk * 4 + j;
#pragma unroll
      for (int ni = 0; ni < 4; ++ni) {
        int col = bn + wn + ni * 16 + lr;
        if (OUT_BF16) ((ushort*)C0)[blockIdx.z * strC + (size_t)row * ldc + col] = f2bf(acc[mi][ni][j]);
        else          ((float*)C0)[blockIdx.z * strC + (size_t)row * ldc + col]  = acc[mi][ni][j];
      }
    }
}

// ---------------------------------------------------------------------------
// vkeys transpose: dstb (bf16) and dstf (f32), both [hv][n=2048][r=128]
// ---------------------------------------------------------------------------
__global__ __launch_bounds__(256) void transpose_cvt_vk(
    const float* __restrict__ src0, ushort* __restrict__ dstb,
    float* __restrict__ dstf)
{
  const float* src = src0 + (size_t)blockIdx.z * 262144;
  ushort* db = dstb + (size_t)blockIdx.z * 262144;
  float*  df = dstf + (size_t)blockIdx.z * 262144;
  __shared__ float tile[64][65];
  const int r0 = blockIdx.y << 6, c0 = blockIdx.x << 6;
  const int t = threadIdx.x;
  for (int i = t; i < 1024; i += 256) {
    int r = i >> 4, c = (i & 15) << 2;
    float4 v = *(const float4*)(src + (size_t)(r0 + r) * 2048 + c0 + c);
    tile[r][c] = v.x; tile[r][c+1] = v.y; tile[r][c+2] = v.z; tile[r][c+3] = v.w;
  }
  __syncthreads();
  int c = t >> 2, rb = (t & 3) << 4;
#pragma unroll
  for (int u = 0; u < 16; u += 4) {
    float4 f = make_float4(tile[rb+u+0][c], tile[rb+u+1][c],
                           tile[rb+u+2][c], tile[rb+u+3][c]);
    ushort4 o; o.x = f2bf(f.x); o.y = f2bf(f.y); o.z = f2bf(f.z); o.w = f2bf(f.w);
    *(ushort4*)(db + (size_t)(c0 + c) * 128 + r0 + rb + u) = o;
    *(float4*) (df + (size_t)(c0 + c) * 128 + r0 + rb + u) = f;
  }
}

// triple-source weight transpose: z=0 Wq, z=1 Wk, z=2 Wo (2048x2048 each)
__global__ __launch_bounds__(256) void transpose_cvt_w3(
    const float* __restrict__ srcA, const float* __restrict__ srcB,
    const float* __restrict__ srcC, ushort* __restrict__ dst0)
{
  const float* src = (blockIdx.z == 0) ? srcA : (blockIdx.z == 1) ? srcB : srcC;
  ushort* dst = dst0 + (size_t)blockIdx.z * 4194304;
  __shared__ float tile[64][65];
  const int r0 = blockIdx.y << 6, c0 = blockIdx.x << 6;
  const int t = threadIdx.x;
  for (int i = t; i < 1024; i += 256) {
    int r = i >> 4, c = (i & 15) << 2;
    float4 v = *(const float4*)(src + (size_t)(r0 + r) * 2048 + c0 + c);
    tile[r][c] = v.x; tile[r][c+1] = v.y; tile[r][c+2] = v.z; tile[r][c+3] = v.w;
  }
  __syncthreads();
  int c = t >> 2, rb = (t & 3) << 4;
#pragma unroll
  for (int u = 0; u < 16; u += 4) {
    ushort4 o;
    o.x = f2bf(tile[rb+u+0][c]); o.y = f2bf(tile[rb+u+1][c]);
    o.z = f2bf(tile[rb+u+2][c]); o.w = f2bf(tile[rb+u+3][c]);
    *(ushort4*)(dst + (size_t)(c0 + c) * 2048 + r0 + rb + u) = o;
  }
}

// bf16 -> bf16 transpose (2048x2048)
__global__ __launch_bounds__(256) void transpose_bf(
    const ushort* __restrict__ src, ushort* __restrict__ dst)
{
  __shared__ ushort tile[64][66];
  const int r0 = blockIdx.y << 6, c0 = blockIdx.x << 6;
  const int t = threadIdx.x;
  for (int i = t; i < 512; i += 256) {
    int r = i >> 3, c8 = (i & 7) << 3;
    *(u16x8*)(&tile[r][c8]) = *(const u16x8*)(src + (size_t)(r0 + r) * 2048 + c0 + c8);
  }
  __syncthreads();
  for (int i = t; i < 512; i += 256) {
    int c = i >> 3, r8 = (i & 7) << 3;
    u16x8 o;
#pragma unroll
    for (int u = 0; u < 8; ++u) o[u] = tile[r8 + u][c];
    *(u16x8*)(dst + (size_t)(c0 + c) * 2048 + r0 + r8) = o;
  }
}

// two f32->bf16 conversions in one launch (4M elems each)
__global__ __launch_bounds__(256) void cvt2_bf16(const float* __restrict__ srcA,
    ushort* __restrict__ dstA, const float* __restrict__ srcB,
    ushort* __restrict__ dstB)
{
  int gid = blockIdx.x * 256 + threadIdx.x;
  const float* s; ushort* d; int i;
  if (gid < 1048576) { s = srcA; d = dstA; i = gid; }
  else               { s = srcB; d = dstB; i = gid - 1048576; }
  float4 v = ((const float4*)s)[i];
  ushort4 o; o.x = f2bf(v.x); o.y = f2bf(v.y); o.z = f2bf(v.z); o.w = f2bf(v.w);
  ((ushort4*)d)[i] = o;
}

// ---------------------------------------------------------------------------
// Fused top-k: packed-u32 candidates (sortable-bf16 | 2047-idx), DPP merge,
// exact f32 recompute on contiguous transposed v_keys, exact top-4.
// One wave per row. Tie-break lower index (matches jax.lax.top_k).
// ---------------------------------------------------------------------------
__global__ __launch_bounds__(256) void topk_sel(const ushort* __restrict__ sim,
    const float* __restrict__ vq, const float* __restrict__ vkTf,
    int* __restrict__ idxo)
{
  const int row = blockIdx.x * 4 + (threadIdx.x >> 6);
  const int hv = row >> 11, s = row & 2047;
  const int lane = threadIdx.x & 63;
  const ushort* r = sim + (size_t)row * 2048;

  // ---- phase 1: per-lane top-8 (packed u32), vectorized scan
  unsigned v[8];
#pragma unroll
  for (int p = 0; p < 8; ++p) v[p] = 0u;
  for (int j = 0; j < 4; ++j) {
    int nb = (lane + (j << 6)) << 3;
    u16x8 e = *(const u16x8*)(r + nb);
#pragma unroll
    for (int u = 0; u < 8; ++u) {
      unsigned pk = (bf_sortable(e[u]) << 16) | (unsigned)(2047 - (nb + u));
      if (pk > v[7]) {
        v[7] = pk;
#pragma unroll
        for (int p = 7; p > 0; --p)
          if (v[p] > v[p-1]) { unsigned tt = v[p]; v[p] = v[p-1]; v[p-1] = tt; }
      }
    }
  }
  // ---- 8 rounds of wave-max extraction (unique packed -> one popper)
  int out_n[8];
#pragma unroll
  for (int r8 = 0; r8 < 8; ++r8) {
    unsigned m = wave_umax64(v[0]);
    out_n[r8] = 2047 - (int)(m & 0x7FFu);
    if (v[0] == m) {
#pragma unroll
      for (int p = 0; p < 7; ++p) v[p] = v[p+1];
      v[7] = 0u;
    }
  }
  // ---- phase 2: exact f32 recompute (contiguous [n][r] reads) + top-4
  const int c = lane & 7, rc = lane >> 3;
  int n = 0;
#pragma unroll
  for (int p = 0; p < 8; ++p) if (p == c) n = out_n[p];
  const float* vqr = vq + (size_t)s * 512 + hv * 128 + rc * 16;
  const float* vkf = vkTf + (size_t)hv * 262144 + (size_t)n * 128 + rc * 16;
  float acc = 0.f;
#pragma unroll
  for (int u = 0; u < 16; ++u) acc = fmaf(vqr[u], vkf[u], acc);
  acc += __shfl_xor(acc, 8);
  acc += __shfl_xor(acc, 16);
  acc += __shfl_xor(acc, 32);
  float cv = acc; int ci = n;
  int picks[4];
#pragma unroll
  for (int p = 0; p < 4; ++p) {
    float bv = cv; int bi = ci;
#pragma unroll
    for (int d = 1; d < 8; d <<= 1) {
      float ov = __shfl_xor(bv, d); int oi = __shfl_xor(bi, d);
      if (ov > bv || (ov == bv && oi < bi)) { bv = ov; bi = oi; }
    }
    picks[p] = bi;
    if (bi == ci) cv = -FLT_MAX;
  }
  if (lane == 0) {
#pragma unroll
    for (int p = 0; p < 4; ++p) idxo[(size_t)row * 4 + p] = picks[p];
  }
}

// ---------------------------------------------------------------------------
__global__ __launch_bounds__(256) void gather_mul_bf(const float* __restrict__ hs,
    const ushort* __restrict__ vemb_bf, const int* __restrict__ idx,
    ushort* __restrict__ vb)
{
  const int s = blockIdx.x;
  const int t = threadIdx.x;
  __shared__ int id[16];
  if (t < 16) id[t] = idx[((size_t)(t >> 2) * 2048 + s) * 4 + (t & 3)];
  __syncthreads();
  int d0 = t << 3;
  float g[8] = {0.f, 0.f, 0.f, 0.f, 0.f, 0.f, 0.f, 0.f};
#pragma unroll
  for (int e = 0; e < 16; ++e) {
    u16x8 ve = *(const u16x8*)(vemb_bf + (size_t)id[e] * 2048 + d0);
#pragma unroll
    for (int u = 0; u < 8; ++u) g[u] += bf2f(ve[u]);
  }
  float4 h0 = *(const float4*)(hs + (size_t)s * 2048 + d0);
  float4 h1 = *(const float4*)(hs + (size_t)s * 2048 + d0 + 4);
  float hv[8] = {h0.x, h0.y, h0.z, h0.w, h1.x, h1.y, h1.z, h1.w};
  u16x8 o;
#pragma unroll
  for (int u = 0; u < 8; ++u) o[u] = f2bf(hv[u] * g[u]);
  *(u16x8*)(vb + (size_t)s * 2048 + d0) = o;
}

__global__ __launch_bounds__(256) void vmean_part(const ushort* __restrict__ vb,
                                                  float* __restrict__ part)
{
  const int h = blockIdx.y, chunk = blockIdx.x;
  const int t = threadIdx.x, d = t & 127, half = t >> 7;
  float s = 0.f;
  int r0 = chunk * 256 + half * 128;
  for (int r = r0; r < r0 + 128; ++r)
    s += bf2f(vb[(size_t)r * 2048 + h * 128 + d]);
  __shared__ float red[256];
  red[t] = s;
  __syncthreads();
  if (t < 128) part[(size_t)(h * 8 + chunk) * 128 + d] = red[t] + red[t + 128];
}

__global__ __launch_bounds__(256) void vmean_i0(const float* __restrict__ part,
    const float* __restrict__ amask, const float* __restrict__ dmask,
    float* __restrict__ vmean, int* __restrict__ i0)
{
  const int h = blockIdx.x, t = threadIdx.x;
  if (t < 128) {
    float s = 0.f;
#pragma unroll
    for (int c = 0; c < 8; ++c) s += part[(size_t)(h * 8 + c) * 128 + t];
    vmean[h * 128 + t] = s * (1.f / 2048.f);
  }
  int best = 0x7fffffff;
  for (int j = t; j < 2048; j += 256) {
    if (amask[j] * dmask[h * 2048 + j] != 0.f) { best = j; break; }
  }
  __shared__ int red[256];
  red[t] = best;
  __syncthreads();
  for (int off = 128; off > 0; off >>= 1) {
    if (t < off) red[t] = min(red[t], red[t + off]);
    __syncthreads();
  }
  if (t == 0) i0[h] = red[0];
}

// ---------------------------------------------------------------------------
// MFMA flash attention, stripe-paired, 8 waves = 2 k-parity groups x 4 row
// waves, XCD-swizzled grid, exp2-domain online softmax.
// ---------------------------------------------------------------------------
#define QLD 4096
__global__ __launch_bounds__(512) void attn_mfma(
    const ushort* __restrict__ qb, const ushort* __restrict__ kb,
    const ushort* __restrict__ vt, const float* __restrict__ amask,
    const float* __restrict__ dmask, const float* __restrict__ vmean,
    const int* __restrict__ i0, ushort* __restrict__ ao)
{
  const int L  = blockIdx.x;
  const int pr = L >> 4;                               // pair 0..15
  const int h  = (L & 7) | (((L >> 3) & 1) << 3);      // head; L%8 == h%8
  const int t  = threadIdx.x, w = t >> 6, lane = t & 63;
  const int g  = w >> 2, wg = w & 3;
  const int lr = lane & 15, lk = lane >> 4;

  __shared__ char smem[155648];
  float* accL  = (float*)smem;                      // [64][132] f32 (merge)
  float* smv   = (float*)(smem + 33792);            // [2][64]
  float* slv   = (float*)(smem + 33792 + 512);      // [2][64]
  float* maddL = (float*)(smem + 147456);           // [2048]

  const int i0h = i0[h];

  for (int j = t; j < 2048; j += 512)
    maddL[j] = (amask[j] * dmask[h * 2048 + j] == 0.f) ? NEG_MIN : 0.f;

  for (int sp = 0; sp < 2; ++sp) {
    const int stripe = (sp == 0) ? pr : 31 - pr;
    const int q0 = stripe << 6;
    const int ntiles = stripe + 1;

    __syncthreads();

    const int qrow = q0 + wg * 16 + lr;
    bf16x8 qf[4];
#pragma unroll
    for (int kk = 0; kk < 4; ++kk)
      qf[kk] = *(const bf16x8*)(qb + (size_t)qrow * QLD + h * 128 + kk * 32 + lk * 8);

    if (g < ntiles) {
      const int c0 = g << 6;
#pragma unroll
      for (int qI = 0; qI < 4; ++qI) {
        int b = wg * 4096 + qI * 1024 + lane * 16;
        int row = b >> 8, colb = b & 255;
        int src = colb ^ ((row & 7) << 4);
        gload_lds16((const char*)kb + ((size_t)(c0 + row) * QLD + h * 128) * 2 + src,
                    smem + g * 32768 + b);
      }
#pragma unroll
      for (int qI = 0; qI < 4; ++qI) {
        int b = wg * 4096 + qI * 1024 + lane * 16;
        int row = b >> 7, colb = b & 127;
        int src = colb ^ ((row & 7) << 4);
        gload_lds16((const char*)vt + ((size_t)(h * 128 + row) * 2048 + c0) * 2 + src,
                    smem + 65536 + g * 32768 + b);
      }
    }

    float m[4], l[4];
    f32x4 acc_o[8];
#pragma unroll
    for (int j = 0; j < 4; ++j) { m[j] = -FLT_MAX; l[j] = 0.f; }
#pragma unroll
    for (int ni = 0; ni < 8; ++ni) acc_o[ni] = (f32x4){0.f, 0.f, 0.f, 0.f};

    int cur = 0;
    const int niter = (ntiles + 1) >> 1;
    for (int it = 0; it < niter; ++it) {
      const int tile = 2 * it + g;
      const int c0 = tile << 6;
      __syncthreads();

      float madd[4];
      if (tile < ntiles) {
#pragma unroll
        for (int ni = 0; ni < 4; ++ni)
          madd[ni] = maddL[c0 + ni * 16 + lr];
      }

      if (tile + 2 < ntiles) {
        const int cn = c0 + 128;
        const int nb = cur ^ 1;
#pragma unroll
        for (int qI = 0; qI < 4; ++qI) {
          int b = wg * 4096 + qI * 1024 + lane * 16;
          int row = b >> 8, colb = b & 255;
          int src = colb ^ ((row & 7) << 4);
          gload_lds16((const char*)kb + ((size_t)(cn + row) * QLD + h * 128) * 2 + src,
                      smem + g * 32768 + nb * 16384 + b);
        }
#pragma unroll
        for (int qI = 0; qI < 4; ++qI) {
          int b = wg * 4096 + qI * 1024 + lane * 16;
          int row = b >> 7, colb = b & 127;
          int src = colb ^ ((row & 7) << 4);
          gload_lds16((const char*)vt + ((size_t)(h * 128 + row) * 2048 + cn) * 2 + src,
                      smem + 65536 + g * 32768 + nb * 16384 + b);
        }
      }

      if (tile < ntiles) {
        const bool diag = (tile == stripe);
        const char* Kbase = smem + g * 32768 + cur * 16384;
        const char* Vbase = smem + 65536 + g * 32768 + cur * 16384;
        char* Pbase = smem + 131072 + g * 8192;

        f32x4 sacc[4];
#pragma unroll
        for (int ni = 0; ni < 4; ++ni) sacc[ni] = (f32x4){0.f, 0.f, 0.f, 0.f};
        __builtin_amdgcn_s_setprio(1);
#pragma unroll
        for (int kk = 0; kk < 4; ++kk) {
#pragma unroll
          for (int ni = 0; ni < 4; ++ni) {
            int krow = ni * 16 + lr;
            bf16x8 bfr = *(const bf16x8*)(Kbase + krow * 256 + ((kk * 64 + lk * 16) ^ ((krow & 7) << 4)));
            sacc[ni] = __builtin_amdgcn_mfma_f32_16x16x32_bf16(qf[kk], bfr, sacc[ni], 0, 0, 0);
          }
        }
        __builtin_amdgcn_s_setprio(0);

#pragma unroll
        for (int j = 0; j < 4; ++j) {
          int grow = q0 + wg * 16 + lk * 4 + j;
          float x[4]; float tmax = -FLT_MAX;
#pragma unroll
          for (int ni = 0; ni < 4; ++ni) {
            float v = fmaf(sacc[ni][j], SCALE_L2E, madd[ni]);
            if (diag && c0 + ni * 16 + lr > grow) v = NEG_MIN;
            x[ni] = v; tmax = fmaxf(tmax, v);
          }
          tmax = fmaxf(tmax, dpp_ror<0x121>(tmax));
          tmax = fmaxf(tmax, dpp_ror<0x122>(tmax));
          tmax = fmaxf(tmax, dpp_ror<0x124>(tmax));
          tmax = fmaxf(tmax, dpp_ror<0x128>(tmax));
          float mn = fmaxf(m[j], tmax);
          float psum = 0.f;
          int prow = wg * 16 + lk * 4 + j;
#pragma unroll
          for (int ni = 0; ni < 4; ++ni) {
            float p = exp2f(x[ni] - mn);
            psum += p;
            *(ushort*)(Pbase + prow * 128 + ((2 * (ni * 16 + lr)) ^ ((prow & 7) << 4))) = f2bf(p);
          }
          psum += dpp_ror<0x121>(psum);
          psum += dpp_ror<0x122>(psum);
          psum += dpp_ror<0x124>(psum);
          psum += dpp_ror<0x128>(psum);
          if (mn > m[j]) {
            float sc = exp2f(m[j] - mn);
            l[j] *= sc;
#pragma unroll
            for (int ni = 0; ni < 8; ++ni) acc_o[ni][j] *= sc;
            m[j] = mn;
          }
          l[j] += psum;
        }

        __builtin_amdgcn_s_setprio(1);
#pragma unroll
        for (int kk = 0; kk < 2; ++kk) {
          int prow = wg * 16 + lr;
          bf16x8 a = *(const bf16x8*)(Pbase + prow * 128 + ((kk * 64 + lk * 16) ^ ((prow & 7) << 4)));
#pragma unroll
          for (int ni = 0; ni < 8; ++ni) {
            int vrow = ni * 16 + lr;
            bf16x8 bfr = *(const bf16x8*)(Vbase + vrow * 128 + ((kk * 64 + lk * 16) ^ ((vrow & 7) << 4)));
            acc_o[ni] = __builtin_amdgcn_mfma_f32_16x16x32_bf16(a, bfr, acc_o[ni], 0, 0, 0);
          }
        }
        __builtin_amdgcn_s_setprio(0);
      }
      cur ^= 1;
    }

    __syncthreads();
    if (lr == 0) {
#pragma unroll
      for (int j = 0; j < 4; ++j) {
        int r = wg * 16 + lk * 4 + j;
        smv[g * 64 + r] = m[j];
        slv[g * 64 + r] = l[j];
      }
    }
    __syncthreads();
    float myf[4], lcomb[4];
#pragma unroll
    for (int j = 0; j < 4; ++j) {
      int r = wg * 16 + lk * 4 + j;
      float m0 = smv[r], m1 = smv[64 + r];
      float l0 = slv[r], l1 = slv[64 + r];
      float mm = fmaxf(m0, m1);
      float f0 = exp2f(m0 - mm), f1 = exp2f(m1 - mm);
      lcomb[j] = l0 * f0 + l1 * f1;
      myf[j] = (g == 0) ? f0 : f1;
    }
    if (g == 1) {
#pragma unroll
      for (int j = 0; j < 4; ++j) {
        int r = wg * 16 + lk * 4 + j;
#pragma unroll
        for (int ni = 0; ni < 8; ++ni)
          accL[r * 132 + ni * 16 + lr] = acc_o[ni][j] * myf[j];
      }
    }
    __syncthreads();
    if (g == 0) {
#pragma unroll
      for (int j = 0; j < 4; ++j) {
        int row = q0 + wg * 16 + lk * 4 + j;
        int r = wg * 16 + lk * 4 + j;
        if (row < i0h) {
#pragma unroll
          for (int ni = 0; ni < 8; ++ni)
            ao[(size_t)row * 2048 + h * 128 + ni * 16 + lr] = f2bf(vmean[h * 128 + ni * 16 + lr]);
        } else {
          float inv = 1.f / lcomb[j];
#pragma unroll
          for (int ni = 0; ni < 8; ++ni) {
            float o = fmaf(acc_o[ni][j], myf[j], accL[r * 132 + ni * 16 + lr]);
            ao[(size_t)row * 2048 + h * 128 + ni * 16 + lr] = f2bf(o * inv);
          }
        }
      }
    }
  }
}

// ---------------------------------------------------------------------------
extern "C" void kernel_launch(void* const* d_in, const int* in_sizes, int n_in,
                              void* d_out, int out_size, void* d_ws, size_t ws_size,
                              hipStream_t stream)
{
  const float* hs    = (const float*)d_in[0];
  const float* amask = (const float*)d_in[1];
  const float* cosb  = (const float*)d_in[2];
  const float* sinb  = (const float*)d_in[3];
  const float* dmask = (const float*)d_in[4];
  const float* Wq    = (const float*)d_in[5];
  const float* Wk    = (const float*)d_in[6];
  const float* Wvq   = (const float*)d_in[7];
  const float* vkeys = (const float*)d_in[8];
  const float* vemb  = (const float*)d_in[9];
  const float* Wo    = (const float*)d_in[10];
  float* outp = (float*)d_out;

  char* ws = (char*)d_ws;
  const size_t MB = 1048576;
  // Lifetimes (phases A..E); high-water 70 MB.
  float*  pvq     = (float*) (ws + 0);              // A: [0,64) 16 partials
  float*  vq_f32  = (float*) (ws + 64*MB);          // A-B: [64,68)
  ushort* vq_bf   = (ushort*)(ws + 68*MB);          // A-B: [68,70)
  ushort* vkT     = (ushort*)(ws + 0);              // B: [0,2)   over dead pvq
  ushort* sim_bf  = (ushort*)(ws + 2*MB);           // B: [2,34)
  int*    idx     = (int*)   (ws + 34*MB);          // B-C: 128 KB
  float*  vkTf32  = (float*) (ws + 36*MB);          // B: [36,40) over dead pvq
  ushort* vemb_bf = (ushort*)(ws + 35*MB);          // C: [35,43) (after topk_sel)
  ushort* hs_bf   = (ushort*)(ws + 43*MB);          // C-D: [43,51)
  ushort* vb      = (ushort*)(ws + 0);              // C: [0,8)   over dead vkT/sim
  ushort* vt      = (ushort*)(ws + 8*MB);           // C-E: [8,16)
  float*  part    = (float*) (ws + 51*MB);          // C: 64 KB
  float*  vmean   = (float*) (ws + 51*MB + 65536);  // C-E: 8 KB
  int*    i0b     = (int*)   (ws + 51*MB + 73728);  // C-E: 64 B
  ushort* WBig    = (ushort*)(ws + 16*MB);          // D-E: [16,40) Wq|Wk|Wo^T
  ushort* WoT     = (ushort*)(ws + 32*MB);          // = WBig + 16MB
  ushort* qkC     = (ushort*)(ws + 52*MB);          // D-E: [52,68) q|k, ld 4096
  ushort* ao      = (ushort*)(ws + 0);              // E: [0,8)   over dead vb

  dim3 blk(256);
  // ---- routing path ----
  gemm_f32_sk<<<dim3(4, 16, 16), blk, 0, stream>>>(hs, 2048, Wvq, 512, pvq, 512, 2048, 512, 128);
  reduce16_cvt<<<dim3(1024), blk, 0, stream>>>(pvq, vq_f32, vq_bf);
  transpose_cvt_vk<<<dim3(32, 2, 4), blk, 0, stream>>>(vkeys, vkT, vkTf32);
  gemm_bf16<1, 0><<<dim3(16, 16, 4), blk, 0, stream>>>(vq_bf, 512, vkT, 128,
      sim_bf, 2048, 128, 128, 262144, 4194304, nullptr, nullptr);
  topk_sel<<<dim3(2048), blk, 0, stream>>>(sim_bf, vq_f32, vkTf32, idx);
  // ---- v construction ----
  cvt2_bf16<<<dim3(8192), blk, 0, stream>>>(vemb, vemb_bf, hs, hs_bf);
  gather_mul_bf<<<dim3(2048), blk, 0, stream>>>(hs, vemb_bf, idx, vb);
  transpose_bf<<<dim3(32, 32), blk, 0, stream>>>(vb, vt);
  vmean_part<<<dim3(8, 16), blk, 0, stream>>>(vb, part);
  vmean_i0<<<dim3(16), blk, 0, stream>>>(part, amask, dmask, vmean, i0b);
  // ---- projections: Wq|Wk|Wo transpose (z=3), fused qk GEMM + RoPE ----
  transpose_cvt_w3<<<dim3(32, 32, 3), blk, 0, stream>>>(Wq, Wk, Wo, WBig);
  gemm_bf16<1, 1><<<dim3(32, 16, 1), blk, 0, stream>>>(hs_bf, 2048, WBig, 2048,
      qkC, 4096, 2048, 0, 0, 0, cosb, sinb);
  // ---- attention (XCD-swizzled 1D grid) ----
  attn_mfma<<<dim3(256), dim3(512), 0, stream>>>(qkC, qkC + 2048, vt, amask, dmask, vmean, i0b, ao);
  // ---- output projection ----
  gemm_bf16<0, 0><<<dim3(16, 16, 1), blk, 0, stream>>>(ao, 2048, WoT, 2048,
      outp, 2048, 2048, 0, 0, 0, nullptr, nullptr);
}

// Round 11
// 326.040 us; speedup vs baseline: 11.6911x; 1.0352x over previous
//
#include <hip/hip_runtime.h>
#include <float.h>

// B=1, S=2048, D=2048, H=16, HD=128, HV=4, R=128, NV=2048, K=4
#define NEG_MIN (-3.4028234663852886e38f)
#define INV_SQRT_HD 0.08838834764831845f
#define SCALE_L2E 0.12751791437968458f    // INV_SQRT_HD * log2(e)

typedef __attribute__((ext_vector_type(8))) short bf16x8;
typedef __attribute__((ext_vector_type(8))) unsigned short u16x8;
typedef __attribute__((ext_vector_type(4))) float f32x4;

__device__ __forceinline__ void gload_lds16(const void* g, void* l) {
  __builtin_amdgcn_global_load_lds((const __attribute__((address_space(1))) void*)g,
                                   (__attribute__((address_space(3))) void*)l, 16, 0, 0);
}
__device__ __forceinline__ ushort f2bf(float x) {
  union { float f; unsigned u; } v; v.f = x;
  unsigned r = v.u + 0x7fffu + ((v.u >> 16) & 1u);   // RNE
  return (ushort)(r >> 16);
}
__device__ __forceinline__ float bf2f(ushort u) {
  union { unsigned i; float f; } v; v.i = ((unsigned)u) << 16; return v.f;
}
template<int CTRL>
__device__ __forceinline__ float dpp_ror(float x) {
  return __int_as_float(__builtin_amdgcn_mov_dpp(__float_as_int(x), CTRL, 0xF, 0xF, true));
}
template<int CTRL>
__device__ __forceinline__ unsigned dpp_ror_u(unsigned x) {
  return (unsigned)__builtin_amdgcn_mov_dpp((int)x, CTRL, 0xF, 0xF, true);
}
__device__ __forceinline__ unsigned wave_umax64(unsigned x) {
  x = max(x, dpp_ror_u<0x121>(x));
  x = max(x, dpp_ror_u<0x122>(x));
  x = max(x, dpp_ror_u<0x124>(x));
  x = max(x, dpp_ror_u<0x128>(x));
  x = max(x, (unsigned)__shfl_xor((int)x, 16));
  x = max(x, (unsigned)__shfl_xor((int)x, 32));
  return x;
}
__device__ __forceinline__ unsigned bf_sortable(ushort b) {
  return (b & 0x8000u) ? (unsigned)(b ^ 0xFFFFu) : (unsigned)(b | 0x8000u);
}

// ---------------------------------------------------------------------------
// Split-K f32 GEMM, 128x128 tile, 8x8 microtile, reg double-buffered staging.
// ---------------------------------------------------------------------------
__global__ __launch_bounds__(256) void gemm_f32_sk(
    const float* __restrict__ A, int lda,
    const float* __restrict__ B, int ldb,
    float* __restrict__ Cp, int ldc, int M, int N, int Kchunk)
{
  __shared__ float As[16][132];
  __shared__ float Bs[16][132];
  const int t = threadIdx.x, tx = t & 15, ty = t >> 4;
  const int bm = blockIdx.y << 7, bn = blockIdx.x << 7;
  const int k0base = blockIdx.z * Kchunk;
  const int arr = t >> 2, ac = (t & 3) << 2;
  const int brr = t >> 5, bc = (t & 31) << 2;

  float acc[8][8];
#pragma unroll
  for (int i = 0; i < 8; ++i)
#pragma unroll
    for (int j = 0; j < 8; ++j) acc[i][j] = 0.f;

  float4 pa0, pa1, pb0, pb1;
  pa0 = *(const float4*)(A + (size_t)(bm + arr) * lda + k0base + ac);
  pa1 = *(const float4*)(A + (size_t)(bm + arr + 64) * lda + k0base + ac);
  pb0 = *(const float4*)(B + (size_t)(k0base + brr) * ldb + bn + bc);
  pb1 = *(const float4*)(B + (size_t)(k0base + brr + 8) * ldb + bn + bc);

  for (int k0 = 0; k0 < Kchunk; k0 += 16) {
    __syncthreads();
    As[ac + 0][arr] = pa0.x; As[ac + 1][arr] = pa0.y;
    As[ac + 2][arr] = pa0.z; As[ac + 3][arr] = pa0.w;
    As[ac + 0][arr + 64] = pa1.x; As[ac + 1][arr + 64] = pa1.y;
    As[ac + 2][arr + 64] = pa1.z; As[ac + 3][arr + 64] = pa1.w;
    *(float4*)(&Bs[brr][bc])     = pb0;
    *(float4*)(&Bs[brr + 8][bc]) = pb1;
    __syncthreads();
    if (k0 + 16 < Kchunk) {
      int kn = k0base + k0 + 16;
      pa0 = *(const float4*)(A + (size_t)(bm + arr) * lda + kn + ac);
      pa1 = *(const float4*)(A + (size_t)(bm + arr + 64) * lda + kn + ac);
      pb0 = *(const float4*)(B + (size_t)(kn + brr) * ldb + bn + bc);
      pb1 = *(const float4*)(B + (size_t)(kn + brr + 8) * ldb + bn + bc);
    }
#pragma unroll
    for (int kk = 0; kk < 16; ++kk) {
      float4 a0 = *(const float4*)(&As[kk][ty * 8]);
      float4 a1 = *(const float4*)(&As[kk][ty * 8 + 4]);
      float4 b0 = *(const float4*)(&Bs[kk][tx * 4]);
      float4 b1 = *(const float4*)(&Bs[kk][tx * 4 + 64]);
      float av[8] = {a0.x, a0.y, a0.z, a0.w, a1.x, a1.y, a1.z, a1.w};
      float bv[8] = {b0.x, b0.y, b0.z, b0.w, b1.x, b1.y, b1.z, b1.w};
#pragma unroll
      for (int i = 0; i < 8; ++i)
#pragma unroll
        for (int j = 0; j < 8; ++j)
          acc[i][j] = fmaf(av[i], bv[j], acc[i][j]);
    }
  }
  float* C = Cp + (size_t)blockIdx.z * M * N;
#pragma unroll
  for (int i = 0; i < 8; ++i) {
    int row = bm + ty * 8 + i;
    *(float4*)(C + (size_t)row * ldc + bn + tx * 4) =
        make_float4(acc[i][0], acc[i][1], acc[i][2], acc[i][3]);
    *(float4*)(C + (size_t)row * ldc + bn + tx * 4 + 64) =
        make_float4(acc[i][4], acc[i][5], acc[i][6], acc[i][7]);
  }
}

// deterministic 16-way reduce of split-K partials + bf16 copy (1M floats)
__global__ __launch_bounds__(256) void reduce16_cvt(const float* __restrict__ Cp,
    float* __restrict__ vq, ushort* __restrict__ vq_bf)
{
  int i = (blockIdx.x * 256 + threadIdx.x) << 2;
  float4 s = make_float4(0.f, 0.f, 0.f, 0.f);
#pragma unroll
  for (int z = 0; z < 16; ++z) {
    float4 a = *(const float4*)(Cp + (size_t)z * 1048576 + i);
    s.x += a.x; s.y += a.y; s.z += a.z; s.w += a.w;
  }
  *(float4*)(vq + i) = s;
  ushort4 o; o.x = f2bf(s.x); o.y = f2bf(s.y); o.z = f2bf(s.z); o.w = f2bf(s.w);
  *(ushort4*)(vq_bf + i) = o;
}

// ---------------------------------------------------------------------------
// bf16 MFMA GEMM (z-batched): C = A @ Bt^T. 128x128 tile, BK=64.
// ROPE=1: fused RoPE epilogue for q-region blocks (bn<16); tile == one head.
// ---------------------------------------------------------------------------
template<int OUT_BF16, int ROPE>
__global__ __launch_bounds__(256) void gemm_bf16(
    const ushort* __restrict__ A0, int lda,
    const ushort* __restrict__ Bt0, int ldb,
    void* __restrict__ C0, int ldc, int Kd,
    size_t strA, size_t strB, size_t strC,
    const float* __restrict__ cosb, const float* __restrict__ sinb)
{
  const ushort* A  = A0  + blockIdx.z * strA;
  const ushort* Bt = Bt0 + blockIdx.z * strB;
  __shared__ ushort smem_g[2 * 128 * 64];     // As | Bs ; reused as rope buffer
  ushort* As = smem_g;
  ushort* Bs = smem_g + 128 * 64;
  const int t = threadIdx.x, w = t >> 6, lane = t & 63;
  const int lr = lane & 15, lk = lane >> 4;
  const int bm = blockIdx.y << 7, bn = blockIdx.x << 7;
  const int wm = (w >> 1) << 6, wn = (w & 1) << 6;
  f32x4 acc[4][4];
#pragma unroll
  for (int i = 0; i < 4; ++i)
#pragma unroll
    for (int j = 0; j < 4; ++j) acc[i][j] = (f32x4){0.f, 0.f, 0.f, 0.f};

  for (int k0 = 0; k0 < Kd; k0 += 64) {
    __syncthreads();
#pragma unroll
    for (int qI = 0; qI < 4; ++qI) {
      int b = w * 4096 + qI * 1024 + lane * 16;
      int row = b >> 7, colb = b & 127;
      int src = colb ^ ((row & 7) << 4);
      gload_lds16((const char*)A + ((size_t)(bm + row) * lda + k0) * 2 + src,
                  (char*)As + w * 4096 + qI * 1024);
    }
#pragma unroll
    for (int qI = 0; qI < 4; ++qI) {
      int b = w * 4096 + qI * 1024 + lane * 16;
      int row = b >> 7, colb = b & 127;
      int src = colb ^ ((row & 7) << 4);
      gload_lds16((const char*)Bt + ((size_t)(bn + row) * ldb + k0) * 2 + src,
                  (char*)Bs + w * 4096 + qI * 1024);
    }
    __syncthreads();
#pragma unroll
    for (int kk = 0; kk < 2; ++kk) {
      bf16x8 af[4], bf[4];
#pragma unroll
      for (int mi = 0; mi < 4; ++mi) {
        int row = wm + mi * 16 + lr;
        af[mi] = *(const bf16x8*)((const char*)As + row * 128 + ((kk * 64 + lk * 16) ^ ((row & 7) << 4)));
      }
#pragma unroll
      for (int ni = 0; ni < 4; ++ni) {
        int row = wn + ni * 16 + lr;
        bf[ni] = *(const bf16x8*)((const char*)Bs + row * 128 + ((kk * 64 + lk * 16) ^ ((row & 7) << 4)));
      }
#pragma unroll
      for (int mi = 0; mi < 4; ++mi)
#pragma unroll
        for (int ni = 0; ni < 4; ++ni)
          acc[mi][ni] = __builtin_amdgcn_mfma_f32_16x16x32_bf16(af[mi], bf[ni], acc[mi][ni], 0, 0, 0);
    }
  }

  if (ROPE && blockIdx.x < 16) {
    __syncthreads();
    ushort* Pl = smem_g;    // [128][128] bf16 = 32 KB
#pragma unroll
    for (int mi = 0; mi < 4; ++mi)
#pragma unroll
      for (int j = 0; j < 4; ++j) {
        int rl = wm + mi * 16 + lk * 4 + j;
#pragma unroll
        for (int ni = 0; ni < 4; ++ni)
          Pl[rl * 128 + wn + ni * 16 + lr] = f2bf(acc[mi][ni][j]);
      }
    __syncthreads();
    const bool lo = (wn == 0);    // wave-uniform: d < 64
#pragma unroll
    for (int mi = 0; mi < 4; ++mi)
#pragma unroll
      for (int j = 0; j < 4; ++j) {
        int rl = wm + mi * 16 + lk * 4 + j;
        int row = bm + rl;
#pragma unroll
        for (int ni = 0; ni < 4; ++ni) {
          int d = wn + ni * 16 + lr;
          float a = bf2f(Pl[rl * 128 + d]);
          float b = bf2f(Pl[rl * 128 + (d ^ 64)]);
          float cs = cosb[row * 128 + d], sn = sinb[row * 128 + d];
          float v = lo ? (a * cs - b * sn) : (a * cs + b * sn);
          ((ushort*)C0)[(size_t)row * ldc + bn + d] = f2bf(v);
        }
      }
    return;
  }

#pragma unroll
  for (int mi = 0; mi < 4; ++mi)
#pragma unroll
    for (int j = 0; j < 4; ++j) {
      int row = bm + wm + mi * 16 + lk * 4 + j;
#pragma unroll
      for (int ni = 0; ni < 4; ++ni) {
        int col = bn + wn + ni * 16 + lr;
        if (OUT_BF16) ((ushort*)C0)[blockIdx.z * strC + (size_t)row * ldc + col] = f2bf(acc[mi][ni][j]);
        else          ((float*)C0)[blockIdx.z * strC + (size_t)row * ldc + col]  = acc[mi][ni][j];
      }
    }
}

// ---------------------------------------------------------------------------
// vkeys transpose: dstb (bf16) and dstf (f32), both [hv][n=2048][r=128]
// ---------------------------------------------------------------------------
__global__ __launch_bounds__(256) void transpose_cvt_vk(
    const float* __restrict__ src0, ushort* __restrict__ dstb,
    float* __restrict__ dstf)
{
  const float* src = src0 + (size_t)blockIdx.z * 262144;
  ushort* db = dstb + (size_t)blockIdx.z * 262144;
  float*  df = dstf + (size_t)blockIdx.z * 262144;
  __shared__ float tile[64][65];
  const int r0 = blockIdx.y << 6, c0 = blockIdx.x << 6;
  const int t = threadIdx.x;
  for (int i = t; i < 1024; i += 256) {
    int r = i >> 4, c = (i & 15) << 2;
    float4 v = *(const float4*)(src + (size_t)(r0 + r) * 2048 + c0 + c);
    tile[r][c] = v.x; tile[r][c+1] = v.y; tile[r][c+2] = v.z; tile[r][c+3] = v.w;
  }
  __syncthreads();
  int c = t >> 2, rb = (t & 3) << 4;
#pragma unroll
  for (int u = 0; u < 16; u += 4) {
    float4 f = make_float4(tile[rb+u+0][c], tile[rb+u+1][c],
                           tile[rb+u+2][c], tile[rb+u+3][c]);
    ushort4 o; o.x = f2bf(f.x); o.y = f2bf(f.y); o.z = f2bf(f.z); o.w = f2bf(f.w);
    *(ushort4*)(db + (size_t)(c0 + c) * 128 + r0 + rb + u) = o;
    *(float4*) (df + (size_t)(c0 + c) * 128 + r0 + rb + u) = f;
  }
}

// triple-source weight transpose: z=0 Wq, z=1 Wk, z=2 Wo (2048x2048 each)
__global__ __launch_bounds__(256) void transpose_cvt_w3(
    const float* __restrict__ srcA, const float* __restrict__ srcB,
    const float* __restrict__ srcC, ushort* __restrict__ dst0)
{
  const float* src = (blockIdx.z == 0) ? srcA : (blockIdx.z == 1) ? srcB : srcC;
  ushort* dst = dst0 + (size_t)blockIdx.z * 4194304;
  __shared__ float tile[64][65];
  const int r0 = blockIdx.y << 6, c0 = blockIdx.x << 6;
  const int t = threadIdx.x;
  for (int i = t; i < 1024; i += 256) {
    int r = i >> 4, c = (i & 15) << 2;
    float4 v = *(const float4*)(src + (size_t)(r0 + r) * 2048 + c0 + c);
    tile[r][c] = v.x; tile[r][c+1] = v.y; tile[r][c+2] = v.z; tile[r][c+3] = v.w;
  }
  __syncthreads();
  int c = t >> 2, rb = (t & 3) << 4;
#pragma unroll
  for (int u = 0; u < 16; u += 4) {
    ushort4 o;
    o.x = f2bf(tile[rb+u+0][c]); o.y = f2bf(tile[rb+u+1][c]);
    o.z = f2bf(tile[rb+u+2][c]); o.w = f2bf(tile[rb+u+3][c]);
    *(ushort4*)(dst + (size_t)(c0 + c) * 2048 + r0 + rb + u) = o;
  }
}

// bf16 -> bf16 transpose (2048x2048)
__global__ __launch_bounds__(256) void transpose_bf(
    const ushort* __restrict__ src, ushort* __restrict__ dst)
{
  __shared__ ushort tile[64][66];
  const int r0 = blockIdx.y << 6, c0 = blockIdx.x << 6;
  const int t = threadIdx.x;
  for (int i = t; i < 512; i += 256) {
    int r = i >> 3, c8 = (i & 7) << 3;
    *(u16x8*)(&tile[r][c8]) = *(const u16x8*)(src + (size_t)(r0 + r) * 2048 + c0 + c8);
  }
  __syncthreads();
  for (int i = t; i < 512; i += 256) {
    int c = i >> 3, r8 = (i & 7) << 3;
    u16x8 o;
#pragma unroll
    for (int u = 0; u < 8; ++u) o[u] = tile[r8 + u][c];
    *(u16x8*)(dst + (size_t)(c0 + c) * 2048 + r0 + r8) = o;
  }
}

// two f32->bf16 conversions in one launch (4M elems each)
__global__ __launch_bounds__(256) void cvt2_bf16(const float* __restrict__ srcA,
    ushort* __restrict__ dstA, const float* __restrict__ srcB,
    ushort* __restrict__ dstB)
{
  int gid = blockIdx.x * 256 + threadIdx.x;
  const float* s; ushort* d; int i;
  if (gid < 1048576) { s = srcA; d = dstA; i = gid; }
  else               { s = srcB; d = dstB; i = gid - 1048576; }
  float4 v = ((const float4*)s)[i];
  ushort4 o; o.x = f2bf(v.x); o.y = f2bf(v.y); o.z = f2bf(v.z); o.w = f2bf(v.w);
  ((ushort4*)d)[i] = o;
}

// ---------------------------------------------------------------------------
// Fused top-k: packed-u32 candidates (sortable-bf16 | 2047-idx), DPP merge,
// exact f32 recompute on contiguous transposed v_keys, exact top-4.
// ---------------------------------------------------------------------------
__global__ __launch_bounds__(256) void topk_sel(const ushort* __restrict__ sim,
    const float* __restrict__ vq, const float* __restrict__ vkTf,
    int* __restrict__ idxo)
{
  const int row = blockIdx.x * 4 + (threadIdx.x >> 6);
  const int hv = row >> 11, s = row & 2047;
  const int lane = threadIdx.x & 63;
  const ushort* r = sim + (size_t)row * 2048;

  unsigned v[8];
#pragma unroll
  for (int p = 0; p < 8; ++p) v[p] = 0u;
  for (int j = 0; j < 4; ++j) {
    int nb = (lane + (j << 6)) << 3;
    u16x8 e = *(const u16x8*)(r + nb);
#pragma unroll
    for (int u = 0; u < 8; ++u) {
      unsigned pk = (bf_sortable(e[u]) << 16) | (unsigned)(2047 - (nb + u));
      if (pk > v[7]) {
        v[7] = pk;
#pragma unroll
        for (int p = 7; p > 0; --p)
          if (v[p] > v[p-1]) { unsigned tt = v[p]; v[p] = v[p-1]; v[p-1] = tt; }
      }
    }
  }
  int out_n[8];
#pragma unroll
  for (int r8 = 0; r8 < 8; ++r8) {
    unsigned m = wave_umax64(v[0]);
    out_n[r8] = 2047 - (int)(m & 0x7FFu);
    if (v[0] == m) {
#pragma unroll
      for (int p = 0; p < 7; ++p) v[p] = v[p+1];
      v[7] = 0u;
    }
  }
  const int c = lane & 7, rc = lane >> 3;
  int n = 0;
#pragma unroll
  for (int p = 0; p < 8; ++p) if (p == c) n = out_n[p];
  const float* vqr = vq + (size_t)s * 512 + hv * 128 + rc * 16;
  const float* vkf = vkTf + (size_t)hv * 262144 + (size_t)n * 128 + rc * 16;
  float acc = 0.f;
#pragma unroll
  for (int u = 0; u < 16; ++u) acc = fmaf(vqr[u], vkf[u], acc);
  acc += __shfl_xor(acc, 8);
  acc += __shfl_xor(acc, 16);
  acc += __shfl_xor(acc, 32);
  float cv = acc; int ci = n;
  int picks[4];
#pragma unroll
  for (int p = 0; p < 4; ++p) {
    float bv = cv; int bi = ci;
#pragma unroll
    for (int d = 1; d < 8; d <<= 1) {
      float ov = __shfl_xor(bv, d); int oi = __shfl_xor(bi, d);
      if (ov > bv || (ov == bv && oi < bi)) { bv = ov; bi = oi; }
    }
    picks[p] = bi;
    if (bi == ci) cv = -FLT_MAX;
  }
  if (lane == 0) {
#pragma unroll
    for (int p = 0; p < 4; ++p) idxo[(size_t)row * 4 + p] = picks[p];
  }
}

// ---------------------------------------------------------------------------
__global__ __launch_bounds__(256) void gather_mul_bf(const float* __restrict__ hs,
    const ushort* __restrict__ vemb_bf, const int* __restrict__ idx,
    ushort* __restrict__ vb)
{
  const int s = blockIdx.x;
  const int t = threadIdx.x;
  __shared__ int id[16];
  if (t < 16) id[t] = idx[((size_t)(t >> 2) * 2048 + s) * 4 + (t & 3)];
  __syncthreads();
  int d0 = t << 3;
  float g[8] = {0.f, 0.f, 0.f, 0.f, 0.f, 0.f, 0.f, 0.f};
#pragma unroll
  for (int e = 0; e < 16; ++e) {
    u16x8 ve = *(const u16x8*)(vemb_bf + (size_t)id[e] * 2048 + d0);
#pragma unroll
    for (int u = 0; u < 8; ++u) g[u] += bf2f(ve[u]);
  }
  float4 h0 = *(const float4*)(hs + (size_t)s * 2048 + d0);
  float4 h1 = *(const float4*)(hs + (size_t)s * 2048 + d0 + 4);
  float hv[8] = {h0.x, h0.y, h0.z, h0.w, h1.x, h1.y, h1.z, h1.w};
  u16x8 o;
#pragma unroll
  for (int u = 0; u < 8; ++u) o[u] = f2bf(hv[u] * g[u]);
  *(u16x8*)(vb + (size_t)s * 2048 + d0) = o;
}

__global__ __launch_bounds__(256) void vmean_part(const ushort* __restrict__ vb,
                                                  float* __restrict__ part)
{
  const int h = blockIdx.y, chunk = blockIdx.x;
  const int t = threadIdx.x, d = t & 127, half = t >> 7;
  float s = 0.f;
  int r0 = chunk * 256 + half * 128;
  for (int r = r0; r < r0 + 128; ++r)
    s += bf2f(vb[(size_t)r * 2048 + h * 128 + d]);
  __shared__ float red[256];
  red[t] = s;
  __syncthreads();
  if (t < 128) part[(size_t)(h * 8 + chunk) * 128 + d] = red[t] + red[t + 128];
}

__global__ __launch_bounds__(256) void vmean_i0(const float* __restrict__ part,
    const float* __restrict__ amask, const float* __restrict__ dmask,
    float* __restrict__ vmean, int* __restrict__ i0)
{
  const int h = blockIdx.x, t = threadIdx.x;
  if (t < 128) {
    float s = 0.f;
#pragma unroll
    for (int c = 0; c < 8; ++c) s += part[(size_t)(h * 8 + c) * 128 + t];
    vmean[h * 128 + t] = s * (1.f / 2048.f);
  }
  int best = 0x7fffffff;
  for (int j = t; j < 2048; j += 256) {
    if (amask[j] * dmask[h * 2048 + j] != 0.f) { best = j; break; }
  }
  __shared__ int red[256];
  red[t] = best;
  __syncthreads();
  for (int off = 128; off > 0; off >>= 1) {
    if (t < off) red[t] = min(red[t], red[t + off]);
    __syncthreads();
  }
  if (t == 0) i0[h] = red[0];
}

// ---------------------------------------------------------------------------
// MFMA flash attention, stripe-paired, 8 waves = 2 k-parity groups x 4 row
// waves, XCD-swizzled grid, exp2-domain online softmax with:
//   - defer-max (THR=16 in log2 domain): DPP max chain + rescale only when
//     the wave's tile max exceeds m+16 (rare after first real tile)
//   - row-sum l via MFMA ones-operand (acc_l), replacing the psum DPP chain
// ---------------------------------------------------------------------------
#define QLD 4096
__global__ __launch_bounds__(512) void attn_mfma(
    const ushort* __restrict__ qb, const ushort* __restrict__ kb,
    const ushort* __restrict__ vt, const float* __restrict__ amask,
    const float* __restrict__ dmask, const float* __restrict__ vmean,
    const int* __restrict__ i0, ushort* __restrict__ ao)
{
  const int L  = blockIdx.x;
  const int pr = L >> 4;                               // pair 0..15
  const int h  = (L & 7) | (((L >> 3) & 1) << 3);      // head; L%8 == h%8
  const int t  = threadIdx.x, w = t >> 6, lane = t & 63;
  const int g  = w >> 2, wg = w & 3;
  const int lr = lane & 15, lk = lane >> 4;

  __shared__ char smem[155648];
  float* accL  = (float*)smem;                      // [64][132] f32 (merge)
  float* smv   = (float*)(smem + 33792);            // [2][64]
  float* slv   = (float*)(smem + 33792 + 512);      // [2][64]
  float* maddL = (float*)(smem + 147456);           // [2048]

  const int i0h = i0[h];

  bf16x8 onesb;
#pragma unroll
  for (int u = 0; u < 8; ++u) onesb[u] = (short)0x3F80;  // bf16 1.0

  for (int j = t; j < 2048; j += 512)
    maddL[j] = (amask[j] * dmask[h * 2048 + j] == 0.f) ? NEG_MIN : 0.f;

  for (int sp = 0; sp < 2; ++sp) {
    const int stripe = (sp == 0) ? pr : 31 - pr;
    const int q0 = stripe << 6;
    const int ntiles = stripe + 1;

    __syncthreads();

    const int qrow = q0 + wg * 16 + lr;
    bf16x8 qf[4];
#pragma unroll
    for (int kk = 0; kk < 4; ++kk)
      qf[kk] = *(const bf16x8*)(qb + (size_t)qrow * QLD + h * 128 + kk * 32 + lk * 8);

    if (g < ntiles) {
      const int c0 = g << 6;
#pragma unroll
      for (int qI = 0; qI < 4; ++qI) {
        int b = wg * 4096 + qI * 1024 + lane * 16;
        int row = b >> 8, colb = b & 255;
        int src = colb ^ ((row & 7) << 4);
        gload_lds16((const char*)kb + ((size_t)(c0 + row) * QLD + h * 128) * 2 + src,
                    smem + g * 32768 + b);
      }
#pragma unroll
      for (int qI = 0; qI < 4; ++qI) {
        int b = wg * 4096 + qI * 1024 + lane * 16;
        int row = b >> 7, colb = b & 127;
        int src = colb ^ ((row & 7) << 4);
        gload_lds16((const char*)vt + ((size_t)(h * 128 + row) * 2048 + c0) * 2 + src,
                    smem + 65536 + g * 32768 + b);
      }
    }

    float m[4];
    f32x4 acc_l = (f32x4){0.f, 0.f, 0.f, 0.f};
    f32x4 acc_o[8];
#pragma unroll
    for (int j = 0; j < 4; ++j) m[j] = -FLT_MAX;
#pragma unroll
    for (int ni = 0; ni < 8; ++ni) acc_o[ni] = (f32x4){0.f, 0.f, 0.f, 0.f};

    int cur = 0;
    const int niter = (ntiles + 1) >> 1;
    for (int it = 0; it < niter; ++it) {
      const int tile = 2 * it + g;
      const int c0 = tile << 6;
      __syncthreads();

      float madd[4];
      if (tile < ntiles) {
#pragma unroll
        for (int ni = 0; ni < 4; ++ni)
          madd[ni] = maddL[c0 + ni * 16 + lr];
      }

      if (tile + 2 < ntiles) {
        const int cn = c0 + 128;
        const int nb = cur ^ 1;
#pragma unroll
        for (int qI = 0; qI < 4; ++qI) {
          int b = wg * 4096 + qI * 1024 + lane * 16;
          int row = b >> 8, colb = b & 255;
          int src = colb ^ ((row & 7) << 4);
          gload_lds16((const char*)kb + ((size_t)(cn + row) * QLD + h * 128) * 2 + src,
                      smem + g * 32768 + nb * 16384 + b);
        }
#pragma unroll
        for (int qI = 0; qI < 4; ++qI) {
          int b = wg * 4096 + qI * 1024 + lane * 16;
          int row = b >> 7, colb = b & 127;
          int src = colb ^ ((row & 7) << 4);
          gload_lds16((const char*)vt + ((size_t)(h * 128 + row) * 2048 + cn) * 2 + src,
                      smem + 65536 + g * 32768 + nb * 16384 + b);
        }
      }

      if (tile < ntiles) {
        const bool diag = (tile == stripe);
        const char* Kbase = smem + g * 32768 + cur * 16384;
        const char* Vbase = smem + 65536 + g * 32768 + cur * 16384;
        char* Pbase = smem + 131072 + g * 8192;

        f32x4 sacc[4];
#pragma unroll
        for (int ni = 0; ni < 4; ++ni) sacc[ni] = (f32x4){0.f, 0.f, 0.f, 0.f};
        __builtin_amdgcn_s_setprio(1);
#pragma unroll
        for (int kk = 0; kk < 4; ++kk) {
#pragma unroll
          for (int ni = 0; ni < 4; ++ni) {
            int krow = ni * 16 + lr;
            bf16x8 bfr = *(const bf16x8*)(Kbase + krow * 256 + ((kk * 64 + lk * 16) ^ ((krow & 7) << 4)));
            sacc[ni] = __builtin_amdgcn_mfma_f32_16x16x32_bf16(qf[kk], bfr, sacc[ni], 0, 0, 0);
          }
        }
        __builtin_amdgcn_s_setprio(0);

        // ---- softmax: defer-max; l comes from MFMA ones-column (acc_l)
#pragma unroll
        for (int j = 0; j < 4; ++j) {
          int grow = q0 + wg * 16 + lk * 4 + j;
          float x[4];
#pragma unroll
          for (int ni = 0; ni < 4; ++ni) {
            float v = fmaf(sacc[ni][j], SCALE_L2E, madd[ni]);
            if (diag && c0 + ni * 16 + lr > grow) v = NEG_MIN;
            x[ni] = v;
          }
          float pm = fmaxf(fmaxf(x[0], x[1]), fmaxf(x[2], x[3]));
          if (!__all(pm <= m[j] + 16.f)) {     // rare after first real tile
            float tmax = pm;
            tmax = fmaxf(tmax, dpp_ror<0x121>(tmax));
            tmax = fmaxf(tmax, dpp_ror<0x122>(tmax));
            tmax = fmaxf(tmax, dpp_ror<0x124>(tmax));
            tmax = fmaxf(tmax, dpp_ror<0x128>(tmax));
            float mn = fmaxf(m[j], tmax);
            if (mn > m[j]) {
              float sc = exp2f(m[j] - mn);
              acc_l[j] *= sc;
#pragma unroll
              for (int ni = 0; ni < 8; ++ni) acc_o[ni][j] *= sc;
              m[j] = mn;
            }
          }
          int prow = wg * 16 + lk * 4 + j;
#pragma unroll
          for (int ni = 0; ni < 4; ++ni) {
            float p = exp2f(x[ni] - m[j]);
            *(ushort*)(Pbase + prow * 128 + ((2 * (ni * 16 + lr)) ^ ((prow & 7) << 4))) = f2bf(p);
          }
        }

        __builtin_amdgcn_s_setprio(1);
#pragma unroll
        for (int kk = 0; kk < 2; ++kk) {
          int prow = wg * 16 + lr;
          bf16x8 a = *(const bf16x8*)(Pbase + prow * 128 + ((kk * 64 + lk * 16) ^ ((prow & 7) << 4)));
          acc_l = __builtin_amdgcn_mfma_f32_16x16x32_bf16(a, onesb, acc_l, 0, 0, 0);
#pragma unroll
          for (int ni = 0; ni < 8; ++ni) {
            int vrow = ni * 16 + lr;
            bf16x8 bfr = *(const bf16x8*)(Vbase + vrow * 128 + ((kk * 64 + lk * 16) ^ ((vrow & 7) << 4)));
            acc_o[ni] = __builtin_amdgcn_mfma_f32_16x16x32_bf16(a, bfr, acc_o[ni], 0, 0, 0);
          }
        }
        __builtin_amdgcn_s_setprio(0);
      }
      cur ^= 1;
    }

    __syncthreads();
    if (lr == 0) {
#pragma unroll
      for (int j = 0; j < 4; ++j) {
        int r = wg * 16 + lk * 4 + j;
        smv[g * 64 + r] = m[j];
        slv[g * 64 + r] = acc_l[j];
      }
    }
    __syncthreads();
    float myf[4], lcomb[4];
#pragma unroll
    for (int j = 0; j < 4; ++j) {
      int r = wg * 16 + lk * 4 + j;
      float m0 = smv[r], m1 = smv[64 + r];
      float l0 = slv[r], l1 = slv[64 + r];
      float mm = fmaxf(m0, m1);
      float f0 = exp2f(m0 - mm), f1 = exp2f(m1 - mm);
      lcomb[j] = l0 * f0 + l1 * f1;
      myf[j] = (g == 0) ? f0 : f1;
    }
    if (g == 1) {
#pragma unroll
      for (int j = 0; j < 4; ++j) {
        int r = wg * 16 + lk * 4 + j;
#pragma unroll
        for (int ni = 0; ni < 8; ++ni)
          accL[r * 132 + ni * 16 + lr] = acc_o[ni][j] * myf[j];
      }
    }
    __syncthreads();
    if (g == 0) {
#pragma unroll
      for (int j = 0; j < 4; ++j) {
        int row = q0 + wg * 16 + lk * 4 + j;
        int r = wg * 16 + lk * 4 + j;
        if (row < i0h) {
#pragma unroll
          for (int ni = 0; ni < 8; ++ni)
            ao[(size_t)row * 2048 + h * 128 + ni * 16 + lr] = f2bf(vmean[h * 128 + ni * 16 + lr]);
        } else {
          float inv = 1.f / lcomb[j];
#pragma unroll
          for (int ni = 0; ni < 8; ++ni) {
            float o = fmaf(acc_o[ni][j], myf[j], accL[r * 132 + ni * 16 + lr]);
            ao[(size_t)row * 2048 + h * 128 + ni * 16 + lr] = f2bf(o * inv);
          }
        }
      }
    }
  }
}

// ---------------------------------------------------------------------------
extern "C" void kernel_launch(void* const* d_in, const int* in_sizes, int n_in,
                              void* d_out, int out_size, void* d_ws, size_t ws_size,
                              hipStream_t stream)
{
  const float* hs    = (const float*)d_in[0];
  const float* amask = (const float*)d_in[1];
  const float* cosb  = (const float*)d_in[2];
  const float* sinb  = (const float*)d_in[3];
  const float* dmask = (const float*)d_in[4];
  const float* Wq    = (const float*)d_in[5];
  const float* Wk    = (const float*)d_in[6];
  const float* Wvq   = (const float*)d_in[7];
  const float* vkeys = (const float*)d_in[8];
  const float* vemb  = (const float*)d_in[9];
  const float* Wo    = (const float*)d_in[10];
  float* outp = (float*)d_out;

  char* ws = (char*)d_ws;
  const size_t MB = 1048576;
  float*  pvq     = (float*) (ws + 0);              // A: [0,64) 16 partials
  float*  vq_f32  = (float*) (ws + 64*MB);          // A-B: [64,68)
  ushort* vq_bf   = (ushort*)(ws + 68*MB);          // A-B: [68,70)
  ushort* vkT     = (ushort*)(ws + 0);              // B: [0,2)   over dead pvq
  ushort* sim_bf  = (ushort*)(ws + 2*MB);           // B: [2,34)
  int*    idx     = (int*)   (ws + 34*MB);          // B-C: 128 KB
  float*  vkTf32  = (float*) (ws + 36*MB);          // B: [36,40) over dead pvq
  ushort* vemb_bf = (ushort*)(ws + 35*MB);          // C: [35,43)
  ushort* hs_bf   = (ushort*)(ws + 43*MB);          // C-D: [43,51)
  ushort* vb      = (ushort*)(ws + 0);              // C: [0,8)   over dead vkT/sim
  ushort* vt      = (ushort*)(ws + 8*MB);           // C-E: [8,16)
  float*  part    = (float*) (ws + 51*MB);          // C: 64 KB
  float*  vmean   = (float*) (ws + 51*MB + 65536);  // C-E: 8 KB
  int*    i0b     = (int*)   (ws + 51*MB + 73728);  // C-E: 64 B
  ushort* WBig    = (ushort*)(ws + 16*MB);          // D-E: [16,40) Wq|Wk|Wo^T
  ushort* WoT     = (ushort*)(ws + 32*MB);          // = WBig + 16MB
  ushort* qkC     = (ushort*)(ws + 52*MB);          // D-E: [52,68) q|k, ld 4096
  ushort* ao      = (ushort*)(ws + 0);              // E: [0,8)   over dead vb

  dim3 blk(256);
  // ---- routing path ----
  gemm_f32_sk<<<dim3(4, 16, 16), blk, 0, stream>>>(hs, 2048, Wvq, 512, pvq, 512, 2048, 512, 128);
  reduce16_cvt<<<dim3(1024), blk, 0, stream>>>(pvq, vq_f32, vq_bf);
  transpose_cvt_vk<<<dim3(32, 2, 4), blk, 0, stream>>>(vkeys, vkT, vkTf32);
  gemm_bf16<1, 0><<<dim3(16, 16, 4), blk, 0, stream>>>(vq_bf, 512, vkT, 128,
      sim_bf, 2048, 128, 128, 262144, 4194304, nullptr, nullptr);
  topk_sel<<<dim3(2048), blk, 0, stream>>>(sim_bf, vq_f32, vkTf32, idx);
  // ---- v construction ----
  cvt2_bf16<<<dim3(8192), blk, 0, stream>>>(vemb, vemb_bf, hs, hs_bf);
  gather_mul_bf<<<dim3(2048), blk, 0, stream>>>(hs, vemb_bf, idx, vb);
  transpose_bf<<<dim3(32, 32), blk, 0, stream>>>(vb, vt);
  vmean_part<<<dim3(8, 16), blk, 0, stream>>>(vb, part);
  vmean_i0<<<dim3(16), blk, 0, stream>>>(part, amask, dmask, vmean, i0b);
  // ---- projections: Wq|Wk|Wo transpose (z=3), fused qk GEMM + RoPE ----
  transpose_cvt_w3<<<dim3(32, 32, 3), blk, 0, stream>>>(Wq, Wk, Wo, WBig);
  gemm_bf16<1, 1><<<dim3(32, 16, 1), blk, 0, stream>>>(hs_bf, 2048, WBig, 2048,
      qkC, 4096, 2048, 0, 0, 0, cosb, sinb);
  // ---- attention (XCD-swizzled 1D grid) ----
  attn_mfma<<<dim3(256), dim3(512), 0, stream>>>(qkC, qkC + 2048, vt, amask, dmask, vmean, i0b, ao);
  // ---- output projection ----
  gemm_bf16<0, 0><<<dim3(16, 16, 1), blk, 0, stream>>>(ao, 2048, WoT, 2048,
      outp, 2048, 2048, 0, 0, 0, nullptr, nullptr);
}

// Round 12
// 311.471 us; speedup vs baseline: 12.2379x; 1.0468x over previous
//
#include <hip/hip_runtime.h>
#include <float.h>

// B=1, S=2048, D=2048, H=16, HD=128, HV=4, R=128, NV=2048, K=4
#define NEG_MIN (-3.4028234663852886e38f)
#define INV_SQRT_HD 0.08838834764831845f
#define SCALE_L2E 0.12751791437968458f    // INV_SQRT_HD * log2(e)

typedef __attribute__((ext_vector_type(8))) short bf16x8;
typedef __attribute__((ext_vector_type(8))) unsigned short u16x8;
typedef __attribute__((ext_vector_type(4))) float f32x4;

__device__ __forceinline__ void gload_lds16(const void* g, void* l) {
  __builtin_amdgcn_global_load_lds((const __attribute__((address_space(1))) void*)g,
                                   (__attribute__((address_space(3))) void*)l, 16, 0, 0);
}
__device__ __forceinline__ ushort f2bf(float x) {
  union { float f; unsigned u; } v; v.f = x;
  unsigned r = v.u + 0x7fffu + ((v.u >> 16) & 1u);   // RNE
  return (ushort)(r >> 16);
}
__device__ __forceinline__ float bf2f(ushort u) {
  union { unsigned i; float f; } v; v.i = ((unsigned)u) << 16; return v.f;
}
template<int CTRL>
__device__ __forceinline__ float dpp_ror(float x) {
  return __int_as_float(__builtin_amdgcn_mov_dpp(__float_as_int(x), CTRL, 0xF, 0xF, true));
}
template<int CTRL>
__device__ __forceinline__ unsigned dpp_ror_u(unsigned x) {
  return (unsigned)__builtin_amdgcn_mov_dpp((int)x, CTRL, 0xF, 0xF, true);
}
__device__ __forceinline__ unsigned wave_umax64(unsigned x) {
  x = max(x, dpp_ror_u<0x121>(x));
  x = max(x, dpp_ror_u<0x122>(x));
  x = max(x, dpp_ror_u<0x124>(x));
  x = max(x, dpp_ror_u<0x128>(x));
  x = max(x, (unsigned)__shfl_xor((int)x, 16));
  x = max(x, (unsigned)__shfl_xor((int)x, 32));
  return x;
}
__device__ __forceinline__ unsigned bf_sortable(ushort b) {
  return (b & 0x8000u) ? (unsigned)(b ^ 0xFFFFu) : (unsigned)(b | 0x8000u);
}

// ---------------------------------------------------------------------------
// Split-K f32 GEMM, 128x128 tile, 8x8 microtile, reg double-buffered staging.
// z=8 (Kchunk=256): halves split-K partial traffic vs R11's z=16.
// ---------------------------------------------------------------------------
__global__ __launch_bounds__(256) void gemm_f32_sk(
    const float* __restrict__ A, int lda,
    const float* __restrict__ B, int ldb,
    float* __restrict__ Cp, int ldc, int M, int N, int Kchunk)
{
  __shared__ float As[16][132];
  __shared__ float Bs[16][132];
  const int t = threadIdx.x, tx = t & 15, ty = t >> 4;
  const int bm = blockIdx.y << 7, bn = blockIdx.x << 7;
  const int k0base = blockIdx.z * Kchunk;
  const int arr = t >> 2, ac = (t & 3) << 2;
  const int brr = t >> 5, bc = (t & 31) << 2;

  float acc[8][8];
#pragma unroll
  for (int i = 0; i < 8; ++i)
#pragma unroll
    for (int j = 0; j < 8; ++j) acc[i][j] = 0.f;

  float4 pa0, pa1, pb0, pb1;
  pa0 = *(const float4*)(A + (size_t)(bm + arr) * lda + k0base + ac);
  pa1 = *(const float4*)(A + (size_t)(bm + arr + 64) * lda + k0base + ac);
  pb0 = *(const float4*)(B + (size_t)(k0base + brr) * ldb + bn + bc);
  pb1 = *(const float4*)(B + (size_t)(k0base + brr + 8) * ldb + bn + bc);

  for (int k0 = 0; k0 < Kchunk; k0 += 16) {
    __syncthreads();
    As[ac + 0][arr] = pa0.x; As[ac + 1][arr] = pa0.y;
    As[ac + 2][arr] = pa0.z; As[ac + 3][arr] = pa0.w;
    As[ac + 0][arr + 64] = pa1.x; As[ac + 1][arr + 64] = pa1.y;
    As[ac + 2][arr + 64] = pa1.z; As[ac + 3][arr + 64] = pa1.w;
    *(float4*)(&Bs[brr][bc])     = pb0;
    *(float4*)(&Bs[brr + 8][bc]) = pb1;
    __syncthreads();
    if (k0 + 16 < Kchunk) {
      int kn = k0base + k0 + 16;
      pa0 = *(const float4*)(A + (size_t)(bm + arr) * lda + kn + ac);
      pa1 = *(const float4*)(A + (size_t)(bm + arr + 64) * lda + kn + ac);
      pb0 = *(const float4*)(B + (size_t)(kn + brr) * ldb + bn + bc);
      pb1 = *(const float4*)(B + (size_t)(kn + brr + 8) * ldb + bn + bc);
    }
#pragma unroll
    for (int kk = 0; kk < 16; ++kk) {
      float4 a0 = *(const float4*)(&As[kk][ty * 8]);
      float4 a1 = *(const float4*)(&As[kk][ty * 8 + 4]);
      float4 b0 = *(const float4*)(&Bs[kk][tx * 4]);
      float4 b1 = *(const float4*)(&Bs[kk][tx * 4 + 64]);
      float av[8] = {a0.x, a0.y, a0.z, a0.w, a1.x, a1.y, a1.z, a1.w};
      float bv[8] = {b0.x, b0.y, b0.z, b0.w, b1.x, b1.y, b1.z, b1.w};
#pragma unroll
      for (int i = 0; i < 8; ++i)
#pragma unroll
        for (int j = 0; j < 8; ++j)
          acc[i][j] = fmaf(av[i], bv[j], acc[i][j]);
    }
  }
  float* C = Cp + (size_t)blockIdx.z * M * N;
#pragma unroll
  for (int i = 0; i < 8; ++i) {
    int row = bm + ty * 8 + i;
    *(float4*)(C + (size_t)row * ldc + bn + tx * 4) =
        make_float4(acc[i][0], acc[i][1], acc[i][2], acc[i][3]);
    *(float4*)(C + (size_t)row * ldc + bn + tx * 4 + 64) =
        make_float4(acc[i][4], acc[i][5], acc[i][6], acc[i][7]);
  }
}

// deterministic 8-way reduce of split-K partials + bf16 copy (1M floats)
__global__ __launch_bounds__(256) void reduce8_cvt(const float* __restrict__ Cp,
    float* __restrict__ vq, ushort* __restrict__ vq_bf)
{
  int i = (blockIdx.x * 256 + threadIdx.x) << 2;
  float4 s = make_float4(0.f, 0.f, 0.f, 0.f);
#pragma unroll
  for (int z = 0; z < 8; ++z) {
    float4 a = *(const float4*)(Cp + (size_t)z * 1048576 + i);
    s.x += a.x; s.y += a.y; s.z += a.z; s.w += a.w;
  }
  *(float4*)(vq + i) = s;
  ushort4 o; o.x = f2bf(s.x); o.y = f2bf(s.y); o.z = f2bf(s.z); o.w = f2bf(s.w);
  *(ushort4*)(vq_bf + i) = o;
}

// ---------------------------------------------------------------------------
// bf16 MFMA GEMM (z-batched): C = A @ Bt^T. 128x128 tile, BK=64.
// 2-phase double-buffered LDS: stage(next) issued BEFORE compute(cur), one
// barrier per K-step -> staging overlaps MFMA (T3-minimum, §5.5).
// ROPE=1: fused RoPE epilogue for q-region blocks (bn<16); tile == one head.
// ---------------------------------------------------------------------------
template<int OUT_BF16, int ROPE>
__global__ __launch_bounds__(256) void gemm_bf16(
    const ushort* __restrict__ A0, int lda,
    const ushort* __restrict__ Bt0, int ldb,
    void* __restrict__ C0, int ldc, int Kd,
    size_t strA, size_t strB, size_t strC,
    const float* __restrict__ cosb, const float* __restrict__ sinb)
{
  const ushort* A  = A0  + blockIdx.z * strA;
  const ushort* Bt = Bt0 + blockIdx.z * strB;
  __shared__ ushort As[2][128 * 64];
  __shared__ ushort Bs[2][128 * 64];
  const int t = threadIdx.x, w = t >> 6, lane = t & 63;
  const int lr = lane & 15, lk = lane >> 4;
  const int bm = blockIdx.y << 7, bn = blockIdx.x << 7;
  const int wm = (w >> 1) << 6, wn = (w & 1) << 6;
  f32x4 acc[4][4];
#pragma unroll
  for (int i = 0; i < 4; ++i)
#pragma unroll
    for (int j = 0; j < 4; ++j) acc[i][j] = (f32x4){0.f, 0.f, 0.f, 0.f};

  // staging: wave-uniform LDS dest + pre-swizzled global source
#define STAGE_QK(buf, kk0)                                                     \
  {                                                                            \
_Pragma("unroll")                                                              \
    for (int qI = 0; qI < 4; ++qI) {                                           \
      int b = w * 4096 + qI * 1024 + lane * 16;                                \
      int row = b >> 7, colb = b & 127;                                        \
      int src = colb ^ ((row & 7) << 4);                                       \
      gload_lds16((const char*)A + ((size_t)(bm + row) * lda + (kk0)) * 2 + src,\
                  (char*)As[buf] + w * 4096 + qI * 1024);                      \
      gload_lds16((const char*)Bt + ((size_t)(bn + row) * ldb + (kk0)) * 2 + src,\
                  (char*)Bs[buf] + w * 4096 + qI * 1024);                      \
    }                                                                          \
  }

  STAGE_QK(0, 0);
  int cur = 0;
  for (int k0 = 0; k0 < Kd; k0 += 64) {
    __syncthreads();               // buf[cur] loaded; prev-tile readers done
    if (k0 + 64 < Kd) STAGE_QK(cur ^ 1, k0 + 64);   // overlaps compute below
#pragma unroll
    for (int kk = 0; kk < 2; ++kk) {
      bf16x8 af[4], bf[4];
#pragma unroll
      for (int mi = 0; mi < 4; ++mi) {
        int row = wm + mi * 16 + lr;
        af[mi] = *(const bf16x8*)((const char*)As[cur] + row * 128 + ((kk * 64 + lk * 16) ^ ((row & 7) << 4)));
      }
#pragma unroll
      for (int ni = 0; ni < 4; ++ni) {
        int row = wn + ni * 16 + lr;
        bf[ni] = *(const bf16x8*)((const char*)Bs[cur] + row * 128 + ((kk * 64 + lk * 16) ^ ((row & 7) << 4)));
      }
#pragma unroll
      for (int mi = 0; mi < 4; ++mi)
#pragma unroll
        for (int ni = 0; ni < 4; ++ni)
          acc[mi][ni] = __builtin_amdgcn_mfma_f32_16x16x32_bf16(af[mi], bf[ni], acc[mi][ni], 0, 0, 0);
    }
    cur ^= 1;
  }
#undef STAGE_QK

  if (ROPE && blockIdx.x < 16) {
    // q-region: tile = head blockIdx.x, cols = d 0..127. RoPE via LDS exchange.
    __syncthreads();
    ushort* Pl = (ushort*)As;    // [128][128] bf16 = 32 KB
#pragma unroll
    for (int mi = 0; mi < 4; ++mi)
#pragma unroll
      for (int j = 0; j < 4; ++j) {
        int rl = wm + mi * 16 + lk * 4 + j;
#pragma unroll
        for (int ni = 0; ni < 4; ++ni)
          Pl[rl * 128 + wn + ni * 16 + lr] = f2bf(acc[mi][ni][j]);
      }
    __syncthreads();
    const bool lo = (wn == 0);    // wave-uniform: d < 64
#pragma unroll
    for (int mi = 0; mi < 4; ++mi)
#pragma unroll
      for (int j = 0; j < 4; ++j) {
        int rl = wm + mi * 16 + lk * 4 + j;
        int row = bm + rl;
#pragma unroll
        for (int ni = 0; ni < 4; ++ni) {
          int d = wn + ni * 16 + lr;
          float a = bf2f(Pl[rl * 128 + d]);
          float b = bf2f(Pl[rl * 128 + (d ^ 64)]);
          float cs = cosb[row * 128 + d], sn = sinb[row * 128 + d];
          float v = lo ? (a * cs - b * sn) : (a * cs + b * sn);
          ((ushort*)C0)[(size_t)row * ldc + bn + d] = f2bf(v);
        }
      }
    return;
  }

#pragma unroll
  for (int mi = 0; mi < 4; ++mi)
#pragma unroll
    for (int j = 0; j < 4; ++j) {
      int row = bm + wm + mi * 16 + lk * 4 + j;
#pragma unroll
      for (int ni = 0; ni < 4; ++ni) {
        int col = bn + wn + ni * 16 + lr;
        if (OUT_BF16) ((ushort*)C0)[blockIdx.z * strC + (size_t)row * ldc + col] = f2bf(acc[mi][ni][j]);
        else          ((float*)C0)[blockIdx.z * strC + (size_t)row * ldc + col]  = acc[mi][ni][j];
      }
    }
}

// ---------------------------------------------------------------------------
// vkeys transpose: dstb (bf16) and dstf (f32), both [hv][n=2048][r=128]
// ---------------------------------------------------------------------------
__global__ __launch_bounds__(256) void transpose_cvt_vk(
    const float* __restrict__ src0, ushort* __restrict__ dstb,
    float* __restrict__ dstf)
{
  const float* src = src0 + (size_t)blockIdx.z * 262144;
  ushort* db = dstb + (size_t)blockIdx.z * 262144;
  float*  df = dstf + (size_t)blockIdx.z * 262144;
  __shared__ float tile[64][65];
  const int r0 = blockIdx.y << 6, c0 = blockIdx.x << 6;
  const int t = threadIdx.x;
  for (int i = t; i < 1024; i += 256) {
    int r = i >> 4, c = (i & 15) << 2;
    float4 v = *(const float4*)(src + (size_t)(r0 + r) * 2048 + c0 + c);
    tile[r][c] = v.x; tile[r][c+1] = v.y; tile[r][c+2] = v.z; tile[r][c+3] = v.w;
  }
  __syncthreads();
  int c = t >> 2, rb = (t & 3) << 4;
#pragma unroll
  for (int u = 0; u < 16; u += 4) {
    float4 f = make_float4(tile[rb+u+0][c], tile[rb+u+1][c],
                           tile[rb+u+2][c], tile[rb+u+3][c]);
    ushort4 o; o.x = f2bf(f.x); o.y = f2bf(f.y); o.z = f2bf(f.z); o.w = f2bf(f.w);
    *(ushort4*)(db + (size_t)(c0 + c) * 128 + r0 + rb + u) = o;
    *(float4*) (df + (size_t)(c0 + c) * 128 + r0 + rb + u) = f;
  }
}

// triple-source weight transpose: z=0 Wq, z=1 Wk, z=2 Wo (2048x2048 each)
__global__ __launch_bounds__(256) void transpose_cvt_w3(
    const float* __restrict__ srcA, const float* __restrict__ srcB,
    const float* __restrict__ srcC, ushort* __restrict__ dst0)
{
  const float* src = (blockIdx.z == 0) ? srcA : (blockIdx.z == 1) ? srcB : srcC;
  ushort* dst = dst0 + (size_t)blockIdx.z * 4194304;
  __shared__ float tile[64][65];
  const int r0 = blockIdx.y << 6, c0 = blockIdx.x << 6;
  const int t = threadIdx.x;
  for (int i = t; i < 1024; i += 256) {
    int r = i >> 4, c = (i & 15) << 2;
    float4 v = *(const float4*)(src + (size_t)(r0 + r) * 2048 + c0 + c);
    tile[r][c] = v.x; tile[r][c+1] = v.y; tile[r][c+2] = v.z; tile[r][c+3] = v.w;
  }
  __syncthreads();
  int c = t >> 2, rb = (t & 3) << 4;
#pragma unroll
  for (int u = 0; u < 16; u += 4) {
    ushort4 o;
    o.x = f2bf(tile[rb+u+0][c]); o.y = f2bf(tile[rb+u+1][c]);
    o.z = f2bf(tile[rb+u+2][c]); o.w = f2bf(tile[rb+u+3][c]);
    *(ushort4*)(dst + (size_t)(c0 + c) * 2048 + r0 + rb + u) = o;
  }
}

// bf16 -> bf16 transpose (2048x2048)
__global__ __launch_bounds__(256) void transpose_bf(
    const ushort* __restrict__ src, ushort* __restrict__ dst)
{
  __shared__ ushort tile[64][66];
  const int r0 = blockIdx.y << 6, c0 = blockIdx.x << 6;
  const int t = threadIdx.x;
  for (int i = t; i < 512; i += 256) {
    int r = i >> 3, c8 = (i & 7) << 3;
    *(u16x8*)(&tile[r][c8]) = *(const u16x8*)(src + (size_t)(r0 + r) * 2048 + c0 + c8);
  }
  __syncthreads();
  for (int i = t; i < 512; i += 256) {
    int c = i >> 3, r8 = (i & 7) << 3;
    u16x8 o;
#pragma unroll
    for (int u = 0; u < 8; ++u) o[u] = tile[r8 + u][c];
    *(u16x8*)(dst + (size_t)(c0 + c) * 2048 + r0 + r8) = o;
  }
}

// two f32->bf16 conversions in one launch (4M elems each)
__global__ __launch_bounds__(256) void cvt2_bf16(const float* __restrict__ srcA,
    ushort* __restrict__ dstA, const float* __restrict__ srcB,
    ushort* __restrict__ dstB)
{
  int gid = blockIdx.x * 256 + threadIdx.x;
  const float* s; ushort* d; int i;
  if (gid < 1048576) { s = srcA; d = dstA; i = gid; }
  else               { s = srcB; d = dstB; i = gid - 1048576; }
  float4 v = ((const float4*)s)[i];
  ushort4 o; o.x = f2bf(v.x); o.y = f2bf(v.y); o.z = f2bf(v.z); o.w = f2bf(v.w);
  ((ushort4*)d)[i] = o;
}

// ---------------------------------------------------------------------------
// Fused top-k: packed-u32 candidates (sortable-bf16 | 2047-idx), DPP merge,
// exact f32 recompute on contiguous transposed v_keys, exact top-4.
// ---------------------------------------------------------------------------
__global__ __launch_bounds__(256) void topk_sel(const ushort* __restrict__ sim,
    const float* __restrict__ vq, const float* __restrict__ vkTf,
    int* __restrict__ idxo)
{
  const int row = blockIdx.x * 4 + (threadIdx.x >> 6);
  const int hv = row >> 11, s = row & 2047;
  const int lane = threadIdx.x & 63;
  const ushort* r = sim + (size_t)row * 2048;

  unsigned v[8];
#pragma unroll
  for (int p = 0; p < 8; ++p) v[p] = 0u;
  for (int j = 0; j < 4; ++j) {
    int nb = (lane + (j << 6)) << 3;
    u16x8 e = *(const u16x8*)(r + nb);
#pragma unroll
    for (int u = 0; u < 8; ++u) {
      unsigned pk = (bf_sortable(e[u]) << 16) | (unsigned)(2047 - (nb + u));
      if (pk > v[7]) {
        v[7] = pk;
#pragma unroll
        for (int p = 7; p > 0; --p)
          if (v[p] > v[p-1]) { unsigned tt = v[p]; v[p] = v[p-1]; v[p-1] = tt; }
      }
    }
  }
  int out_n[8];
#pragma unroll
  for (int r8 = 0; r8 < 8; ++r8) {
    unsigned m = wave_umax64(v[0]);
    out_n[r8] = 2047 - (int)(m & 0x7FFu);
    if (v[0] == m) {
#pragma unroll
      for (int p = 0; p < 7; ++p) v[p] = v[p+1];
      v[7] = 0u;
    }
  }
  const int c = lane & 7, rc = lane >> 3;
  int n = 0;
#pragma unroll
  for (int p = 0; p < 8; ++p) if (p == c) n = out_n[p];
  const float* vqr = vq + (size_t)s * 512 + hv * 128 + rc * 16;
  const float* vkf = vkTf + (size_t)hv * 262144 + (size_t)n * 128 + rc * 16;
  float acc = 0.f;
#pragma unroll
  for (int u = 0; u < 16; ++u) acc = fmaf(vqr[u], vkf[u], acc);
  acc += __shfl_xor(acc, 8);
  acc += __shfl_xor(acc, 16);
  acc += __shfl_xor(acc, 32);
  float cv = acc; int ci = n;
  int picks[4];
#pragma unroll
  for (int p = 0; p < 4; ++p) {
    float bv = cv; int bi = ci;
#pragma unroll
    for (int d = 1; d < 8; d <<= 1) {
      float ov = __shfl_xor(bv, d); int oi = __shfl_xor(bi, d);
      if (ov > bv || (ov == bv && oi < bi)) { bv = ov; bi = oi; }
    }
    picks[p] = bi;
    if (bi == ci) cv = -FLT_MAX;
  }
  if (lane == 0) {
#pragma unroll
    for (int p = 0; p < 4; ++p) idxo[(size_t)row * 4 + p] = picks[p];
  }
}

// ---------------------------------------------------------------------------
__global__ __launch_bounds__(256) void gather_mul_bf(const float* __restrict__ hs,
    const ushort* __restrict__ vemb_bf, const int* __restrict__ idx,
    ushort* __restrict__ vb)
{
  const int s = blockIdx.x;
  const int t = threadIdx.x;
  __shared__ int id[16];
  if (t < 16) id[t] = idx[((size_t)(t >> 2) * 2048 + s) * 4 + (t & 3)];
  __syncthreads();
  int d0 = t << 3;
  float g[8] = {0.f, 0.f, 0.f, 0.f, 0.f, 0.f, 0.f, 0.f};
#pragma unroll
  for (int e = 0; e < 16; ++e) {
    u16x8 ve = *(const u16x8*)(vemb_bf + (size_t)id[e] * 2048 + d0);
#pragma unroll
    for (int u = 0; u < 8; ++u) g[u] += bf2f(ve[u]);
  }
  float4 h0 = *(const float4*)(hs + (size_t)s * 2048 + d0);
  float4 h1 = *(const float4*)(hs + (size_t)s * 2048 + d0 + 4);
  float hv[8] = {h0.x, h0.y, h0.z, h0.w, h1.x, h1.y, h1.z, h1.w};
  u16x8 o;
#pragma unroll
  for (int u = 0; u < 8; ++u) o[u] = f2bf(hv[u] * g[u]);
  *(u16x8*)(vb + (size_t)s * 2048 + d0) = o;
}

__global__ __launch_bounds__(256) void vmean_part(const ushort* __restrict__ vb,
                                                  float* __restrict__ part)
{
  const int h = blockIdx.y, chunk = blockIdx.x;
  const int t = threadIdx.x, d = t & 127, half = t >> 7;
  float s = 0.f;
  int r0 = chunk * 256 + half * 128;
  for (int r = r0; r < r0 + 128; ++r)
    s += bf2f(vb[(size_t)r * 2048 + h * 128 + d]);
  __shared__ float red[256];
  red[t] = s;
  __syncthreads();
  if (t < 128) part[(size_t)(h * 8 + chunk) * 128 + d] = red[t] + red[t + 128];
}

__global__ __launch_bounds__(256) void vmean_i0(const float* __restrict__ part,
    const float* __restrict__ amask, const float* __restrict__ dmask,
    float* __restrict__ vmean, int* __restrict__ i0)
{
  const int h = blockIdx.x, t = threadIdx.x;
  if (t < 128) {
    float s = 0.f;
#pragma unroll
    for (int c = 0; c < 8; ++c) s += part[(size_t)(h * 8 + c) * 128 + t];
    vmean[h * 128 + t] = s * (1.f / 2048.f);
  }
  int best = 0x7fffffff;
  for (int j = t; j < 2048; j += 256) {
    if (amask[j] * dmask[h * 2048 + j] != 0.f) { best = j; break; }
  }
  __shared__ int red[256];
  red[t] = best;
  __syncthreads();
  for (int off = 128; off > 0; off >>= 1) {
    if (t < off) red[t] = min(red[t], red[t + off]);
    __syncthreads();
  }
  if (t == 0) i0[h] = red[0];
}

// ---------------------------------------------------------------------------
// MFMA flash attention, stripe-paired, 8 waves = 2 k-parity groups x 4 row
// waves, XCD-swizzled grid, exp2-domain online softmax, defer-max + MFMA-l.
// ---------------------------------------------------------------------------
#define QLD 4096
__global__ __launch_bounds__(512) void attn_mfma(
    const ushort* __restrict__ qb, const ushort* __restrict__ kb,
    const ushort* __restrict__ vt, const float* __restrict__ amask,
    const float* __restrict__ dmask, const float* __restrict__ vmean,
    const int* __restrict__ i0, ushort* __restrict__ ao)
{
  const int L  = blockIdx.x;
  const int pr = L >> 4;                               // pair 0..15
  const int h  = (L & 7) | (((L >> 3) & 1) << 3);      // head; L%8 == h%8
  const int t  = threadIdx.x, w = t >> 6, lane = t & 63;
  const int g  = w >> 2, wg = w & 3;
  const int lr = lane & 15, lk = lane >> 4;

  __shared__ char smem[155648];
  float* accL  = (float*)smem;                      // [64][132] f32 (merge)
  float* smv   = (float*)(smem + 33792);            // [2][64]
  float* slv   = (float*)(smem + 33792 + 512);      // [2][64]
  float* maddL = (float*)(smem + 147456);           // [2048]

  const int i0h = i0[h];

  bf16x8 onesb;
#pragma unroll
  for (int u = 0; u < 8; ++u) onesb[u] = (short)0x3F80;  // bf16 1.0

  for (int j = t; j < 2048; j += 512)
    maddL[j] = (amask[j] * dmask[h * 2048 + j] == 0.f) ? NEG_MIN : 0.f;

  for (int sp = 0; sp < 2; ++sp) {
    const int stripe = (sp == 0) ? pr : 31 - pr;
    const int q0 = stripe << 6;
    const int ntiles = stripe + 1;

    __syncthreads();

    const int qrow = q0 + wg * 16 + lr;
    bf16x8 qf[4];
#pragma unroll
    for (int kk = 0; kk < 4; ++kk)
      qf[kk] = *(const bf16x8*)(qb + (size_t)qrow * QLD + h * 128 + kk * 32 + lk * 8);

    if (g < ntiles) {
      const int c0 = g << 6;
#pragma unroll
      for (int qI = 0; qI < 4; ++qI) {
        int b = wg * 4096 + qI * 1024 + lane * 16;
        int row = b >> 8, colb = b & 255;
        int src = colb ^ ((row & 7) << 4);
        gload_lds16((const char*)kb + ((size_t)(c0 + row) * QLD + h * 128) * 2 + src,
                    smem + g * 32768 + b);
      }
#pragma unroll
      for (int qI = 0; qI < 4; ++qI) {
        int b = wg * 4096 + qI * 1024 + lane * 16;
        int row = b >> 7, colb = b & 127;
        int src = colb ^ ((row & 7) << 4);
        gload_lds16((const char*)vt + ((size_t)(h * 128 + row) * 2048 + c0) * 2 + src,
                    smem + 65536 + g * 32768 + b);
      }
    }

    float m[4];
    f32x4 acc_l = (f32x4){0.f, 0.f, 0.f, 0.f};
    f32x4 acc_o[8];
#pragma unroll
    for (int j = 0; j < 4; ++j) m[j] = -FLT_MAX;
#pragma unroll
    for (int ni = 0; ni < 8; ++ni) acc_o[ni] = (f32x4){0.f, 0.f, 0.f, 0.f};

    int cur = 0;
    const int niter = (ntiles + 1) >> 1;
    for (int it = 0; it < niter; ++it) {
      const int tile = 2 * it + g;
      const int c0 = tile << 6;
      __syncthreads();

      float madd[4];
      if (tile < ntiles) {
#pragma unroll
        for (int ni = 0; ni < 4; ++ni)
          madd[ni] = maddL[c0 + ni * 16 + lr];
      }

      if (tile + 2 < ntiles) {
        const int cn = c0 + 128;
        const int nb = cur ^ 1;
#pragma unroll
        for (int qI = 0; qI < 4; ++qI) {
          int b = wg * 4096 + qI * 1024 + lane * 16;
          int row = b >> 8, colb = b & 255;
          int src = colb ^ ((row & 7) << 4);
          gload_lds16((const char*)kb + ((size_t)(cn + row) * QLD + h * 128) * 2 + src,
                      smem + g * 32768 + nb * 16384 + b);
        }
#pragma unroll
        for (int qI = 0; qI < 4; ++qI) {
          int b = wg * 4096 + qI * 1024 + lane * 16;
          int row = b >> 7, colb = b & 127;
          int src = colb ^ ((row & 7) << 4);
          gload_lds16((const char*)vt + ((size_t)(h * 128 + row) * 2048 + cn) * 2 + src,
                      smem + 65536 + g * 32768 + nb * 16384 + b);
        }
      }

      if (tile < ntiles) {
        const bool diag = (tile == stripe);
        const char* Kbase = smem + g * 32768 + cur * 16384;
        const char* Vbase = smem + 65536 + g * 32768 + cur * 16384;
        char* Pbase = smem + 131072 + g * 8192;

        f32x4 sacc[4];
#pragma unroll
        for (int ni = 0; ni < 4; ++ni) sacc[ni] = (f32x4){0.f, 0.f, 0.f, 0.f};
        __builtin_amdgcn_s_setprio(1);
#pragma unroll
        for (int kk = 0; kk < 4; ++kk) {
#pragma unroll
          for (int ni = 0; ni < 4; ++ni) {
            int krow = ni * 16 + lr;
            bf16x8 bfr = *(const bf16x8*)(Kbase + krow * 256 + ((kk * 64 + lk * 16) ^ ((krow & 7) << 4)));
            sacc[ni] = __builtin_amdgcn_mfma_f32_16x16x32_bf16(qf[kk], bfr, sacc[ni], 0, 0, 0);
          }
        }
        __builtin_amdgcn_s_setprio(0);

        // ---- softmax: defer-max; l from MFMA ones-column (acc_l)
#pragma unroll
        for (int j = 0; j < 4; ++j) {
          int grow = q0 + wg * 16 + lk * 4 + j;
          float x[4];
#pragma unroll
          for (int ni = 0; ni < 4; ++ni) {
            float v = fmaf(sacc[ni][j], SCALE_L2E, madd[ni]);
            if (diag && c0 + ni * 16 + lr > grow) v = NEG_MIN;
            x[ni] = v;
          }
          float pm = fmaxf(fmaxf(x[0], x[1]), fmaxf(x[2], x[3]));
          if (!__all(pm <= m[j] + 16.f)) {
            float tmax = pm;
            tmax = fmaxf(tmax, dpp_ror<0x121>(tmax));
            tmax = fmaxf(tmax, dpp_ror<0x122>(tmax));
            tmax = fmaxf(tmax, dpp_ror<0x124>(tmax));
            tmax = fmaxf(tmax, dpp_ror<0x128>(tmax));
            float mn = fmaxf(m[j], tmax);
            if (mn > m[j]) {
              float sc = exp2f(m[j] - mn);
              acc_l[j] *= sc;
#pragma unroll
              for (int ni = 0; ni < 8; ++ni) acc_o[ni][j] *= sc;
              m[j] = mn;
            }
          }
          int prow = wg * 16 + lk * 4 + j;
#pragma unroll
          for (int ni = 0; ni < 4; ++ni) {
            float p = exp2f(x[ni] - m[j]);
            *(ushort*)(Pbase + prow * 128 + ((2 * (ni * 16 + lr)) ^ ((prow & 7) << 4))) = f2bf(p);
          }
        }

        __builtin_amdgcn_s_setprio(1);
#pragma unroll
        for (int kk = 0; kk < 2; ++kk) {
          int prow = wg * 16 + lr;
          bf16x8 a = *(const bf16x8*)(Pbase + prow * 128 + ((kk * 64 + lk * 16) ^ ((prow & 7) << 4)));
          acc_l = __builtin_amdgcn_mfma_f32_16x16x32_bf16(a, onesb, acc_l, 0, 0, 0);
#pragma unroll
          for (int ni = 0; ni < 8; ++ni) {
            int vrow = ni * 16 + lr;
            bf16x8 bfr = *(const bf16x8*)(Vbase + vrow * 128 + ((kk * 64 + lk * 16) ^ ((vrow & 7) << 4)));
            acc_o[ni] = __builtin_amdgcn_mfma_f32_16x16x32_bf16(a, bfr, acc_o[ni], 0, 0, 0);
          }
        }
        __builtin_amdgcn_s_setprio(0);
      }
      cur ^= 1;
    }

    __syncthreads();
    if (lr == 0) {
#pragma unroll
      for (int j = 0; j < 4; ++j) {
        int r = wg * 16 + lk * 4 + j;
        smv[g * 64 + r] = m[j];
        slv[g * 64 + r] = acc_l[j];
      }
    }
    __syncthreads();
    float myf[4], lcomb[4];
#pragma unroll
    for (int j = 0; j < 4; ++j) {
      int r = wg * 16 + lk * 4 + j;
      float m0 = smv[r], m1 = smv[64 + r];
      float l0 = slv[r], l1 = slv[64 + r];
      float mm = fmaxf(m0, m1);
      float f0 = exp2f(m0 - mm), f1 = exp2f(m1 - mm);
      lcomb[j] = l0 * f0 + l1 * f1;
      myf[j] = (g == 0) ? f0 : f1;
    }
    if (g == 1) {
#pragma unroll
      for (int j = 0; j < 4; ++j) {
        int r = wg * 16 + lk * 4 + j;
#pragma unroll
        for (int ni = 0; ni < 8; ++ni)
          accL[r * 132 + ni * 16 + lr] = acc_o[ni][j] * myf[j];
      }
    }
    __syncthreads();
    if (g == 0) {
#pragma unroll
      for (int j = 0; j < 4; ++j) {
        int row = q0 + wg * 16 + lk * 4 + j;
        int r = wg * 16 + lk * 4 + j;
        if (row < i0h) {
#pragma unroll
          for (int ni = 0; ni < 8; ++ni)
            ao[(size_t)row * 2048 + h * 128 + ni * 16 + lr] = f2bf(vmean[h * 128 + ni * 16 + lr]);
        } else {
          float inv = 1.f / lcomb[j];
#pragma unroll
          for (int ni = 0; ni < 8; ++ni) {
            float o = fmaf(acc_o[ni][j], myf[j], accL[r * 132 + ni * 16 + lr]);
            ao[(size_t)row * 2048 + h * 128 + ni * 16 + lr] = f2bf(o * inv);
          }
        }
      }
    }
  }
}

// ---------------------------------------------------------------------------
extern "C" void kernel_launch(void* const* d_in, const int* in_sizes, int n_in,
                              void* d_out, int out_size, void* d_ws, size_t ws_size,
                              hipStream_t stream)
{
  const float* hs    = (const float*)d_in[0];
  const float* amask = (const float*)d_in[1];
  const float* cosb  = (const float*)d_in[2];
  const float* sinb  = (const float*)d_in[3];
  const float* dmask = (const float*)d_in[4];
  const float* Wq    = (const float*)d_in[5];
  const float* Wk    = (const float*)d_in[6];
  const float* Wvq   = (const float*)d_in[7];
  const float* vkeys = (const float*)d_in[8];
  const float* vemb  = (const float*)d_in[9];
  const float* Wo    = (const float*)d_in[10];
  float* outp = (float*)d_out;

  char* ws = (char*)d_ws;
  const size_t MB = 1048576;
  float*  pvq     = (float*) (ws + 0);              // A: [0,32) 8 partials
  float*  vq_f32  = (float*) (ws + 64*MB);          // A-B: [64,68)
  ushort* vq_bf   = (ushort*)(ws + 68*MB);          // A-B: [68,70)
  ushort* vkT     = (ushort*)(ws + 0);              // B: [0,2)   over dead pvq
  ushort* sim_bf  = (ushort*)(ws + 2*MB);           // B: [2,34)
  int*    idx     = (int*)   (ws + 34*MB);          // B-C: 128 KB
  float*  vkTf32  = (float*) (ws + 36*MB);          // B: [36,40) over dead pvq
  ushort* vemb_bf = (ushort*)(ws + 35*MB);          // C: [35,43)
  ushort* hs_bf   = (ushort*)(ws + 43*MB);          // C-D: [43,51)
  ushort* vb      = (ushort*)(ws + 0);              // C: [0,8)   over dead vkT/sim
  ushort* vt      = (ushort*)(ws + 8*MB);           // C-E: [8,16)
  float*  part    = (float*) (ws + 51*MB);          // C: 64 KB
  float*  vmean   = (float*) (ws + 51*MB + 65536);  // C-E: 8 KB
  int*    i0b     = (int*)   (ws + 51*MB + 73728);  // C-E: 64 B
  ushort* WBig    = (ushort*)(ws + 16*MB);          // D-E: [16,40) Wq|Wk|Wo^T
  ushort* WoT     = (ushort*)(ws + 32*MB);          // = WBig + 16MB
  ushort* qkC     = (ushort*)(ws + 52*MB);          // D-E: [52,68) q|k, ld 4096
  ushort* ao      = (ushort*)(ws + 0);              // E: [0,8)   over dead vb

  dim3 blk(256);
  // ---- routing path ----
  gemm_f32_sk<<<dim3(4, 16, 8), blk, 0, stream>>>(hs, 2048, Wvq, 512, pvq, 512, 2048, 512, 256);
  reduce8_cvt<<<dim3(1024), blk, 0, stream>>>(pvq, vq_f32, vq_bf);
  transpose_cvt_vk<<<dim3(32, 2, 4), blk, 0, stream>>>(vkeys, vkT, vkTf32);
  gemm_bf16<1, 0><<<dim3(16, 16, 4), blk, 0, stream>>>(vq_bf, 512, vkT, 128,
      sim_bf, 2048, 128, 128, 262144, 4194304, nullptr, nullptr);
  topk_sel<<<dim3(2048), blk, 0, stream>>>(sim_bf, vq_f32, vkTf32, idx);
  // ---- v construction ----
  cvt2_bf16<<<dim3(8192), blk, 0, stream>>>(vemb, vemb_bf, hs, hs_bf);
  gather_mul_bf<<<dim3(2048), blk, 0, stream>>>(hs, vemb_bf, idx, vb);
  transpose_bf<<<dim3(32, 32), blk, 0, stream>>>(vb, vt);
  vmean_part<<<dim3(8, 16), blk, 0, stream>>>(vb, part);
  vmean_i0<<<dim3(16), blk, 0, stream>>>(part, amask, dmask, vmean, i0b);
  // ---- projections: Wq|Wk|Wo transpose (z=3), fused qk GEMM + RoPE ----
  transpose_cvt_w3<<<dim3(32, 32, 3), blk, 0, stream>>>(Wq, Wk, Wo, WBig);
  gemm_bf16<1, 1><<<dim3(32, 16, 1), blk, 0, stream>>>(hs_bf, 2048, WBig, 2048,
      qkC, 4096, 2048, 0, 0, 0, cosb, sinb);
  // ---- attention (XCD-swizzled 1D grid) ----
  attn_mfma<<<dim3(256), dim3(512), 0, stream>>>(qkC, qkC + 2048, vt, amask, dmask, vmean, i0b, ao);
  // ---- output projection ----
  gemm_bf16<0, 0><<<dim3(16, 16, 1), blk, 0, stream>>>(ao, 2048, WoT, 2048,
      outp, 2048, 2048, 0, 0, 0, nullptr, nullptr);
}